// Round 1
// baseline (1838.159 us; speedup 1.0000x reference)
//
#include <hip/hip_runtime.h>
#include <hip/hip_bf16.h>

#define NN 50000
#define NE 800000
#define FIN0 128
#define HID 60
#define CAT 180
#define NCLS 7
#define BN_EPS 1e-5f

// ---------------- CSR build ----------------

__global__ void k_hist(const int* __restrict__ dst, int* __restrict__ counts, int e) {
    int i = blockIdx.x * blockDim.x + threadIdx.x;
    if (i < e) atomicAdd(&counts[dst[i]], 1);
}

// single block 256 threads: exclusive scan counts[0..n) -> row_ptr[0..n]
__global__ void k_scan(const int* __restrict__ counts, int* __restrict__ row_ptr, int n) {
    __shared__ int part[256];
    int t = threadIdx.x;
    int per = (n + 255) / 256;
    int start = t * per;
    int end = start + per; if (end > n) end = n;
    if (start > n) start = n;
    int s = 0;
    for (int i = start; i < end; ++i) s += counts[i];
    part[t] = s;
    __syncthreads();
    for (int off = 1; off < 256; off <<= 1) {
        int v = (t >= off) ? part[t - off] : 0;
        __syncthreads();
        part[t] += v;
        __syncthreads();
    }
    int run = (t == 0) ? 0 : part[t - 1];
    for (int i = start; i < end; ++i) { row_ptr[i] = run; run += counts[i]; }
    if (t == 255) row_ptr[n] = run;
}

__global__ void k_dinv(const int* __restrict__ counts, float* __restrict__ dinv, int n) {
    int i = blockIdx.x * blockDim.x + threadIdx.x;
    if (i < n) dinv[i] = rsqrtf((float)(counts[i] + 1));  // +1 self loop
}

__global__ void k_scatter(const int* __restrict__ src, const int* __restrict__ dst,
                          const float* __restrict__ dinv, int* __restrict__ cursor,
                          int* __restrict__ ssrc, float* __restrict__ snorm, int e) {
    int i = blockIdx.x * blockDim.x + threadIdx.x;
    if (i >= e) return;
    int s = src[i], d = dst[i];
    int pos = atomicAdd(&cursor[d], 1);
    ssrc[pos] = s;
    snorm[pos] = dinv[s] * dinv[d];
}

// ---------------- propagation: out[n] = dinv[n]^2 x[n] + sum_e norm_e x[src_e]
// one block per dst node, threads = features (blockDim >= F)
__global__ void k_prop(const float* __restrict__ x, float* __restrict__ out,
                       const float* __restrict__ dinv, const int* __restrict__ rp,
                       const int* __restrict__ ssrc, const float* __restrict__ snorm,
                       int F) {
    int n = blockIdx.x, t = threadIdx.x;
    if (t >= F) return;
    float di = dinv[n];
    float acc = di * di * x[(size_t)n * F + t];
    int e0 = rp[n], e1 = rp[n + 1];
    for (int e = e0; e < e1; ++e) {
        acc += snorm[e] * x[(size_t)ssrc[e] * F + t];
    }
    out[(size_t)n * F + t] = acc;
}

// ---------------- mixhop fused linear: out[n,0:60]=x@w0+b0 | h1@w1+b1 | h2@w2+b2
// 8 nodes per block, rows staged in LDS; safe for out==xin (all reads before barrier)
template <int FINT>
__global__ void k_mixhop_lin(const float* __restrict__ xin, const float* __restrict__ h1,
                             const float* __restrict__ h2,
                             const float* __restrict__ w0, const float* __restrict__ b0,
                             const float* __restrict__ w1, const float* __restrict__ b1,
                             const float* __restrict__ w2, const float* __restrict__ b2,
                             float* __restrict__ out, int n) {
    const int NB = 8;
    __shared__ float sx[3][NB * FINT];
    int nb0 = blockIdx.x * NB;
    int t = threadIdx.x;
    for (int i = t; i < NB * FINT; i += 256) {
        int node = nb0 + i / FINT;
        size_t off = (size_t)node * FINT + (i % FINT);
        bool ok = node < n;
        sx[0][i] = ok ? xin[off] : 0.f;
        sx[1][i] = ok ? h1[off] : 0.f;
        sx[2][i] = ok ? h2[off] : 0.f;
    }
    __syncthreads();
    for (int o = t; o < NB * CAT; o += 256) {
        int ln = o / CAT;
        int j = o % CAT;
        int g = j / HID;
        int jj = j % HID;
        int node = nb0 + ln;
        if (node >= n) continue;
        const float* w = (g == 0) ? w0 : ((g == 1) ? w1 : w2);
        const float* b = (g == 0) ? b0 : ((g == 1) ? b1 : b2);
        const float* xr = &sx[g][ln * FINT];
        float acc = b[jj];
#pragma unroll 4
        for (int k = 0; k < FINT; ++k) acc += xr[k] * w[k * HID + jj];
        out[(size_t)node * CAT + j] = acc;
    }
}

// ---------------- batchnorm (training stats over node dim)
__global__ void k_bnstats(const float* __restrict__ h, float* __restrict__ mean,
                          float* __restrict__ rstd, int n) {
    int c = blockIdx.x;  // 0..CAT-1
    int t = threadIdx.x;
    float s1 = 0.f, s2 = 0.f;
    for (int r = t; r < n; r += 256) {
        float v = h[(size_t)r * CAT + c];
        s1 += v;
        s2 += v * v;
    }
    __shared__ float a1[256], a2[256];
    a1[t] = s1; a2[t] = s2;
    __syncthreads();
    for (int off = 128; off > 0; off >>= 1) {
        if (t < off) { a1[t] += a1[t + off]; a2[t] += a2[t + off]; }
        __syncthreads();
    }
    if (t == 0) {
        float mu = a1[0] / (float)n;
        float var = a2[0] / (float)n - mu * mu;
        mean[c] = mu;
        rstd[c] = rsqrtf(var + BN_EPS);
    }
}

__global__ void k_bnapply(float* __restrict__ h, const float* __restrict__ mean,
                          const float* __restrict__ rstd, const float* __restrict__ g,
                          const float* __restrict__ b, size_t total) {
    size_t i = (size_t)blockIdx.x * blockDim.x + threadIdx.x;
    if (i >= total) return;
    int c = (int)(i % CAT);
    h[i] = (h[i] - mean[c]) * rstd[c] * g[c] + b[c];
}

// ---------------- final linear [N,180]@[180,7]+b
__global__ void k_final(const float* __restrict__ h, const float* __restrict__ w,
                        const float* __restrict__ b, float* __restrict__ out, int n) {
    __shared__ float sw[CAT * NCLS];
    __shared__ float sb[NCLS];
    for (int i = threadIdx.x; i < CAT * NCLS; i += 256) sw[i] = w[i];
    if (threadIdx.x < NCLS) sb[threadIdx.x] = b[threadIdx.x];
    __syncthreads();
    int node = blockIdx.x * 256 + threadIdx.x;
    if (node >= n) return;
    float acc[NCLS];
#pragma unroll
    for (int j = 0; j < NCLS; ++j) acc[j] = sb[j];
    for (int k = 0; k < CAT; ++k) {
        float v = h[(size_t)node * CAT + k];
#pragma unroll
        for (int j = 0; j < NCLS; ++j) acc[j] += v * sw[k * NCLS + j];
    }
#pragma unroll
    for (int j = 0; j < NCLS; ++j) out[(size_t)node * NCLS + j] = acc[j];
}

extern "C" void kernel_launch(void* const* d_in, const int* in_sizes, int n_in,
                              void* d_out, int out_size, void* d_ws, size_t ws_size,
                              hipStream_t stream) {
    const float* x = (const float*)d_in[0];
    const int* ei = (const int*)d_in[1];
    const int* esrc = ei;
    const int* edst = ei + NE;

    // dict order: x, edge_index, then for p in 0..2: c1_wp,c1_bp,c2_wp,c2_bp,c3_wp,c3_bp
    const float* c_w[3][3];  // [layer][power]
    const float* c_b[3][3];
    for (int p = 0; p < 3; ++p)
        for (int l = 0; l < 3; ++l) {
            c_w[l][p] = (const float*)d_in[2 + p * 6 + l * 2];
            c_b[l][p] = (const float*)d_in[3 + p * 6 + l * 2];
        }
    const float* bn_g[3] = {(const float*)d_in[20], (const float*)d_in[22], (const float*)d_in[24]};
    const float* bn_b[3] = {(const float*)d_in[21], (const float*)d_in[23], (const float*)d_in[25]};
    const float* lw = (const float*)d_in[26];
    const float* lb = (const float*)d_in[27];
    float* out = (float*)d_out;

    // workspace carve
    char* wp = (char*)d_ws;
    auto alloc = [&](size_t bytes) {
        char* p = wp;
        wp += (bytes + 255) & ~(size_t)255;
        return p;
    };
    int* counts = (int*)alloc((size_t)NN * 4);
    int* row_ptr = (int*)alloc((size_t)(NN + 1) * 4);
    int* cursor = (int*)alloc((size_t)NN * 4);
    int* ssrc = (int*)alloc((size_t)NE * 4);
    float* snorm = (float*)alloc((size_t)NE * 4);
    float* dinv = (float*)alloc((size_t)NN * 4);
    float* mean = (float*)alloc((size_t)CAT * 4);
    float* rstd = (float*)alloc((size_t)CAT * 4);
    float* H1 = (float*)alloc((size_t)NN * CAT * 4);
    float* H2 = (float*)alloc((size_t)NN * CAT * 4);
    float* C = (float*)alloc((size_t)NN * CAT * 4);

    // ---- CSR build ----
    hipMemsetAsync(counts, 0, (size_t)NN * 4, stream);
    k_hist<<<(NE + 255) / 256, 256, 0, stream>>>(edst, counts, NE);
    k_scan<<<1, 256, 0, stream>>>(counts, row_ptr, NN);
    k_dinv<<<(NN + 255) / 256, 256, 0, stream>>>(counts, dinv, NN);
    hipMemcpyAsync(cursor, row_ptr, (size_t)NN * 4, hipMemcpyDeviceToDevice, stream);
    k_scatter<<<(NE + 255) / 256, 256, 0, stream>>>(esrc, edst, dinv, cursor, ssrc, snorm, NE);

    size_t total = (size_t)NN * CAT;

    // ---- layer 1 (Fin = 128) ----
    k_prop<<<NN, 128, 0, stream>>>(x, H1, dinv, row_ptr, ssrc, snorm, FIN0);
    k_prop<<<NN, 128, 0, stream>>>(H1, H2, dinv, row_ptr, ssrc, snorm, FIN0);
    k_mixhop_lin<FIN0><<<(NN + 7) / 8, 256, 0, stream>>>(
        x, H1, H2, c_w[0][0], c_b[0][0], c_w[0][1], c_b[0][1], c_w[0][2], c_b[0][2], C, NN);
    k_bnstats<<<CAT, 256, 0, stream>>>(C, mean, rstd, NN);
    k_bnapply<<<(int)((total + 255) / 256), 256, 0, stream>>>(C, mean, rstd, bn_g[0], bn_b[0], total);

    // ---- layers 2,3 (Fin = 180) ----
    for (int l = 1; l < 3; ++l) {
        k_prop<<<NN, 192, 0, stream>>>(C, H1, dinv, row_ptr, ssrc, snorm, CAT);
        k_prop<<<NN, 192, 0, stream>>>(H1, H2, dinv, row_ptr, ssrc, snorm, CAT);
        k_mixhop_lin<CAT><<<(NN + 7) / 8, 256, 0, stream>>>(
            C, H1, H2, c_w[l][0], c_b[l][0], c_w[l][1], c_b[l][1], c_w[l][2], c_b[l][2], C, NN);
        k_bnstats<<<CAT, 256, 0, stream>>>(C, mean, rstd, NN);
        k_bnapply<<<(int)((total + 255) / 256), 256, 0, stream>>>(C, mean, rstd, bn_g[l], bn_b[l], total);
    }

    // ---- final linear ----
    k_final<<<(NN + 255) / 256, 256, 0, stream>>>(C, lw, lb, out, NN);
}

// Round 2
// 889.638 us; speedup vs baseline: 2.0662x; 2.0662x over previous
//
#include <hip/hip_runtime.h>
#include <hip/hip_bf16.h>

#define NN 50000
#define NE 800000
#define FIN0 128
#define HID 60
#define CAT 180
#define NCLS 7
#define BN_EPS 1e-5f

// ---------------- CSR build ----------------

__global__ void k_hist(const int* __restrict__ dst, int* __restrict__ counts, int e) {
    int i = blockIdx.x * blockDim.x + threadIdx.x;
    if (i < e) atomicAdd(&counts[dst[i]], 1);
}

// single block 256 threads: exclusive scan counts[0..n) -> row_ptr[0..n]
__global__ void k_scan(const int* __restrict__ counts, int* __restrict__ row_ptr, int n) {
    __shared__ int part[256];
    int t = threadIdx.x;
    int per = (n + 255) / 256;
    int start = t * per;
    int end = start + per; if (end > n) end = n;
    if (start > n) start = n;
    int s = 0;
    for (int i = start; i < end; ++i) s += counts[i];
    part[t] = s;
    __syncthreads();
    for (int off = 1; off < 256; off <<= 1) {
        int v = (t >= off) ? part[t - off] : 0;
        __syncthreads();
        part[t] += v;
        __syncthreads();
    }
    int run = (t == 0) ? 0 : part[t - 1];
    for (int i = start; i < end; ++i) { row_ptr[i] = run; run += counts[i]; }
    if (t == 255) row_ptr[n] = run;
}

__global__ void k_dinv(const int* __restrict__ counts, float* __restrict__ dinv, int n) {
    int i = blockIdx.x * blockDim.x + threadIdx.x;
    if (i < n) dinv[i] = rsqrtf((float)(counts[i] + 1));  // +1 self loop
}

// pack (src, norm) into int2 for single 8B load per edge in props
__global__ void k_scatter(const int* __restrict__ src, const int* __restrict__ dst,
                          const float* __restrict__ dinv, int* __restrict__ cursor,
                          int2* __restrict__ epack, int e) {
    int i = blockIdx.x * blockDim.x + threadIdx.x;
    if (i >= e) return;
    int s = src[i], d = dst[i];
    int pos = atomicAdd(&cursor[d], 1);
    int2 v;
    v.x = s;
    v.y = __float_as_int(dinv[s] * dinv[d]);
    epack[pos] = v;
}

// ---------------- GEMM: per power p (grid.y), out_p = X @ w_p  (bias only for p=0)
// block: 128 nodes x 64 cols (60 used); 256 thr = 64 nsub x 4 cg; thread: 2 nodes x 16 cols
template <int FIN>
__global__ __launch_bounds__(256) void k_gemm(
        const float* __restrict__ X,
        const float* __restrict__ w0, const float* __restrict__ w1, const float* __restrict__ w2,
        const float* __restrict__ b0,
        float* __restrict__ Y0,   // N x 60 (p=0 out)
        float* __restrict__ Y12,  // N x 120 (p=1 cols 0-59, p=2 cols 60-119)
        int n) {
    const int p = blockIdx.y;
    const float* __restrict__ W = (p == 0) ? w0 : ((p == 1) ? w1 : w2);
    __shared__ float sx[16][128];  // [k][node_local]
    __shared__ float sw[16][64];   // [k][col]

    const int t = threadIdx.x;
    const int cg = t & 3;          // col group (16 cols)
    const int nsub = t >> 2;       // 0..63 -> nodes nsub*2, nsub*2+1
    const int nb0 = blockIdx.x * 128;
    const int cbase = cg << 4;

    float4 acc0[4], acc1[4];
#pragma unroll
    for (int j = 0; j < 4; ++j) {
        acc0[j] = make_float4(0.f, 0.f, 0.f, 0.f);
        acc1[j] = make_float4(0.f, 0.f, 0.f, 0.f);
    }

    const int node_l = t >> 1;     // staging: node slot 0..127
    const int half = t & 1;        // k-half (0..7 / 8..15)

    for (int k0 = 0; k0 < FIN; k0 += 16) {
        const int kc = (FIN - k0 < 16) ? (FIN - k0) : 16;
        __syncthreads();
        // stage x tile transposed
        {
            int node = nb0 + node_l;
            int kbase = k0 + half * 8;
            if (node < n) {
                if (kbase + 8 <= FIN) {
                    const float4* xp = (const float4*)(X + (size_t)node * FIN + kbase);
                    float4 a = xp[0], b = xp[1];
                    sx[half * 8 + 0][node_l] = a.x;
                    sx[half * 8 + 1][node_l] = a.y;
                    sx[half * 8 + 2][node_l] = a.z;
                    sx[half * 8 + 3][node_l] = a.w;
                    sx[half * 8 + 4][node_l] = b.x;
                    sx[half * 8 + 5][node_l] = b.y;
                    sx[half * 8 + 6][node_l] = b.z;
                    sx[half * 8 + 7][node_l] = b.w;
                } else if (kbase < FIN) {
                    for (int j = 0; j < 8; ++j) {
                        float v = (kbase + j < FIN) ? X[(size_t)node * FIN + kbase + j] : 0.f;
                        sx[half * 8 + j][node_l] = v;
                    }
                }
            } else {
                for (int j = 0; j < 8; ++j) sx[half * 8 + j][node_l] = 0.f;
            }
        }
        // stage w chunk
        for (int i = t; i < 16 * 64; i += 256) {
            int kk = i >> 6, c = i & 63;
            sw[kk][c] = (c < 60 && (k0 + kk) < FIN) ? W[(size_t)(k0 + kk) * 60 + c] : 0.f;
        }
        __syncthreads();

        if (kc == 16) {
#pragma unroll
            for (int kk = 0; kk < 16; ++kk) {
                float2 xv = *(const float2*)&sx[kk][nsub * 2];
#pragma unroll
                for (int j = 0; j < 4; ++j) {
                    float4 wv = *(const float4*)&sw[kk][cbase + (j << 2)];
                    acc0[j].x += xv.x * wv.x; acc0[j].y += xv.x * wv.y;
                    acc0[j].z += xv.x * wv.z; acc0[j].w += xv.x * wv.w;
                    acc1[j].x += xv.y * wv.x; acc1[j].y += xv.y * wv.y;
                    acc1[j].z += xv.y * wv.z; acc1[j].w += xv.y * wv.w;
                }
            }
        } else {
            for (int kk = 0; kk < kc; ++kk) {
                float2 xv = *(const float2*)&sx[kk][nsub * 2];
#pragma unroll
                for (int j = 0; j < 4; ++j) {
                    float4 wv = *(const float4*)&sw[kk][cbase + (j << 2)];
                    acc0[j].x += xv.x * wv.x; acc0[j].y += xv.x * wv.y;
                    acc0[j].z += xv.x * wv.z; acc0[j].w += xv.x * wv.w;
                    acc1[j].x += xv.y * wv.x; acc1[j].y += xv.y * wv.y;
                    acc1[j].z += xv.y * wv.z; acc1[j].w += xv.y * wv.w;
                }
            }
        }
    }

    // epilogue
#pragma unroll
    for (int i = 0; i < 2; ++i) {
        int node = nb0 + nsub * 2 + i;
        if (node >= n) continue;
#pragma unroll
        for (int j = 0; j < 4; ++j) {
            int c = cbase + (j << 2);
            if (c >= 60) continue;
            float4 v = (i == 0) ? acc0[j] : acc1[j];
            if (p == 0) {
                float4 bv = *(const float4*)&b0[c];
                v.x += bv.x; v.y += bv.y; v.z += bv.z; v.w += bv.w;
                *(float4*)(Y0 + (size_t)node * 60 + c) = v;
            } else {
                *(float4*)(Y12 + (size_t)node * 120 + (size_t)(p - 1) * 60 + c) = v;
            }
        }
    }
}

// ---------------- propA: F=120 over Y12; cols 0-59 -> Z (+b1), cols 60-119 -> Z (raw)
__global__ __launch_bounds__(64) void k_propA(
        const float* __restrict__ Y12, float* __restrict__ Z,
        const float* __restrict__ b1,
        const float* __restrict__ dinv, const int* __restrict__ rp,
        const int2* __restrict__ ep) {
    int nnode = blockIdx.x, t = threadIdx.x;
    if (t >= 60) return;
    float di = dinv[nnode];
    float w = di * di;
    float2 acc = *(const float2*)(Y12 + (size_t)nnode * 120 + 2 * t);
    acc.x *= w; acc.y *= w;
    int e0 = rp[nnode], e1 = rp[nnode + 1];
    int e = e0;
    for (; e + 1 < e1; e += 2) {
        int2 a = ep[e], b = ep[e + 1];
        float na = __int_as_float(a.y), nb = __int_as_float(b.y);
        float2 xa = *(const float2*)(Y12 + (size_t)a.x * 120 + 2 * t);
        float2 xb = *(const float2*)(Y12 + (size_t)b.x * 120 + 2 * t);
        acc.x += na * xa.x + nb * xb.x;
        acc.y += na * xa.y + nb * xb.y;
    }
    if (e < e1) {
        int2 a = ep[e];
        float na = __int_as_float(a.y);
        float2 xa = *(const float2*)(Y12 + (size_t)a.x * 120 + 2 * t);
        acc.x += na * xa.x;
        acc.y += na * xa.y;
    }
    if (t < 30) {  // power-1 final: add bias b1
        float2 bv = *(const float2*)(b1 + 2 * t);
        acc.x += bv.x; acc.y += bv.y;
    }
    *(float2*)(Z + (size_t)nnode * 120 + 2 * t) = acc;
}

// ---------------- propB: F=60 over Z cols 60-119 -> Q2 (+b2)
__global__ __launch_bounds__(64) void k_propB(
        const float* __restrict__ Z, float* __restrict__ Q2,
        const float* __restrict__ b2,
        const float* __restrict__ dinv, const int* __restrict__ rp,
        const int2* __restrict__ ep) {
    int nnode = blockIdx.x, t = threadIdx.x;
    if (t >= 60) return;
    float di = dinv[nnode];
    float acc = di * di * Z[(size_t)nnode * 120 + 60 + t];
    int e0 = rp[nnode], e1 = rp[nnode + 1];
    int e = e0;
    for (; e + 1 < e1; e += 2) {
        int2 a = ep[e], b = ep[e + 1];
        float xa = Z[(size_t)a.x * 120 + 60 + t];
        float xb = Z[(size_t)b.x * 120 + 60 + t];
        acc += __int_as_float(a.y) * xa + __int_as_float(b.y) * xb;
    }
    if (e < e1) {
        int2 a = ep[e];
        acc += __int_as_float(a.y) * Z[(size_t)a.x * 120 + 60 + t];
    }
    Q2[(size_t)nnode * 60 + t] = acc + b2[t];
}

// ---------------- BN stats: partial sums, coalesced row-major reads
__global__ __launch_bounds__(192) void k_bnstats(
        const float* __restrict__ Y0, const float* __restrict__ Z,
        const float* __restrict__ Q2,
        float* __restrict__ gsum, float* __restrict__ gsum2,
        int n, int rows_per) {
    int t = threadIdx.x;
    if (t >= CAT) return;
    const float* src;
    int stride;
    if (t < 60) { src = Y0 + t; stride = 60; }
    else if (t < 120) { src = Z + (t - 60); stride = 120; }
    else { src = Q2 + (t - 120); stride = 60; }
    int r0 = blockIdx.x * rows_per;
    int r1 = r0 + rows_per; if (r1 > n) r1 = n;
    float s1 = 0.f, s2 = 0.f;
    for (int r = r0; r < r1; ++r) {
        float v = src[(size_t)r * stride];
        s1 += v;
        s2 += v * v;
    }
    atomicAdd(&gsum[t], s1);
    atomicAdd(&gsum2[t], s2);
}

__global__ void k_bnfin(const float* __restrict__ gsum, const float* __restrict__ gsum2,
                        float* __restrict__ mean, float* __restrict__ rstd, int n) {
    int t = threadIdx.x;
    if (t >= CAT) return;
    float mu = gsum[t] / (float)n;
    float var = gsum2[t] / (float)n - mu * mu;
    mean[t] = mu;
    rstd[t] = rsqrtf(var + BN_EPS);
}

// ---------------- BN apply: gather 3 sources -> C (N x 180), float4
__global__ __launch_bounds__(256) void k_bnapply(
        const float* __restrict__ Y0, const float* __restrict__ Z,
        const float* __restrict__ Q2,
        const float* __restrict__ mean, const float* __restrict__ rstd,
        const float* __restrict__ g, const float* __restrict__ b,
        float* __restrict__ C, size_t total4) {
    size_t stride = (size_t)gridDim.x * blockDim.x;
    for (size_t i = (size_t)blockIdx.x * blockDim.x + threadIdx.x; i < total4; i += stride) {
        size_t e0 = i * 4;
        int c = (int)(e0 % CAT);
        size_t r = e0 / CAT;
        const float* sp;
        if (c < 60) sp = Y0 + r * 60 + c;
        else if (c < 120) sp = Z + r * 120 + (c - 60);
        else sp = Q2 + r * 60 + (c - 120);
        float4 v = *(const float4*)sp;
        float4 m = *(const float4*)&mean[c];
        float4 rs = *(const float4*)&rstd[c];
        float4 gv = *(const float4*)&g[c];
        float4 bv = *(const float4*)&b[c];
        float4 o;
        o.x = (v.x - m.x) * rs.x * gv.x + bv.x;
        o.y = (v.y - m.y) * rs.y * gv.y + bv.y;
        o.z = (v.z - m.z) * rs.z * gv.z + bv.z;
        o.w = (v.w - m.w) * rs.w * gv.w + bv.w;
        *(float4*)(C + e0) = o;
    }
}

// ---------------- final linear [N,180]@[180,7]+b
__global__ __launch_bounds__(256) void k_final(
        const float* __restrict__ h, const float* __restrict__ w,
        const float* __restrict__ b, float* __restrict__ out, int n) {
    __shared__ float sw[CAT * NCLS];
    __shared__ float sb[NCLS];
    for (int i = threadIdx.x; i < CAT * NCLS; i += 256) sw[i] = w[i];
    if (threadIdx.x < NCLS) sb[threadIdx.x] = b[threadIdx.x];
    __syncthreads();
    int node = blockIdx.x * 256 + threadIdx.x;
    if (node >= n) return;
    float acc[NCLS];
#pragma unroll
    for (int j = 0; j < NCLS; ++j) acc[j] = sb[j];
    const float4* hp = (const float4*)(h + (size_t)node * CAT);
#pragma unroll 5
    for (int k4 = 0; k4 < CAT / 4; ++k4) {
        float4 hv = hp[k4];
        int k = k4 * 4;
#pragma unroll
        for (int j = 0; j < NCLS; ++j) {
            acc[j] += hv.x * sw[(k + 0) * NCLS + j];
            acc[j] += hv.y * sw[(k + 1) * NCLS + j];
            acc[j] += hv.z * sw[(k + 2) * NCLS + j];
            acc[j] += hv.w * sw[(k + 3) * NCLS + j];
        }
    }
#pragma unroll
    for (int j = 0; j < NCLS; ++j) out[(size_t)node * NCLS + j] = acc[j];
}

extern "C" void kernel_launch(void* const* d_in, const int* in_sizes, int n_in,
                              void* d_out, int out_size, void* d_ws, size_t ws_size,
                              hipStream_t stream) {
    const float* x = (const float*)d_in[0];
    const int* ei = (const int*)d_in[1];
    const int* esrc = ei;
    const int* edst = ei + NE;

    // dict order: x, edge_index, then for p in 0..2: c1_wp,c1_bp,c2_wp,c2_bp,c3_wp,c3_bp
    const float* c_w[3][3];  // [layer][power]
    const float* c_b[3][3];
    for (int p = 0; p < 3; ++p)
        for (int l = 0; l < 3; ++l) {
            c_w[l][p] = (const float*)d_in[2 + p * 6 + l * 2];
            c_b[l][p] = (const float*)d_in[3 + p * 6 + l * 2];
        }
    const float* bn_g[3] = {(const float*)d_in[20], (const float*)d_in[22], (const float*)d_in[24]};
    const float* bn_b[3] = {(const float*)d_in[21], (const float*)d_in[23], (const float*)d_in[25]};
    const float* lw = (const float*)d_in[26];
    const float* lb = (const float*)d_in[27];
    float* out = (float*)d_out;

    // workspace carve
    char* wp = (char*)d_ws;
    auto alloc = [&](size_t bytes) {
        char* p = wp;
        wp += (bytes + 255) & ~(size_t)255;
        return p;
    };
    int* counts = (int*)alloc((size_t)NN * 4);
    int* row_ptr = (int*)alloc((size_t)(NN + 1) * 4);
    int* cursor = (int*)alloc((size_t)NN * 4);
    int2* epack = (int2*)alloc((size_t)NE * 8);
    float* dinv = (float*)alloc((size_t)NN * 4);
    float* gsum = (float*)alloc((size_t)2 * CAT * 4);  // gsum | gsum2
    float* gsum2 = gsum + CAT;
    float* mean = (float*)alloc((size_t)CAT * 4);
    float* rstd = (float*)alloc((size_t)CAT * 4);
    float* Y0 = (float*)alloc((size_t)NN * 60 * 4);
    float* Y12 = (float*)alloc((size_t)NN * 120 * 4);
    float* Z = (float*)alloc((size_t)NN * 120 * 4);
    float* Q2 = (float*)alloc((size_t)NN * 60 * 4);
    float* C = (float*)alloc((size_t)NN * CAT * 4);

    // ---- CSR build ----
    hipMemsetAsync(counts, 0, (size_t)NN * 4, stream);
    k_hist<<<(NE + 255) / 256, 256, 0, stream>>>(edst, counts, NE);
    k_scan<<<1, 256, 0, stream>>>(counts, row_ptr, NN);
    k_dinv<<<(NN + 255) / 256, 256, 0, stream>>>(counts, dinv, NN);
    hipMemcpyAsync(cursor, row_ptr, (size_t)NN * 4, hipMemcpyDeviceToDevice, stream);
    k_scatter<<<(NE + 255) / 256, 256, 0, stream>>>(esrc, edst, dinv, cursor, epack, NE);

    const size_t total4 = (size_t)NN * CAT / 4;
    const int gemm_gx = (NN + 127) / 128;
    const int stats_blocks = 500;
    const int rows_per = (NN + stats_blocks - 1) / stats_blocks;

    const float* xin = x;
    for (int l = 0; l < 3; ++l) {
        if (l == 0) {
            k_gemm<FIN0><<<dim3(gemm_gx, 3), 256, 0, stream>>>(
                xin, c_w[0][0], c_w[0][1], c_w[0][2], c_b[0][0], Y0, Y12, NN);
        } else {
            k_gemm<CAT><<<dim3(gemm_gx, 3), 256, 0, stream>>>(
                xin, c_w[l][0], c_w[l][1], c_w[l][2], c_b[l][0], Y0, Y12, NN);
        }
        k_propA<<<NN, 64, 0, stream>>>(Y12, Z, c_b[l][1], dinv, row_ptr, epack);
        k_propB<<<NN, 64, 0, stream>>>(Z, Q2, c_b[l][2], dinv, row_ptr, epack);
        hipMemsetAsync(gsum, 0, (size_t)2 * CAT * 4, stream);
        k_bnstats<<<stats_blocks, 192, 0, stream>>>(Y0, Z, Q2, gsum, gsum2, NN, rows_per);
        k_bnfin<<<1, 192, 0, stream>>>(gsum, gsum2, mean, rstd, NN);
        k_bnapply<<<2048, 256, 0, stream>>>(Y0, Z, Q2, mean, rstd, bn_g[l], bn_b[l], C, total4);
        xin = C;
    }

    k_final<<<(NN + 255) / 256, 256, 0, stream>>>(C, lw, lb, out, NN);
}

// Round 3
// 838.431 us; speedup vs baseline: 2.1924x; 1.0611x over previous
//
#include <hip/hip_runtime.h>
#include <hip/hip_bf16.h>

#define NN 50000
#define NE 800000
#define FIN0 128
#define HID 60
#define CAT 180
#define NCLS 7
#define BN_EPS 1e-5f

typedef unsigned int uint;
typedef unsigned short ushort;

__device__ __forceinline__ ushort f2bf(float f) {
    uint u = __float_as_uint(f);
    u += 0x7FFFu + ((u >> 16) & 1u);
    return (ushort)(u >> 16);
}
__device__ __forceinline__ float bf_lo(uint v) { return __uint_as_float(v << 16); }
__device__ __forceinline__ float bf_hi(uint v) { return __uint_as_float(v & 0xFFFF0000u); }
__device__ __forceinline__ float bf2f(ushort u) { return __uint_as_float(((uint)u) << 16); }

// ---------------- CSR build ----------------

__global__ void k_hist(const int* __restrict__ dst, int* __restrict__ counts, int e) {
    int i = blockIdx.x * blockDim.x + threadIdx.x;
    if (i < e) atomicAdd(&counts[dst[i]], 1);
}

__global__ void k_scan(const int* __restrict__ counts, int* __restrict__ row_ptr, int n) {
    __shared__ int part[256];
    int t = threadIdx.x;
    int per = (n + 255) / 256;
    int start = t * per;
    int end = start + per; if (end > n) end = n;
    if (start > n) start = n;
    int s = 0;
    for (int i = start; i < end; ++i) s += counts[i];
    part[t] = s;
    __syncthreads();
    for (int off = 1; off < 256; off <<= 1) {
        int v = (t >= off) ? part[t - off] : 0;
        __syncthreads();
        part[t] += v;
        __syncthreads();
    }
    int run = (t == 0) ? 0 : part[t - 1];
    for (int i = start; i < end; ++i) { row_ptr[i] = run; run += counts[i]; }
    if (t == 255) row_ptr[n] = run;
}

__global__ void k_dinv(const int* __restrict__ counts, float* __restrict__ dinv, int n) {
    int i = blockIdx.x * blockDim.x + threadIdx.x;
    if (i < n) dinv[i] = rsqrtf((float)(counts[i] + 1));  // +1 self loop
}

__global__ void k_scatter(const int* __restrict__ src, const int* __restrict__ dst,
                          const float* __restrict__ dinv, int* __restrict__ cursor,
                          int2* __restrict__ epack, int e) {
    int i = blockIdx.x * blockDim.x + threadIdx.x;
    if (i >= e) return;
    int s = src[i], d = dst[i];
    int pos = atomicAdd(&cursor[d], 1);
    int2 v;
    v.x = s;
    v.y = __float_as_int(dinv[s] * dinv[d]);
    epack[pos] = v;
}

// ---------------- GEMM: per power p (grid.y): Y_p = X @ w_p
// p=0 -> Y0 fp32 (+b0). p=1,2 -> Y12 bf16, interleaved: Y12[node][2c+(p-1)]
// tile 64 nodes x 64 cols (60 used); 256 thr; thread = 2 nodes x 8 cols
template <int FIN>
__global__ __launch_bounds__(256, 8) void k_gemm(
        const float* __restrict__ X,
        const float* __restrict__ w0, const float* __restrict__ w1, const float* __restrict__ w2,
        const float* __restrict__ b0,
        float* __restrict__ Y0,     // N x 60 fp32
        ushort* __restrict__ Y12,   // N x 120 bf16 interleaved
        int n) {
    constexpr int KC = (FIN == 128) ? 32 : 36;   // chunk: exact divisor of FIN
    constexpr int NCH = FIN / KC;
    constexpr int SXP = 74;                      // padded row (even, breaks bank stride)
    __shared__ float sx[KC][SXP];                // [k][node]
    __shared__ float sw[KC][64];                 // [k][col]

    const int p = blockIdx.y;
    const float* __restrict__ W = (p == 0) ? w0 : ((p == 1) ? w1 : w2);
    const int t = threadIdx.x;
    const int cg = t & 7;          // col group *8
    const int nsub = t >> 3;       // node pair 0..31
    const int nb0 = blockIdx.x * 64;

    float4 acc[2][2];
#pragma unroll
    for (int i = 0; i < 2; ++i)
#pragma unroll
        for (int j = 0; j < 2; ++j) acc[i][j] = make_float4(0.f, 0.f, 0.f, 0.f);

    for (int ch = 0; ch < NCH; ++ch) {
        const int k0 = ch * KC;
        __syncthreads();
        // stage X tile (coalesced float4 read, transposed scalar LDS writes)
        for (int i = t; i < 16 * KC; i += 256) {
            int node_l = i / (KC / 4);
            int kq = i - node_l * (KC / 4);
            int node = nb0 + node_l;
            float4 v = make_float4(0.f, 0.f, 0.f, 0.f);
            if (node < n) v = *(const float4*)(X + (size_t)node * FIN + k0 + kq * 4);
            sx[kq * 4 + 0][node_l] = v.x;
            sx[kq * 4 + 1][node_l] = v.y;
            sx[kq * 4 + 2][node_l] = v.z;
            sx[kq * 4 + 3][node_l] = v.w;
        }
        // stage W chunk
        for (int i = t; i < KC * 64; i += 256) {
            int kk = i >> 6, cc = i & 63;
            sw[kk][cc] = (cc < 60) ? W[(size_t)(k0 + kk) * 60 + cc] : 0.f;
        }
        __syncthreads();
#pragma unroll 4
        for (int kk = 0; kk < KC; ++kk) {
            float2 xv = *(const float2*)&sx[kk][nsub * 2];
            float4 wa = *(const float4*)&sw[kk][cg * 8];
            float4 wb = *(const float4*)&sw[kk][cg * 8 + 4];
            acc[0][0].x += xv.x * wa.x; acc[0][0].y += xv.x * wa.y;
            acc[0][0].z += xv.x * wa.z; acc[0][0].w += xv.x * wa.w;
            acc[0][1].x += xv.x * wb.x; acc[0][1].y += xv.x * wb.y;
            acc[0][1].z += xv.x * wb.z; acc[0][1].w += xv.x * wb.w;
            acc[1][0].x += xv.y * wa.x; acc[1][0].y += xv.y * wa.y;
            acc[1][0].z += xv.y * wa.z; acc[1][0].w += xv.y * wa.w;
            acc[1][1].x += xv.y * wb.x; acc[1][1].y += xv.y * wb.y;
            acc[1][1].z += xv.y * wb.z; acc[1][1].w += xv.y * wb.w;
        }
    }

    // epilogue
#pragma unroll
    for (int i = 0; i < 2; ++i) {
        int node = nb0 + nsub * 2 + i;
        if (node >= n) continue;
#pragma unroll
        for (int j = 0; j < 2; ++j) {
            int c0 = cg * 8 + j * 4;
            if (c0 >= 60) continue;
            float4 v = acc[i][j];
            if (p == 0) {
                float4 bv = *(const float4*)&b0[c0];
                v.x += bv.x; v.y += bv.y; v.z += bv.z; v.w += bv.w;
                *(float4*)(Y0 + (size_t)node * 60 + c0) = v;
            } else {
                ushort* yp = Y12 + (size_t)node * 120 + 2 * c0 + (p - 1);
                yp[0] = f2bf(v.x);
                yp[2] = f2bf(v.y);
                yp[4] = f2bf(v.z);
                yp[6] = f2bf(v.w);
            }
        }
    }
}

// ---------------- propA: over Y12 (bf16 interleaved, F=120)
// lane j: power1 col j -> Z1 fp32 (+b1); power2 col j -> ZQ bf16
__global__ __launch_bounds__(256) void k_propA(
        const ushort* __restrict__ Y12, float* __restrict__ Z1, ushort* __restrict__ ZQ,
        const float* __restrict__ b1,
        const float* __restrict__ dinv, const int* __restrict__ rp,
        const int2* __restrict__ ep, int n) {
    int node = blockIdx.x * 4 + (threadIdx.x >> 6);
    int lane = threadIdx.x & 63;
    if (node >= n || lane >= 60) return;
    float di = dinv[node];
    float swt = di * di;
    uint sv = *(const uint*)(Y12 + (size_t)node * 120 + 2 * lane);
    float a1 = swt * bf_lo(sv);
    float a2 = swt * bf_hi(sv);
    int e0 = rp[node], e1 = rp[node + 1];
    int e = e0;
    for (; e + 3 < e1; e += 4) {
        int2 p0 = ep[e], p1 = ep[e + 1], p2 = ep[e + 2], p3 = ep[e + 3];
        uint v0 = *(const uint*)(Y12 + (size_t)p0.x * 120 + 2 * lane);
        uint v1 = *(const uint*)(Y12 + (size_t)p1.x * 120 + 2 * lane);
        uint v2 = *(const uint*)(Y12 + (size_t)p2.x * 120 + 2 * lane);
        uint v3 = *(const uint*)(Y12 + (size_t)p3.x * 120 + 2 * lane);
        float n0 = __int_as_float(p0.y), n1 = __int_as_float(p1.y);
        float n2 = __int_as_float(p2.y), n3 = __int_as_float(p3.y);
        a1 += n0 * bf_lo(v0) + n1 * bf_lo(v1) + n2 * bf_lo(v2) + n3 * bf_lo(v3);
        a2 += n0 * bf_hi(v0) + n1 * bf_hi(v1) + n2 * bf_hi(v2) + n3 * bf_hi(v3);
    }
    for (; e < e1; ++e) {
        int2 pq = ep[e];
        uint v = *(const uint*)(Y12 + (size_t)pq.x * 120 + 2 * lane);
        float nm = __int_as_float(pq.y);
        a1 += nm * bf_lo(v);
        a2 += nm * bf_hi(v);
    }
    Z1[(size_t)node * 60 + lane] = a1 + b1[lane];
    ZQ[(size_t)node * 60 + lane] = f2bf(a2);
}

// ---------------- propB: over ZQ (bf16, F=60) -> Q2 fp32 (+b2)
__global__ __launch_bounds__(256) void k_propB(
        const ushort* __restrict__ ZQ, float* __restrict__ Q2,
        const float* __restrict__ b2,
        const float* __restrict__ dinv, const int* __restrict__ rp,
        const int2* __restrict__ ep, int n) {
    int node = blockIdx.x * 4 + (threadIdx.x >> 6);
    int lane = threadIdx.x & 63;
    if (node >= n || lane >= 60) return;
    float di = dinv[node];
    float acc = di * di * bf2f(ZQ[(size_t)node * 60 + lane]);
    int e0 = rp[node], e1 = rp[node + 1];
    int e = e0;
    for (; e + 3 < e1; e += 4) {
        int2 p0 = ep[e], p1 = ep[e + 1], p2 = ep[e + 2], p3 = ep[e + 3];
        float x0 = bf2f(ZQ[(size_t)p0.x * 60 + lane]);
        float x1 = bf2f(ZQ[(size_t)p1.x * 60 + lane]);
        float x2 = bf2f(ZQ[(size_t)p2.x * 60 + lane]);
        float x3 = bf2f(ZQ[(size_t)p3.x * 60 + lane]);
        acc += __int_as_float(p0.y) * x0 + __int_as_float(p1.y) * x1 +
               __int_as_float(p2.y) * x2 + __int_as_float(p3.y) * x3;
    }
    for (; e < e1; ++e) {
        int2 pq = ep[e];
        acc += __int_as_float(pq.y) * bf2f(ZQ[(size_t)pq.x * 60 + lane]);
    }
    Q2[(size_t)node * 60 + lane] = acc + b2[lane];
}

// ---------------- BN stats: partial sums over 3 fp32 N x 60 buffers
__global__ __launch_bounds__(192) void k_bnstats(
        const float* __restrict__ Y0, const float* __restrict__ Z1,
        const float* __restrict__ Q2,
        float* __restrict__ gsum, float* __restrict__ gsum2,
        int n, int rows_per) {
    int t = threadIdx.x;
    if (t >= CAT) return;
    int reg = t / 60, col = t - reg * 60;
    const float* src = ((reg == 0) ? Y0 : ((reg == 1) ? Z1 : Q2)) + col;
    int r0 = blockIdx.x * rows_per;
    int r1 = r0 + rows_per; if (r1 > n) r1 = n;
    float s1 = 0.f, s2 = 0.f;
    for (int r = r0; r < r1; ++r) {
        float v = src[(size_t)r * 60];
        s1 += v;
        s2 += v * v;
    }
    atomicAdd(&gsum[t], s1);
    atomicAdd(&gsum2[t], s2);
}

__global__ void k_bnfin(const float* __restrict__ gsum, const float* __restrict__ gsum2,
                        float* __restrict__ mean, float* __restrict__ rstd, int n) {
    int t = threadIdx.x;
    if (t >= CAT) return;
    float mu = gsum[t] / (float)n;
    float var = gsum2[t] / (float)n - mu * mu;
    mean[t] = mu;
    rstd[t] = rsqrtf(var + BN_EPS);
}

// ---------------- BN apply: gather 3 sources -> C (N x 180 fp32)
__global__ __launch_bounds__(256) void k_bnapply(
        const float* __restrict__ Y0, const float* __restrict__ Z1,
        const float* __restrict__ Q2,
        const float* __restrict__ mean, const float* __restrict__ rstd,
        const float* __restrict__ g, const float* __restrict__ b,
        float* __restrict__ C, size_t total4) {
    size_t stride = (size_t)gridDim.x * blockDim.x;
    for (size_t i = (size_t)blockIdx.x * blockDim.x + threadIdx.x; i < total4; i += stride) {
        size_t e0 = i * 4;
        int c = (int)(e0 % CAT);
        size_t r = e0 / CAT;
        const float* sp;
        if (c < 60) sp = Y0 + r * 60 + c;
        else if (c < 120) sp = Z1 + r * 60 + (c - 60);
        else sp = Q2 + r * 60 + (c - 120);
        float4 v = *(const float4*)sp;
        float4 m = *(const float4*)&mean[c];
        float4 rs = *(const float4*)&rstd[c];
        float4 gv = *(const float4*)&g[c];
        float4 bv = *(const float4*)&b[c];
        float4 o;
        o.x = (v.x - m.x) * rs.x * gv.x + bv.x;
        o.y = (v.y - m.y) * rs.y * gv.y + bv.y;
        o.z = (v.z - m.z) * rs.z * gv.z + bv.z;
        o.w = (v.w - m.w) * rs.w * gv.w + bv.w;
        *(float4*)(C + e0) = o;
    }
}

// ---------------- final linear [N,180]@[180,7]+b
__global__ __launch_bounds__(256) void k_final(
        const float* __restrict__ h, const float* __restrict__ w,
        const float* __restrict__ b, float* __restrict__ out, int n) {
    __shared__ float sw[CAT * NCLS];
    __shared__ float sb[NCLS];
    for (int i = threadIdx.x; i < CAT * NCLS; i += 256) sw[i] = w[i];
    if (threadIdx.x < NCLS) sb[threadIdx.x] = b[threadIdx.x];
    __syncthreads();
    int node = blockIdx.x * 256 + threadIdx.x;
    if (node >= n) return;
    float acc[NCLS];
#pragma unroll
    for (int j = 0; j < NCLS; ++j) acc[j] = sb[j];
    const float4* hp = (const float4*)(h + (size_t)node * CAT);
#pragma unroll 5
    for (int k4 = 0; k4 < CAT / 4; ++k4) {
        float4 hv = hp[k4];
        int k = k4 * 4;
#pragma unroll
        for (int j = 0; j < NCLS; ++j) {
            acc[j] += hv.x * sw[(k + 0) * NCLS + j];
            acc[j] += hv.y * sw[(k + 1) * NCLS + j];
            acc[j] += hv.z * sw[(k + 2) * NCLS + j];
            acc[j] += hv.w * sw[(k + 3) * NCLS + j];
        }
    }
#pragma unroll
    for (int j = 0; j < NCLS; ++j) out[(size_t)node * NCLS + j] = acc[j];
}

extern "C" void kernel_launch(void* const* d_in, const int* in_sizes, int n_in,
                              void* d_out, int out_size, void* d_ws, size_t ws_size,
                              hipStream_t stream) {
    const float* x = (const float*)d_in[0];
    const int* ei = (const int*)d_in[1];
    const int* esrc = ei;
    const int* edst = ei + NE;

    // dict order: x, edge_index, then for p in 0..2: c1_wp,c1_bp,c2_wp,c2_bp,c3_wp,c3_bp
    const float* c_w[3][3];  // [layer][power]
    const float* c_b[3][3];
    for (int p = 0; p < 3; ++p)
        for (int l = 0; l < 3; ++l) {
            c_w[l][p] = (const float*)d_in[2 + p * 6 + l * 2];
            c_b[l][p] = (const float*)d_in[3 + p * 6 + l * 2];
        }
    const float* bn_g[3] = {(const float*)d_in[20], (const float*)d_in[22], (const float*)d_in[24]};
    const float* bn_b[3] = {(const float*)d_in[21], (const float*)d_in[23], (const float*)d_in[25]};
    const float* lw = (const float*)d_in[26];
    const float* lb = (const float*)d_in[27];
    float* out = (float*)d_out;

    // workspace carve
    char* wp = (char*)d_ws;
    auto alloc = [&](size_t bytes) {
        char* p = wp;
        wp += (bytes + 255) & ~(size_t)255;
        return p;
    };
    int* counts = (int*)alloc((size_t)NN * 4);
    int* row_ptr = (int*)alloc((size_t)(NN + 1) * 4);
    int* cursor = (int*)alloc((size_t)NN * 4);
    int2* epack = (int2*)alloc((size_t)NE * 8);
    float* dinv = (float*)alloc((size_t)NN * 4);
    float* gsum = (float*)alloc((size_t)2 * CAT * 4);
    float* gsum2 = gsum + CAT;
    float* mean = (float*)alloc((size_t)CAT * 4);
    float* rstd = (float*)alloc((size_t)CAT * 4);
    float* Y0 = (float*)alloc((size_t)NN * 60 * 4);
    ushort* Y12 = (ushort*)alloc((size_t)NN * 120 * 2);
    float* Z1 = (float*)alloc((size_t)NN * 60 * 4);
    ushort* ZQ = (ushort*)alloc((size_t)NN * 60 * 2);
    float* Q2 = (float*)alloc((size_t)NN * 60 * 4);
    float* C = (float*)alloc((size_t)NN * CAT * 4);

    // ---- CSR build ----
    hipMemsetAsync(counts, 0, (size_t)NN * 4, stream);
    k_hist<<<(NE + 255) / 256, 256, 0, stream>>>(edst, counts, NE);
    k_scan<<<1, 256, 0, stream>>>(counts, row_ptr, NN);
    k_dinv<<<(NN + 255) / 256, 256, 0, stream>>>(counts, dinv, NN);
    hipMemcpyAsync(cursor, row_ptr, (size_t)NN * 4, hipMemcpyDeviceToDevice, stream);
    k_scatter<<<(NE + 255) / 256, 256, 0, stream>>>(esrc, edst, dinv, cursor, epack, NE);

    const size_t total4 = (size_t)NN * CAT / 4;
    const int gemm_gx = (NN + 63) / 64;
    const int prop_gx = (NN + 3) / 4;
    const int stats_blocks = 500;
    const int rows_per = (NN + stats_blocks - 1) / stats_blocks;

    const float* xin = x;
    for (int l = 0; l < 3; ++l) {
        if (l == 0) {
            k_gemm<FIN0><<<dim3(gemm_gx, 3), 256, 0, stream>>>(
                xin, c_w[0][0], c_w[0][1], c_w[0][2], c_b[0][0], Y0, Y12, NN);
        } else {
            k_gemm<CAT><<<dim3(gemm_gx, 3), 256, 0, stream>>>(
                xin, c_w[l][0], c_w[l][1], c_w[l][2], c_b[l][0], Y0, Y12, NN);
        }
        k_propA<<<prop_gx, 256, 0, stream>>>(Y12, Z1, ZQ, c_b[l][1], dinv, row_ptr, epack, NN);
        k_propB<<<prop_gx, 256, 0, stream>>>(ZQ, Q2, c_b[l][2], dinv, row_ptr, epack, NN);
        hipMemsetAsync(gsum, 0, (size_t)2 * CAT * 4, stream);
        k_bnstats<<<stats_blocks, 192, 0, stream>>>(Y0, Z1, Q2, gsum, gsum2, NN, rows_per);
        k_bnfin<<<1, 192, 0, stream>>>(gsum, gsum2, mean, rstd, NN);
        k_bnapply<<<2048, 256, 0, stream>>>(Y0, Z1, Q2, mean, rstd, bn_g[l], bn_b[l], C, total4);
        xin = C;
    }

    k_final<<<(NN + 255) / 256, 256, 0, stream>>>(C, lw, lb, out, NN);
}

// Round 4
// 608.618 us; speedup vs baseline: 3.0202x; 1.3776x over previous
//
#include <hip/hip_runtime.h>
#include <hip/hip_bf16.h>

#define NN 50000
#define NE 800000
#define FIN0 128
#define HID 60
#define CAT 180
#define NCLS 7
#define BN_EPS 1e-5f

typedef unsigned int uint;
typedef unsigned short ushort;
typedef __attribute__((ext_vector_type(8))) short short8;
typedef __attribute__((ext_vector_type(4))) float f32x4;

__device__ __forceinline__ ushort f2bf(float f) {
    uint u = __float_as_uint(f);
    u += 0x7FFFu + ((u >> 16) & 1u);
    return (ushort)(u >> 16);
}
__device__ __forceinline__ float bf_lo(uint v) { return __uint_as_float(v << 16); }
__device__ __forceinline__ float bf_hi(uint v) { return __uint_as_float(v & 0xFFFF0000u); }
__device__ __forceinline__ float bf2f(ushort u) { return __uint_as_float(((uint)u) << 16); }

// ---------------- CSR build ----------------

__global__ void k_hist(const int* __restrict__ dst, int* __restrict__ counts, int e) {
    int i = blockIdx.x * blockDim.x + threadIdx.x;
    if (i < e) atomicAdd(&counts[dst[i]], 1);
}

__global__ void k_blocksum(const int* __restrict__ counts, int* __restrict__ bsum, int n) {
    __shared__ int s[256];
    int t = threadIdx.x;
    int i = blockIdx.x * 256 + t;
    s[t] = (i < n) ? counts[i] : 0;
    __syncthreads();
    for (int off = 128; off > 0; off >>= 1) {
        if (t < off) s[t] += s[t + off];
        __syncthreads();
    }
    if (t == 0) bsum[blockIdx.x] = s[0];
}

// one block, G <= 256: exclusive scan of bsum -> boff
__global__ void k_scanb(const int* __restrict__ bsum, int* __restrict__ boff, int G) {
    __shared__ int s[256];
    int t = threadIdx.x;
    s[t] = (t < G) ? bsum[t] : 0;
    __syncthreads();
    for (int off = 1; off < 256; off <<= 1) {
        int v = (t >= off) ? s[t - off] : 0;
        __syncthreads();
        s[t] += v;
        __syncthreads();
    }
    if (t < G) boff[t] = (t == 0) ? 0 : s[t - 1];
}

__global__ void k_rowptr(const int* __restrict__ counts, const int* __restrict__ boff,
                         int* __restrict__ row_ptr, int n) {
    __shared__ int s[256];
    int t = threadIdx.x;
    int i = blockIdx.x * 256 + t;
    int c = (i < n) ? counts[i] : 0;
    s[t] = c;
    __syncthreads();
    for (int off = 1; off < 256; off <<= 1) {
        int v = (t >= off) ? s[t - off] : 0;
        __syncthreads();
        s[t] += v;
        __syncthreads();
    }
    if (i <= n) row_ptr[i] = boff[blockIdx.x] + s[t] - c;
}

__global__ void k_dinv(const int* __restrict__ counts, float* __restrict__ dinv, int n) {
    int i = blockIdx.x * blockDim.x + threadIdx.x;
    if (i < n) dinv[i] = rsqrtf((float)(counts[i] + 1));  // +1 self loop
}

__global__ void k_scatter(const int* __restrict__ src, const int* __restrict__ dst,
                          const float* __restrict__ dinv, int* __restrict__ cursor,
                          int2* __restrict__ epack, int e) {
    int i = blockIdx.x * blockDim.x + threadIdx.x;
    if (i >= e) return;
    int s = src[i], d = dst[i];
    int pos = atomicAdd(&cursor[d], 1);
    int2 v;
    v.x = s;
    v.y = __float_as_int(dinv[s] * dinv[d]);
    epack[pos] = v;
}

// ---------------- x -> bf16 cast (layer 1 input) ----------------
__global__ __launch_bounds__(256) void k_cast(const float* __restrict__ x,
                                              ushort* __restrict__ xb, size_t total4) {
    size_t stride = (size_t)gridDim.x * blockDim.x;
    for (size_t i = (size_t)blockIdx.x * blockDim.x + threadIdx.x; i < total4; i += stride) {
        float4 v = *(const float4*)(x + i * 4);
        ushort4 o;
        o.x = f2bf(v.x); o.y = f2bf(v.y); o.z = f2bf(v.z); o.w = f2bf(v.w);
        *(ushort4*)(xb + i * 4) = o;
    }
}

// ---------------- weight pack into MFMA B-fragment order ----------------
// WP[p][kt][ct][lane][8]: value = W[kt*32 + (lane>>4)*8 + j][ct*16 + (lane&15)]
__global__ void k_wpack(const float* __restrict__ w0, const float* __restrict__ w1,
                        const float* __restrict__ w2, ushort* __restrict__ WP,
                        int K_real, int KT) {
    int p = blockIdx.y;
    int kt = blockIdx.x >> 2;
    int ct = blockIdx.x & 3;
    const float* __restrict__ W = (p == 0) ? w0 : ((p == 1) ? w1 : w2);
    int lane = threadIdx.x;  // 0..63
    int k0 = kt * 32 + (lane >> 4) * 8;
    int c = ct * 16 + (lane & 15);
    ushort* dst = WP + (((size_t)(p * KT + kt) * 4 + ct) << 9) + (lane << 3);
    ushort4 o0, o1;
    float v;
#define WVAL(J) ((k0 + (J)) < K_real && c < 60) ? W[(size_t)(k0 + (J)) * 60 + c] : 0.f
    v = WVAL(0); o0.x = f2bf(v);
    v = WVAL(1); o0.y = f2bf(v);
    v = WVAL(2); o0.z = f2bf(v);
    v = WVAL(3); o0.w = f2bf(v);
    v = WVAL(4); o1.x = f2bf(v);
    v = WVAL(5); o1.y = f2bf(v);
    v = WVAL(6); o1.z = f2bf(v);
    v = WVAL(7); o1.w = f2bf(v);
#undef WVAL
    *(ushort4*)dst = o0;
    *(ushort4*)(dst + 4) = o1;
}

// ---------------- MFMA GEMM: per power p (grid.y): Y_p = XB @ w_p
// block: 256 thr = 4 waves; wave = 16 nodes x 64 cols; KT k-tiles of 32
template <int KT>
__global__ __launch_bounds__(256) void k_gemm_mfma(
        const ushort* __restrict__ XB,   // N x (KT*32) bf16
        const ushort* __restrict__ WP,   // packed [3][KT][4][64][8]
        const float* __restrict__ b0,
        float* __restrict__ Y0,          // N x 60 fp32 (p=0, +b0)
        ushort* __restrict__ Y12,        // N x 120 bf16 interleaved (p=1,2)
        int n) {
    const int p = blockIdx.y;
    const int t = threadIdx.x;
    const int wv = t >> 6;
    const int lane = t & 63;
    const int l15 = lane & 15;
    const int lhi = lane >> 4;
    const int nb = blockIdx.x * 64 + wv * 16;

    f32x4 acc[4];
#pragma unroll
    for (int ct = 0; ct < 4; ++ct) acc[ct] = (f32x4){0.f, 0.f, 0.f, 0.f};

    int arow = nb + l15;
    bool arow_ok = arow < n;
    const ushort* xrow = XB + (size_t)(arow_ok ? arow : 0) * (KT * 32) + lhi * 8;
    const ushort* wpP = WP + ((size_t)p * KT * 4 << 9) + (lane << 3);

#pragma unroll
    for (int kt = 0; kt < KT; ++kt) {
        short8 a = *(const short8*)(xrow + kt * 32);
#pragma unroll
        for (int ct = 0; ct < 4; ++ct) {
            short8 b = *(const short8*)(wpP + (((kt << 2) + ct) << 9));
            acc[ct] = __builtin_amdgcn_mfma_f32_16x16x32_bf16(a, b, acc[ct], 0, 0, 0);
        }
    }

    // epilogue: C/D layout col = lane&15, row = (lane>>4)*4 + reg
#pragma unroll
    for (int ct = 0; ct < 4; ++ct) {
        int col = ct * 16 + l15;
        if (col >= 60) continue;
        if (p == 0) {
            float bias = b0[col];
#pragma unroll
            for (int j = 0; j < 4; ++j) {
                int node = nb + lhi * 4 + j;
                if (node < n) Y0[(size_t)node * 60 + col] = acc[ct][j] + bias;
            }
        } else {
#pragma unroll
            for (int j = 0; j < 4; ++j) {
                int node = nb + lhi * 4 + j;
                if (node < n) Y12[(size_t)node * 120 + 2 * col + (p - 1)] = f2bf(acc[ct][j]);
            }
        }
    }
}

// ---------------- propA: over Y12 (bf16 interleaved, F=120)
__global__ __launch_bounds__(256) void k_propA(
        const ushort* __restrict__ Y12, float* __restrict__ Z1, ushort* __restrict__ ZQ,
        const float* __restrict__ b1,
        const float* __restrict__ dinv, const int* __restrict__ rp,
        const int2* __restrict__ ep, int n) {
    int node = blockIdx.x * 4 + (threadIdx.x >> 6);
    int lane = threadIdx.x & 63;
    if (node >= n || lane >= 60) return;
    float di = dinv[node];
    float swt = di * di;
    uint sv = *(const uint*)(Y12 + (size_t)node * 120 + 2 * lane);
    float a1 = swt * bf_lo(sv);
    float a2 = swt * bf_hi(sv);
    int e0 = rp[node], e1 = rp[node + 1];
    int e = e0;
    for (; e + 3 < e1; e += 4) {
        int2 p0 = ep[e], p1 = ep[e + 1], p2 = ep[e + 2], p3 = ep[e + 3];
        uint v0 = *(const uint*)(Y12 + (size_t)p0.x * 120 + 2 * lane);
        uint v1 = *(const uint*)(Y12 + (size_t)p1.x * 120 + 2 * lane);
        uint v2 = *(const uint*)(Y12 + (size_t)p2.x * 120 + 2 * lane);
        uint v3 = *(const uint*)(Y12 + (size_t)p3.x * 120 + 2 * lane);
        float n0 = __int_as_float(p0.y), n1 = __int_as_float(p1.y);
        float n2 = __int_as_float(p2.y), n3 = __int_as_float(p3.y);
        a1 += n0 * bf_lo(v0) + n1 * bf_lo(v1) + n2 * bf_lo(v2) + n3 * bf_lo(v3);
        a2 += n0 * bf_hi(v0) + n1 * bf_hi(v1) + n2 * bf_hi(v2) + n3 * bf_hi(v3);
    }
    for (; e < e1; ++e) {
        int2 pq = ep[e];
        uint v = *(const uint*)(Y12 + (size_t)pq.x * 120 + 2 * lane);
        float nm = __int_as_float(pq.y);
        a1 += nm * bf_lo(v);
        a2 += nm * bf_hi(v);
    }
    Z1[(size_t)node * 60 + lane] = a1 + b1[lane];
    ZQ[(size_t)node * 60 + lane] = f2bf(a2);
}

// ---------------- propB: over ZQ (bf16, F=60) -> Q2 fp32 (+b2)
__global__ __launch_bounds__(256) void k_propB(
        const ushort* __restrict__ ZQ, float* __restrict__ Q2,
        const float* __restrict__ b2,
        const float* __restrict__ dinv, const int* __restrict__ rp,
        const int2* __restrict__ ep, int n) {
    int node = blockIdx.x * 4 + (threadIdx.x >> 6);
    int lane = threadIdx.x & 63;
    if (node >= n || lane >= 60) return;
    float di = dinv[node];
    float acc = di * di * bf2f(ZQ[(size_t)node * 60 + lane]);
    int e0 = rp[node], e1 = rp[node + 1];
    int e = e0;
    for (; e + 3 < e1; e += 4) {
        int2 p0 = ep[e], p1 = ep[e + 1], p2 = ep[e + 2], p3 = ep[e + 3];
        float x0 = bf2f(ZQ[(size_t)p0.x * 60 + lane]);
        float x1 = bf2f(ZQ[(size_t)p1.x * 60 + lane]);
        float x2 = bf2f(ZQ[(size_t)p2.x * 60 + lane]);
        float x3 = bf2f(ZQ[(size_t)p3.x * 60 + lane]);
        acc += __int_as_float(p0.y) * x0 + __int_as_float(p1.y) * x1 +
               __int_as_float(p2.y) * x2 + __int_as_float(p3.y) * x3;
    }
    for (; e < e1; ++e) {
        int2 pq = ep[e];
        acc += __int_as_float(pq.y) * bf2f(ZQ[(size_t)pq.x * 60 + lane]);
    }
    Q2[(size_t)node * 60 + lane] = acc + b2[lane];
}

// ---------------- BN stats
__global__ __launch_bounds__(192) void k_bnstats(
        const float* __restrict__ Y0, const float* __restrict__ Z1,
        const float* __restrict__ Q2,
        float* __restrict__ gsum, float* __restrict__ gsum2,
        int n, int rows_per) {
    int t = threadIdx.x;
    if (t >= CAT) return;
    int reg = t / 60, col = t - reg * 60;
    const float* src = ((reg == 0) ? Y0 : ((reg == 1) ? Z1 : Q2)) + col;
    int r0 = blockIdx.x * rows_per;
    int r1 = r0 + rows_per; if (r1 > n) r1 = n;
    float s1 = 0.f, s2 = 0.f;
    for (int r = r0; r < r1; ++r) {
        float v = src[(size_t)r * 60];
        s1 += v;
        s2 += v * v;
    }
    atomicAdd(&gsum[t], s1);
    atomicAdd(&gsum2[t], s2);
}

__global__ void k_bnfin(const float* __restrict__ gsum, const float* __restrict__ gsum2,
                        float* __restrict__ mean, float* __restrict__ rstd, int n) {
    int t = threadIdx.x;
    if (t >= CAT) return;
    float mu = gsum[t] / (float)n;
    float var = gsum2[t] / (float)n - mu * mu;
    mean[t] = mu;
    rstd[t] = rsqrtf(var + BN_EPS);
}

// ---------------- BN apply -> CB (N x 192 bf16, zero-padded cols 180..191)
__global__ __launch_bounds__(256) void k_bnapply(
        const float* __restrict__ Y0, const float* __restrict__ Z1,
        const float* __restrict__ Q2,
        const float* __restrict__ mean, const float* __restrict__ rstd,
        const float* __restrict__ g, const float* __restrict__ b,
        ushort* __restrict__ CB, size_t total) {  // total = n*48
    size_t stride = (size_t)gridDim.x * blockDim.x;
    for (size_t i = (size_t)blockIdx.x * blockDim.x + threadIdx.x; i < total; i += stride) {
        size_t node = i / 48;
        int c0 = (int)(i % 48) * 4;
        ushort4 o;
        if (c0 >= CAT) {
            o.x = 0; o.y = 0; o.z = 0; o.w = 0;
        } else {
            const float* sp;
            if (c0 < 60) sp = Y0 + node * 60 + c0;
            else if (c0 < 120) sp = Z1 + node * 60 + (c0 - 60);
            else sp = Q2 + node * 60 + (c0 - 120);
            float4 v = *(const float4*)sp;
            float4 m = *(const float4*)&mean[c0];
            float4 rs = *(const float4*)&rstd[c0];
            float4 gv = *(const float4*)&g[c0];
            float4 bv = *(const float4*)&b[c0];
            o.x = f2bf((v.x - m.x) * rs.x * gv.x + bv.x);
            o.y = f2bf((v.y - m.y) * rs.y * gv.y + bv.y);
            o.z = f2bf((v.z - m.z) * rs.z * gv.z + bv.z);
            o.w = f2bf((v.w - m.w) * rs.w * gv.w + bv.w);
        }
        *(ushort4*)(CB + node * 192 + c0) = o;
    }
}

// ---------------- final linear: CB (bf16) [N,180] @ [180,7] + b
__global__ __launch_bounds__(256) void k_final(
        const ushort* __restrict__ CB, const float* __restrict__ w,
        const float* __restrict__ b, float* __restrict__ out, int n) {
    __shared__ float sw[CAT * NCLS];
    __shared__ float sb[NCLS];
    for (int i = threadIdx.x; i < CAT * NCLS; i += 256) sw[i] = w[i];
    if (threadIdx.x < NCLS) sb[threadIdx.x] = b[threadIdx.x];
    __syncthreads();
    int node = blockIdx.x * 256 + threadIdx.x;
    if (node >= n) return;
    float acc[NCLS];
#pragma unroll
    for (int j = 0; j < NCLS; ++j) acc[j] = sb[j];
    const uint* hp = (const uint*)(CB + (size_t)node * 192);
#pragma unroll 6
    for (int k2 = 0; k2 < 90; ++k2) {
        uint v = hp[k2];
        float f0 = bf_lo(v), f1 = bf_hi(v);
        int k = k2 * 2;
#pragma unroll
        for (int j = 0; j < NCLS; ++j)
            acc[j] += f0 * sw[k * NCLS + j] + f1 * sw[(k + 1) * NCLS + j];
    }
#pragma unroll
    for (int j = 0; j < NCLS; ++j) out[(size_t)node * NCLS + j] = acc[j];
}

extern "C" void kernel_launch(void* const* d_in, const int* in_sizes, int n_in,
                              void* d_out, int out_size, void* d_ws, size_t ws_size,
                              hipStream_t stream) {
    const float* x = (const float*)d_in[0];
    const int* ei = (const int*)d_in[1];
    const int* esrc = ei;
    const int* edst = ei + NE;

    const float* c_w[3][3];
    const float* c_b[3][3];
    for (int p = 0; p < 3; ++p)
        for (int l = 0; l < 3; ++l) {
            c_w[l][p] = (const float*)d_in[2 + p * 6 + l * 2];
            c_b[l][p] = (const float*)d_in[3 + p * 6 + l * 2];
        }
    const float* bn_g[3] = {(const float*)d_in[20], (const float*)d_in[22], (const float*)d_in[24]};
    const float* bn_b[3] = {(const float*)d_in[21], (const float*)d_in[23], (const float*)d_in[25]};
    const float* lw = (const float*)d_in[26];
    const float* lb = (const float*)d_in[27];
    float* out = (float*)d_out;

    char* wp = (char*)d_ws;
    auto alloc = [&](size_t bytes) {
        char* p = wp;
        wp += (bytes + 255) & ~(size_t)255;
        return p;
    };
    int* counts = (int*)alloc((size_t)NN * 4);
    int* row_ptr = (int*)alloc((size_t)(NN + 1) * 4);
    int* cursor = (int*)alloc((size_t)NN * 4);
    int* bsum = (int*)alloc((size_t)256 * 4);
    int* boff = (int*)alloc((size_t)256 * 4);
    int2* epack = (int2*)alloc((size_t)NE * 8);
    float* dinv = (float*)alloc((size_t)NN * 4);
    float* gsum = (float*)alloc((size_t)2 * CAT * 4);
    float* gsum2 = gsum + CAT;
    float* mean = (float*)alloc((size_t)CAT * 4);
    float* rstd = (float*)alloc((size_t)CAT * 4);
    float* Y0 = (float*)alloc((size_t)NN * 60 * 4);
    ushort* Y12 = (ushort*)alloc((size_t)NN * 120 * 2);
    float* Z1 = (float*)alloc((size_t)NN * 60 * 4);
    ushort* ZQ = (ushort*)alloc((size_t)NN * 60 * 2);
    float* Q2 = (float*)alloc((size_t)NN * 60 * 4);
    ushort* XB1 = (ushort*)alloc((size_t)NN * 128 * 2);
    ushort* CB = (ushort*)alloc((size_t)NN * 192 * 2);
    ushort* WP1 = (ushort*)alloc((size_t)3 * 4 * 4 * 512 * 2);
    ushort* WP2 = (ushort*)alloc((size_t)3 * 6 * 4 * 512 * 2);
    ushort* WP3 = (ushort*)alloc((size_t)3 * 6 * 4 * 512 * 2);

    const int GB = (NN + 255) / 256;  // 196

    // ---- CSR build ----
    hipMemsetAsync(counts, 0, (size_t)NN * 4, stream);
    k_hist<<<(NE + 255) / 256, 256, 0, stream>>>(edst, counts, NE);
    k_blocksum<<<GB, 256, 0, stream>>>(counts, bsum, NN);
    k_scanb<<<1, 256, 0, stream>>>(bsum, boff, GB);
    k_rowptr<<<GB, 256, 0, stream>>>(counts, boff, row_ptr, NN);
    k_dinv<<<(NN + 255) / 256, 256, 0, stream>>>(counts, dinv, NN);
    hipMemcpyAsync(cursor, row_ptr, (size_t)NN * 4, hipMemcpyDeviceToDevice, stream);
    k_scatter<<<(NE + 255) / 256, 256, 0, stream>>>(esrc, edst, dinv, cursor, epack, NE);

    // ---- prep: x cast + weight packs ----
    k_cast<<<2048, 256, 0, stream>>>(x, XB1, (size_t)NN * 128 / 4);
    k_wpack<<<dim3(16, 3), 64, 0, stream>>>(c_w[0][0], c_w[0][1], c_w[0][2], WP1, FIN0, 4);
    k_wpack<<<dim3(24, 3), 64, 0, stream>>>(c_w[1][0], c_w[1][1], c_w[1][2], WP2, CAT, 6);
    k_wpack<<<dim3(24, 3), 64, 0, stream>>>(c_w[2][0], c_w[2][1], c_w[2][2], WP3, CAT, 6);

    const int gemm_gx = (NN + 63) / 64;
    const int prop_gx = (NN + 3) / 4;
    const int stats_blocks = 500;
    const int rows_per = (NN + stats_blocks - 1) / stats_blocks;
    const size_t bn_total = (size_t)NN * 48;

    for (int l = 0; l < 3; ++l) {
        if (l == 0) {
            k_gemm_mfma<4><<<dim3(gemm_gx, 3), 256, 0, stream>>>(XB1, WP1, c_b[0][0], Y0, Y12, NN);
        } else {
            const ushort* WPl = (l == 1) ? WP2 : WP3;
            k_gemm_mfma<6><<<dim3(gemm_gx, 3), 256, 0, stream>>>(CB, WPl, c_b[l][0], Y0, Y12, NN);
        }
        k_propA<<<prop_gx, 256, 0, stream>>>(Y12, Z1, ZQ, c_b[l][1], dinv, row_ptr, epack, NN);
        k_propB<<<prop_gx, 256, 0, stream>>>(ZQ, Q2, c_b[l][2], dinv, row_ptr, epack, NN);
        hipMemsetAsync(gsum, 0, (size_t)2 * CAT * 4, stream);
        k_bnstats<<<stats_blocks, 192, 0, stream>>>(Y0, Z1, Q2, gsum, gsum2, NN, rows_per);
        k_bnfin<<<1, 192, 0, stream>>>(gsum, gsum2, mean, rstd, NN);
        k_bnapply<<<2048, 256, 0, stream>>>(Y0, Z1, Q2, mean, rstd, bn_g[l], bn_b[l], CB, bn_total);
    }

    k_final<<<(NN + 255) / 256, 256, 0, stream>>>(CB, lw, lb, out, NN);
}

// Round 5
// 601.838 us; speedup vs baseline: 3.0542x; 1.0113x over previous
//
#include <hip/hip_runtime.h>
#include <hip/hip_bf16.h>

#define NN 50000
#define NE 800000
#define FIN0 128
#define HID 60
#define CAT 180
#define NCLS 7
#define BN_EPS 1e-5f

typedef unsigned int uint;
typedef unsigned short ushort;
typedef __attribute__((ext_vector_type(8))) short short8;
typedef __attribute__((ext_vector_type(4))) float f32x4;

__device__ __forceinline__ ushort f2bf(float f) {
    uint u = __float_as_uint(f);
    u += 0x7FFFu + ((u >> 16) & 1u);
    return (ushort)(u >> 16);
}
__device__ __forceinline__ float bf_lo(uint v) { return __uint_as_float(v << 16); }
__device__ __forceinline__ float bf_hi(uint v) { return __uint_as_float(v & 0xFFFF0000u); }

// ---------------- CSR build ----------------

__global__ void k_hist(const int* __restrict__ dst, int* __restrict__ counts, int e) {
    int i = blockIdx.x * blockDim.x + threadIdx.x;
    if (i < e) atomicAdd(&counts[dst[i]], 1);
}

__global__ void k_blocksum(const int* __restrict__ counts, int* __restrict__ bsum, int n) {
    __shared__ int s[256];
    int t = threadIdx.x;
    int i = blockIdx.x * 256 + t;
    s[t] = (i < n) ? counts[i] : 0;
    __syncthreads();
    for (int off = 128; off > 0; off >>= 1) {
        if (t < off) s[t] += s[t + off];
        __syncthreads();
    }
    if (t == 0) bsum[blockIdx.x] = s[0];
}

// one block, G <= 256: exclusive scan of bsum -> boff
__global__ void k_scanb(const int* __restrict__ bsum, int* __restrict__ boff, int G) {
    __shared__ int s[256];
    int t = threadIdx.x;
    s[t] = (t < G) ? bsum[t] : 0;
    __syncthreads();
    for (int off = 1; off < 256; off <<= 1) {
        int v = (t >= off) ? s[t - off] : 0;
        __syncthreads();
        s[t] += v;
        __syncthreads();
    }
    if (t < G) boff[t] = (t == 0) ? 0 : s[t - 1];
}

// row_ptr + cursor copy + dinv, one pass
__global__ void k_rowptr(const int* __restrict__ counts, const int* __restrict__ boff,
                         int* __restrict__ row_ptr, int* __restrict__ cursor,
                         float* __restrict__ dinv, int n) {
    __shared__ int s[256];
    int t = threadIdx.x;
    int i = blockIdx.x * 256 + t;
    int c = (i < n) ? counts[i] : 0;
    s[t] = c;
    __syncthreads();
    for (int off = 1; off < 256; off <<= 1) {
        int v = (t >= off) ? s[t - off] : 0;
        __syncthreads();
        s[t] += v;
        __syncthreads();
    }
    if (i <= n) {
        int rp = boff[blockIdx.x] + s[t] - c;
        row_ptr[i] = rp;
        if (i < n) {
            cursor[i] = rp;
            dinv[i] = rsqrtf((float)(c + 1));  // +1 self loop
        }
    }
}

// scatter only src index (4B) — norms are pre-folded into node features
__global__ void k_scatter(const int* __restrict__ src, const int* __restrict__ dst,
                          int* __restrict__ cursor, int* __restrict__ ssrc, int e) {
    int i = blockIdx.x * blockDim.x + threadIdx.x;
    if (i >= e) return;
    int pos = atomicAdd(&cursor[dst[i]], 1);
    ssrc[pos] = src[i];
}

// ---------------- x -> bf16 cast (layer 1 input) ----------------
__global__ __launch_bounds__(256) void k_cast(const float* __restrict__ x,
                                              ushort* __restrict__ xb, size_t total4) {
    size_t stride = (size_t)gridDim.x * blockDim.x;
    for (size_t i = (size_t)blockIdx.x * blockDim.x + threadIdx.x; i < total4; i += stride) {
        float4 v = *(const float4*)(x + i * 4);
        ushort4 o;
        o.x = f2bf(v.x); o.y = f2bf(v.y); o.z = f2bf(v.z); o.w = f2bf(v.w);
        *(ushort4*)(xb + i * 4) = o;
    }
}

// ---------------- weight pack into MFMA B-fragment order ----------------
__global__ void k_wpack(const float* __restrict__ w0, const float* __restrict__ w1,
                        const float* __restrict__ w2, ushort* __restrict__ WP,
                        int K_real, int KT) {
    int p = blockIdx.y;
    int kt = blockIdx.x >> 2;
    int ct = blockIdx.x & 3;
    const float* __restrict__ W = (p == 0) ? w0 : ((p == 1) ? w1 : w2);
    int lane = threadIdx.x;  // 0..63
    int k0 = kt * 32 + (lane >> 4) * 8;
    int c = ct * 16 + (lane & 15);
    ushort* dst = WP + (((size_t)(p * KT + kt) * 4 + ct) << 9) + (lane << 3);
    ushort4 o0, o1;
    float v;
#define WVAL(J) ((k0 + (J)) < K_real && c < 60) ? W[(size_t)(k0 + (J)) * 60 + c] : 0.f
    v = WVAL(0); o0.x = f2bf(v);
    v = WVAL(1); o0.y = f2bf(v);
    v = WVAL(2); o0.z = f2bf(v);
    v = WVAL(3); o0.w = f2bf(v);
    v = WVAL(4); o1.x = f2bf(v);
    v = WVAL(5); o1.y = f2bf(v);
    v = WVAL(6); o1.z = f2bf(v);
    v = WVAL(7); o1.w = f2bf(v);
#undef WVAL
    *(ushort4*)dst = o0;
    *(ushort4*)(dst + 4) = o1;
}

// ---------------- MFMA GEMM: per power p (grid.y): Y_p = XB @ w_p
// p=0 -> Y0 fp32 (+b0); p=1,2 -> Y12 bf16 interleaved, PRE-SCALED by dinv[node]
template <int KT>
__global__ __launch_bounds__(256) void k_gemm_mfma(
        const ushort* __restrict__ XB,   // N x (KT*32) bf16
        const ushort* __restrict__ WP,   // packed [3][KT][4][64][8]
        const float* __restrict__ b0,
        const float* __restrict__ dinv,
        float* __restrict__ Y0,
        ushort* __restrict__ Y12,
        int n) {
    const int p = blockIdx.y;
    const int t = threadIdx.x;
    const int wv = t >> 6;
    const int lane = t & 63;
    const int l15 = lane & 15;
    const int lhi = lane >> 4;
    const int nb = blockIdx.x * 64 + wv * 16;

    f32x4 acc[4];
#pragma unroll
    for (int ct = 0; ct < 4; ++ct) acc[ct] = (f32x4){0.f, 0.f, 0.f, 0.f};

    int arow = nb + l15;
    bool arow_ok = arow < n;
    const ushort* xrow = XB + (size_t)(arow_ok ? arow : 0) * (KT * 32) + lhi * 8;
    const ushort* wpP = WP + ((size_t)p * KT * 4 << 9) + (lane << 3);

#pragma unroll
    for (int kt = 0; kt < KT; ++kt) {
        short8 a = *(const short8*)(xrow + kt * 32);
#pragma unroll
        for (int ct = 0; ct < 4; ++ct) {
            short8 b = *(const short8*)(wpP + (((kt << 2) + ct) << 9));
            acc[ct] = __builtin_amdgcn_mfma_f32_16x16x32_bf16(a, b, acc[ct], 0, 0, 0);
        }
    }

    // C/D layout: col = lane&15, row = (lane>>4)*4 + reg
    float dv[4];
#pragma unroll
    for (int j = 0; j < 4; ++j) {
        int node = nb + lhi * 4 + j;
        dv[j] = (p != 0 && node < n) ? dinv[node] : 0.f;
    }
#pragma unroll
    for (int ct = 0; ct < 4; ++ct) {
        int col = ct * 16 + l15;
        if (col >= 60) continue;
        if (p == 0) {
            float bias = b0[col];
#pragma unroll
            for (int j = 0; j < 4; ++j) {
                int node = nb + lhi * 4 + j;
                if (node < n) Y0[(size_t)node * 60 + col] = acc[ct][j] + bias;
            }
        } else {
#pragma unroll
            for (int j = 0; j < 4; ++j) {
                int node = nb + lhi * 4 + j;
                if (node < n) Y12[(size_t)node * 120 + 2 * col + (p - 1)] = f2bf(dv[j] * acc[ct][j]);
            }
        }
    }
}

// ---------------- propA: hop over pre-scaled Y12 (bf16 interleaved)
// Z1 = dinv*sum1 + b1 (fp32, final power-1); ZQ = dinv^2*sum2 (bf16, pre-scaled for hop 2)
__global__ __launch_bounds__(256) void k_propA(
        const ushort* __restrict__ Y12, float* __restrict__ Z1, ushort* __restrict__ ZQ,
        const float* __restrict__ b1,
        const float* __restrict__ dinv, const int* __restrict__ rp,
        const int* __restrict__ es, int n) {
    int node = blockIdx.x * 4 + (threadIdx.x >> 6);
    int lane = threadIdx.x & 63;
    if (node >= n || lane >= 60) return;
    uint sv = *(const uint*)(Y12 + (size_t)node * 120 + 2 * lane);
    float a1 = bf_lo(sv);
    float a2 = bf_hi(sv);
    int e0 = rp[node], e1 = rp[node + 1];
    int e = e0;
    for (; e + 7 < e1; e += 8) {
        int s0 = es[e], s1 = es[e + 1], s2 = es[e + 2], s3 = es[e + 3];
        int s4 = es[e + 4], s5 = es[e + 5], s6 = es[e + 6], s7 = es[e + 7];
        uint v0 = *(const uint*)(Y12 + (size_t)s0 * 120 + 2 * lane);
        uint v1 = *(const uint*)(Y12 + (size_t)s1 * 120 + 2 * lane);
        uint v2 = *(const uint*)(Y12 + (size_t)s2 * 120 + 2 * lane);
        uint v3 = *(const uint*)(Y12 + (size_t)s3 * 120 + 2 * lane);
        uint v4 = *(const uint*)(Y12 + (size_t)s4 * 120 + 2 * lane);
        uint v5 = *(const uint*)(Y12 + (size_t)s5 * 120 + 2 * lane);
        uint v6 = *(const uint*)(Y12 + (size_t)s6 * 120 + 2 * lane);
        uint v7 = *(const uint*)(Y12 + (size_t)s7 * 120 + 2 * lane);
        a1 += ((bf_lo(v0) + bf_lo(v1)) + (bf_lo(v2) + bf_lo(v3))) +
              ((bf_lo(v4) + bf_lo(v5)) + (bf_lo(v6) + bf_lo(v7)));
        a2 += ((bf_hi(v0) + bf_hi(v1)) + (bf_hi(v2) + bf_hi(v3))) +
              ((bf_hi(v4) + bf_hi(v5)) + (bf_hi(v6) + bf_hi(v7)));
    }
    for (; e < e1; ++e) {
        uint v = *(const uint*)(Y12 + (size_t)es[e] * 120 + 2 * lane);
        a1 += bf_lo(v);
        a2 += bf_hi(v);
    }
    float di = dinv[node];
    Z1[(size_t)node * 60 + lane] = di * a1 + b1[lane];
    ZQ[(size_t)node * 60 + lane] = f2bf(di * di * a2);
}

// ---------------- propB: hop over pre-scaled ZQ -> Q2 fp32 (+b2)
__global__ __launch_bounds__(256) void k_propB(
        const ushort* __restrict__ ZQ, float* __restrict__ Q2,
        const float* __restrict__ b2,
        const float* __restrict__ dinv, const int* __restrict__ rp,
        const int* __restrict__ es, int n) {
    int node = blockIdx.x * 4 + (threadIdx.x >> 6);
    int lane = threadIdx.x & 63;
    if (node >= n || lane >= 60) return;
    float acc = __uint_as_float(((uint)ZQ[(size_t)node * 60 + lane]) << 16);
    int e0 = rp[node], e1 = rp[node + 1];
    int e = e0;
    for (; e + 7 < e1; e += 8) {
        int s0 = es[e], s1 = es[e + 1], s2 = es[e + 2], s3 = es[e + 3];
        int s4 = es[e + 4], s5 = es[e + 5], s6 = es[e + 6], s7 = es[e + 7];
        float x0 = __uint_as_float(((uint)ZQ[(size_t)s0 * 60 + lane]) << 16);
        float x1 = __uint_as_float(((uint)ZQ[(size_t)s1 * 60 + lane]) << 16);
        float x2 = __uint_as_float(((uint)ZQ[(size_t)s2 * 60 + lane]) << 16);
        float x3 = __uint_as_float(((uint)ZQ[(size_t)s3 * 60 + lane]) << 16);
        float x4 = __uint_as_float(((uint)ZQ[(size_t)s4 * 60 + lane]) << 16);
        float x5 = __uint_as_float(((uint)ZQ[(size_t)s5 * 60 + lane]) << 16);
        float x6 = __uint_as_float(((uint)ZQ[(size_t)s6 * 60 + lane]) << 16);
        float x7 = __uint_as_float(((uint)ZQ[(size_t)s7 * 60 + lane]) << 16);
        acc += ((x0 + x1) + (x2 + x3)) + ((x4 + x5) + (x6 + x7));
    }
    for (; e < e1; ++e) {
        acc += __uint_as_float(((uint)ZQ[(size_t)es[e] * 60 + lane]) << 16);
    }
    Q2[(size_t)node * 60 + lane] = dinv[node] * acc + b2[lane];
}

// ---------------- BN stats
__global__ __launch_bounds__(192) void k_bnstats(
        const float* __restrict__ Y0, const float* __restrict__ Z1,
        const float* __restrict__ Q2,
        float* __restrict__ gsum, float* __restrict__ gsum2,
        int n, int rows_per) {
    int t = threadIdx.x;
    if (t >= CAT) return;
    int reg = t / 60, col = t - reg * 60;
    const float* src = ((reg == 0) ? Y0 : ((reg == 1) ? Z1 : Q2)) + col;
    int r0 = blockIdx.x * rows_per;
    int r1 = r0 + rows_per; if (r1 > n) r1 = n;
    float s1 = 0.f, s2 = 0.f;
    for (int r = r0; r < r1; ++r) {
        float v = src[(size_t)r * 60];
        s1 += v;
        s2 += v * v;
    }
    atomicAdd(&gsum[t], s1);
    atomicAdd(&gsum2[t], s2);
}

// ---------------- BN apply (inline finalize) -> CB (N x 192 bf16, zero-padded)
__global__ __launch_bounds__(256) void k_bnapply(
        const float* __restrict__ Y0, const float* __restrict__ Z1,
        const float* __restrict__ Q2,
        const float* __restrict__ gsum, const float* __restrict__ gsum2,
        const float* __restrict__ g, const float* __restrict__ b,
        ushort* __restrict__ CB, int n, size_t total) {  // total = n*48
    __shared__ float ssc[CAT], ssh[CAT];
    int tt = threadIdx.x;
    if (tt < CAT) {
        float mu = gsum[tt] / (float)n;
        float var = gsum2[tt] / (float)n - mu * mu;
        float sc = rsqrtf(var + BN_EPS) * g[tt];
        ssc[tt] = sc;
        ssh[tt] = b[tt] - mu * sc;
    }
    __syncthreads();
    size_t stride = (size_t)gridDim.x * blockDim.x;
    for (size_t i = (size_t)blockIdx.x * blockDim.x + tt; i < total; i += stride) {
        size_t node = i / 48;
        int c0 = (int)(i % 48) * 4;
        ushort4 o;
        if (c0 >= CAT) {
            o.x = 0; o.y = 0; o.z = 0; o.w = 0;
        } else {
            const float* sp;
            if (c0 < 60) sp = Y0 + node * 60 + c0;
            else if (c0 < 120) sp = Z1 + node * 60 + (c0 - 60);
            else sp = Q2 + node * 60 + (c0 - 120);
            float4 v = *(const float4*)sp;
            o.x = f2bf(v.x * ssc[c0 + 0] + ssh[c0 + 0]);
            o.y = f2bf(v.y * ssc[c0 + 1] + ssh[c0 + 1]);
            o.z = f2bf(v.z * ssc[c0 + 2] + ssh[c0 + 2]);
            o.w = f2bf(v.w * ssc[c0 + 3] + ssh[c0 + 3]);
        }
        *(ushort4*)(CB + node * 192 + c0) = o;
    }
}

// ---------------- final linear: CB (bf16) [N,180] @ [180,7] + b
__global__ __launch_bounds__(256) void k_final(
        const ushort* __restrict__ CB, const float* __restrict__ w,
        const float* __restrict__ b, float* __restrict__ out, int n) {
    __shared__ float sw[CAT * NCLS];
    __shared__ float sb[NCLS];
    for (int i = threadIdx.x; i < CAT * NCLS; i += 256) sw[i] = w[i];
    if (threadIdx.x < NCLS) sb[threadIdx.x] = b[threadIdx.x];
    __syncthreads();
    int node = blockIdx.x * 256 + threadIdx.x;
    if (node >= n) return;
    float acc[NCLS];
#pragma unroll
    for (int j = 0; j < NCLS; ++j) acc[j] = sb[j];
    const uint* hp = (const uint*)(CB + (size_t)node * 192);
#pragma unroll 6
    for (int k2 = 0; k2 < 90; ++k2) {
        uint v = hp[k2];
        float f0 = bf_lo(v), f1 = bf_hi(v);
        int k = k2 * 2;
#pragma unroll
        for (int j = 0; j < NCLS; ++j)
            acc[j] += f0 * sw[k * NCLS + j] + f1 * sw[(k + 1) * NCLS + j];
    }
#pragma unroll
    for (int j = 0; j < NCLS; ++j) out[(size_t)node * NCLS + j] = acc[j];
}

extern "C" void kernel_launch(void* const* d_in, const int* in_sizes, int n_in,
                              void* d_out, int out_size, void* d_ws, size_t ws_size,
                              hipStream_t stream) {
    const float* x = (const float*)d_in[0];
    const int* ei = (const int*)d_in[1];
    const int* esrc = ei;
    const int* edst = ei + NE;

    const float* c_w[3][3];
    const float* c_b[3][3];
    for (int p = 0; p < 3; ++p)
        for (int l = 0; l < 3; ++l) {
            c_w[l][p] = (const float*)d_in[2 + p * 6 + l * 2];
            c_b[l][p] = (const float*)d_in[3 + p * 6 + l * 2];
        }
    const float* bn_g[3] = {(const float*)d_in[20], (const float*)d_in[22], (const float*)d_in[24]};
    const float* bn_b[3] = {(const float*)d_in[21], (const float*)d_in[23], (const float*)d_in[25]};
    const float* lw = (const float*)d_in[26];
    const float* lb = (const float*)d_in[27];
    float* out = (float*)d_out;

    char* wp = (char*)d_ws;
    auto alloc = [&](size_t bytes) {
        char* p = wp;
        wp += (bytes + 255) & ~(size_t)255;
        return p;
    };
    int* counts = (int*)alloc((size_t)NN * 4);
    int* row_ptr = (int*)alloc((size_t)(NN + 1) * 4);
    int* cursor = (int*)alloc((size_t)NN * 4);
    int* bsum = (int*)alloc((size_t)256 * 4);
    int* boff = (int*)alloc((size_t)256 * 4);
    int* ssrc = (int*)alloc((size_t)NE * 4);
    float* dinv = (float*)alloc((size_t)NN * 4);
    float* gsum = (float*)alloc((size_t)2 * CAT * 4);
    float* gsum2 = gsum + CAT;
    float* Y0 = (float*)alloc((size_t)NN * 60 * 4);
    ushort* Y12 = (ushort*)alloc((size_t)NN * 120 * 2);
    float* Z1 = (float*)alloc((size_t)NN * 60 * 4);
    ushort* ZQ = (ushort*)alloc((size_t)NN * 60 * 2);
    float* Q2 = (float*)alloc((size_t)NN * 60 * 4);
    ushort* XB1 = (ushort*)alloc((size_t)NN * 128 * 2);
    ushort* CB = (ushort*)alloc((size_t)NN * 192 * 2);
    ushort* WP1 = (ushort*)alloc((size_t)3 * 4 * 4 * 512 * 2);
    ushort* WP2 = (ushort*)alloc((size_t)3 * 6 * 4 * 512 * 2);
    ushort* WP3 = (ushort*)alloc((size_t)3 * 6 * 4 * 512 * 2);

    const int GB = (NN + 255) / 256;  // 196

    // ---- CSR build ----
    hipMemsetAsync(counts, 0, (size_t)NN * 4, stream);
    k_hist<<<(NE + 255) / 256, 256, 0, stream>>>(edst, counts, NE);
    k_blocksum<<<GB, 256, 0, stream>>>(counts, bsum, NN);
    k_scanb<<<1, 256, 0, stream>>>(bsum, boff, GB);
    k_rowptr<<<GB, 256, 0, stream>>>(counts, boff, row_ptr, cursor, dinv, NN);
    k_scatter<<<(NE + 255) / 256, 256, 0, stream>>>(esrc, edst, cursor, ssrc, NE);

    // ---- prep: x cast + weight packs ----
    k_cast<<<2048, 256, 0, stream>>>(x, XB1, (size_t)NN * 128 / 4);
    k_wpack<<<dim3(16, 3), 64, 0, stream>>>(c_w[0][0], c_w[0][1], c_w[0][2], WP1, FIN0, 4);
    k_wpack<<<dim3(24, 3), 64, 0, stream>>>(c_w[1][0], c_w[1][1], c_w[1][2], WP2, CAT, 6);
    k_wpack<<<dim3(24, 3), 64, 0, stream>>>(c_w[2][0], c_w[2][1], c_w[2][2], WP3, CAT, 6);

    const int gemm_gx = (NN + 63) / 64;
    const int prop_gx = (NN + 3) / 4;
    const int stats_blocks = 500;
    const int rows_per = (NN + stats_blocks - 1) / stats_blocks;
    const size_t bn_total = (size_t)NN * 48;

    for (int l = 0; l < 3; ++l) {
        if (l == 0) {
            k_gemm_mfma<4><<<dim3(gemm_gx, 3), 256, 0, stream>>>(XB1, WP1, c_b[0][0], dinv, Y0, Y12, NN);
        } else {
            const ushort* WPl = (l == 1) ? WP2 : WP3;
            k_gemm_mfma<6><<<dim3(gemm_gx, 3), 256, 0, stream>>>(CB, WPl, c_b[l][0], dinv, Y0, Y12, NN);
        }
        k_propA<<<prop_gx, 256, 0, stream>>>(Y12, Z1, ZQ, c_b[l][1], dinv, row_ptr, ssrc, NN);
        k_propB<<<prop_gx, 256, 0, stream>>>(ZQ, Q2, c_b[l][2], dinv, row_ptr, ssrc, NN);
        hipMemsetAsync(gsum, 0, (size_t)2 * CAT * 4, stream);
        k_bnstats<<<stats_blocks, 192, 0, stream>>>(Y0, Z1, Q2, gsum, gsum2, NN, rows_per);
        k_bnapply<<<2048, 256, 0, stream>>>(Y0, Z1, Q2, gsum, gsum2, bn_g[l], bn_b[l], CB, NN, bn_total);
    }

    k_final<<<(NN + 255) / 256, 256, 0, stream>>>(CB, lw, lb, out, NN);
}

// Round 6
// 490.469 us; speedup vs baseline: 3.7478x; 1.2271x over previous
//
#include <hip/hip_runtime.h>
#include <hip/hip_bf16.h>

#define NN 50000
#define NE 800000
#define FIN0 128
#define HID 60
#define CAT 180
#define NCLS 7
#define BN_EPS 1e-5f
#define NBUCK 196      // ceil(NN/256)
#define BCAP 5120      // max edges per 256-node bucket (mean 4096, sigma 64)

typedef unsigned int uint;
typedef unsigned short ushort;
typedef __attribute__((ext_vector_type(8))) short short8;
typedef __attribute__((ext_vector_type(4))) float f32x4;

__device__ __forceinline__ ushort f2bf(float f) {
    uint u = __float_as_uint(f);
    u += 0x7FFFu + ((u >> 16) & 1u);
    return (ushort)(u >> 16);
}
__device__ __forceinline__ float bf_lo(uint v) { return __uint_as_float(v << 16); }
__device__ __forceinline__ float bf_hi(uint v) { return __uint_as_float(v & 0xFFFF0000u); }
__device__ __forceinline__ float bf2f(ushort u) { return __uint_as_float(((uint)u) << 16); }

// ---------------- CSR build: bucketed, write-combined ----------------

__global__ void k_initcur(int* __restrict__ gcur) {
    int t = threadIdx.x;
    if (t < NBUCK) gcur[t] = t * BCAP;
}

// pass 1: bin edges into 196 coarse buckets; per-block LDS ranking so each
// block writes contiguous runs (lines written by one block -> L2 combine)
__global__ __launch_bounds__(256) void k_bin(const int* __restrict__ src,
                                             const int* __restrict__ dst,
                                             int* __restrict__ gcur,
                                             int2* __restrict__ ebuf, int e) {
    __shared__ int cnt[NBUCK];
    __shared__ int base[NBUCK];
    int t = threadIdx.x;
    for (int c0 = blockIdx.x * 2048; c0 < e; c0 += gridDim.x * 2048) {
        if (t < NBUCK) cnt[t] = 0;
        __syncthreads();
        int sv[8], dv[8], rk[8], bk[8], ok[8];
#pragma unroll
        for (int j = 0; j < 8; ++j) {
            int i = c0 + j * 256 + t;
            ok[j] = i < e;
            if (ok[j]) {
                sv[j] = src[i];
                dv[j] = dst[i];
                bk[j] = dv[j] >> 8;
                rk[j] = atomicAdd(&cnt[bk[j]], 1);
            }
        }
        __syncthreads();
        if (t < NBUCK && cnt[t] > 0) base[t] = atomicAdd(&gcur[t], cnt[t]);
        __syncthreads();
#pragma unroll
        for (int j = 0; j < 8; ++j) {
            if (ok[j]) {
                int2 v; v.x = sv[j]; v.y = dv[j];
                ebuf[base[bk[j]] + rk[j]] = v;
            }
        }
        __syncthreads();
    }
}

// scan bucket counts -> bucket bases; row_ptr[NN] = NE
__global__ void k_bscan(const int* __restrict__ gcur, int* __restrict__ bbase,
                        int* __restrict__ bcnt, int* __restrict__ row_ptr) {
    __shared__ int s[256];
    int t = threadIdx.x;
    int c = (t < NBUCK) ? (gcur[t] - t * BCAP) : 0;
    s[t] = c;
    __syncthreads();
    for (int off = 1; off < 256; off <<= 1) {
        int v = (t >= off) ? s[t - off] : 0;
        __syncthreads();
        s[t] += v;
        __syncthreads();
    }
    if (t < NBUCK) { bbase[t] = s[t] - c; bcnt[t] = c; }
    if (t == 0) row_ptr[NN] = NE;
}

// pass 2: one block per bucket -> exact per-node CSR + dinv
__global__ __launch_bounds__(256) void k_bucket_csr(
        const int2* __restrict__ ebuf, const int* __restrict__ bbase,
        const int* __restrict__ bcnt,
        int* __restrict__ row_ptr, float* __restrict__ dinv,
        int* __restrict__ ssrc, int n) {
    __shared__ int ncnt[256];
    __shared__ int loff[256];
    int b = blockIdx.x, t = threadIdx.x;
    int cnt = bcnt[b];
    int gbase = bbase[b];
    const int2* ee = ebuf + (size_t)b * BCAP;
    ncnt[t] = 0;
    __syncthreads();
    for (int i = t; i < cnt; i += 256) atomicAdd(&ncnt[ee[i].y & 255], 1);
    __syncthreads();
    int c = ncnt[t];
    loff[t] = c;
    __syncthreads();
    for (int off = 1; off < 256; off <<= 1) {
        int v = (t >= off) ? loff[t - off] : 0;
        __syncthreads();
        loff[t] += v;
        __syncthreads();
    }
    int excl = loff[t] - c;
    int node = b * 256 + t;
    if (node < n) {
        row_ptr[node] = gbase + excl;
        dinv[node] = rsqrtf((float)(c + 1));  // +1 self loop
    }
    __syncthreads();
    ncnt[t] = excl;  // reuse as cursor
    __syncthreads();
    for (int i = t; i < cnt; i += 256) {
        int2 ed = ee[i];
        int pos = atomicAdd(&ncnt[ed.y & 255], 1);
        ssrc[gbase + pos] = ed.x;
    }
}

// ---------------- x -> bf16 cast ----------------
__global__ __launch_bounds__(256) void k_cast(const float* __restrict__ x,
                                              ushort* __restrict__ xb, size_t total4) {
    size_t stride = (size_t)gridDim.x * blockDim.x;
    for (size_t i = (size_t)blockIdx.x * blockDim.x + threadIdx.x; i < total4; i += stride) {
        float4 v = *(const float4*)(x + i * 4);
        ushort4 o;
        o.x = f2bf(v.x); o.y = f2bf(v.y); o.z = f2bf(v.z); o.w = f2bf(v.w);
        *(ushort4*)(xb + i * 4) = o;
    }
}

// ---------------- weight pack into MFMA B-fragment order ----------------
__global__ void k_wpack(const float* __restrict__ w0, const float* __restrict__ w1,
                        const float* __restrict__ w2, ushort* __restrict__ WP,
                        int K_real, int KT) {
    int p = blockIdx.y;
    int kt = blockIdx.x >> 2;
    int ct = blockIdx.x & 3;
    const float* __restrict__ W = (p == 0) ? w0 : ((p == 1) ? w1 : w2);
    int lane = threadIdx.x;  // 0..63
    int k0 = kt * 32 + (lane >> 4) * 8;
    int c = ct * 16 + (lane & 15);
    ushort* dst = WP + (((size_t)(p * KT + kt) * 4 + ct) << 9) + (lane << 3);
    ushort4 o0, o1;
    float v;
#define WVAL(J) ((k0 + (J)) < K_real && c < 60) ? W[(size_t)(k0 + (J)) * 60 + c] : 0.f
    v = WVAL(0); o0.x = f2bf(v);
    v = WVAL(1); o0.y = f2bf(v);
    v = WVAL(2); o0.z = f2bf(v);
    v = WVAL(3); o0.w = f2bf(v);
    v = WVAL(4); o1.x = f2bf(v);
    v = WVAL(5); o1.y = f2bf(v);
    v = WVAL(6); o1.z = f2bf(v);
    v = WVAL(7); o1.w = f2bf(v);
#undef WVAL
    *(ushort4*)dst = o0;
    *(ushort4*)(dst + 4) = o1;
}

// ---------------- MFMA GEMM, all 3 powers in one block (shared A-frags)
// p=0 -> Y0 bf16 (+b0); p=1,2 -> Y12 bf16 interleaved, pre-scaled by dinv
template <int KT>
__global__ __launch_bounds__(256) void k_gemm_mfma(
        const ushort* __restrict__ XB,   // N x (KT*32) bf16
        const ushort* __restrict__ WP,   // packed [3][KT][4][64][8]
        const float* __restrict__ b0,
        const float* __restrict__ dinv,
        ushort* __restrict__ Y0,
        ushort* __restrict__ Y12,
        int n) {
    const int t = threadIdx.x;
    const int wv = t >> 6;
    const int lane = t & 63;
    const int l15 = lane & 15;
    const int lhi = lane >> 4;
    const int nb = blockIdx.x * 64 + wv * 16;

    f32x4 acc[3][4];
#pragma unroll
    for (int p = 0; p < 3; ++p)
#pragma unroll
        for (int ct = 0; ct < 4; ++ct) acc[p][ct] = (f32x4){0.f, 0.f, 0.f, 0.f};

    int arow = nb + l15;
    const ushort* xrow = XB + (size_t)(arow < n ? arow : 0) * (KT * 32) + lhi * 8;
    const ushort* wpL = WP + (lane << 3);

#pragma unroll
    for (int kt = 0; kt < KT; ++kt) {
        short8 a = *(const short8*)(xrow + kt * 32);
#pragma unroll
        for (int p = 0; p < 3; ++p)
#pragma unroll
            for (int ct = 0; ct < 4; ++ct) {
                short8 b = *(const short8*)(wpL + (((size_t)(p * KT + kt) * 4 + ct) << 9));
                acc[p][ct] = __builtin_amdgcn_mfma_f32_16x16x32_bf16(a, b, acc[p][ct], 0, 0, 0);
            }
    }

    // C/D layout: col = lane&15, row = (lane>>4)*4 + reg
    float dv[4];
#pragma unroll
    for (int j = 0; j < 4; ++j) {
        int node = nb + lhi * 4 + j;
        dv[j] = (node < n) ? dinv[node] : 0.f;
    }
#pragma unroll
    for (int ct = 0; ct < 4; ++ct) {
        int col = ct * 16 + l15;
        if (col >= 60) continue;
        float bias = b0[col];
#pragma unroll
        for (int j = 0; j < 4; ++j) {
            int node = nb + lhi * 4 + j;
            if (node >= n) continue;
            Y0[(size_t)node * 60 + col] = f2bf(acc[0][ct][j] + bias);
            uint pk = ((uint)f2bf(dv[j] * acc[2][ct][j]) << 16) |
                      (uint)f2bf(dv[j] * acc[1][ct][j]);
            *(uint*)(Y12 + (size_t)node * 120 + 2 * col) = pk;
        }
    }
}

// ---------------- propA: hop over pre-scaled Y12 (bf16 interleaved)
// Z1 = dinv*sum1 + b1 (bf16, final power-1); ZQ = dinv^2*sum2 (bf16, for hop 2)
__global__ __launch_bounds__(256) void k_propA(
        const ushort* __restrict__ Y12, ushort* __restrict__ Z1, ushort* __restrict__ ZQ,
        const float* __restrict__ b1,
        const float* __restrict__ dinv, const int* __restrict__ rp,
        const int* __restrict__ es, int n) {
    int node = blockIdx.x * 4 + (threadIdx.x >> 6);
    int lane = threadIdx.x & 63;
    if (node >= n || lane >= 60) return;
    uint sv = *(const uint*)(Y12 + (size_t)node * 120 + 2 * lane);
    float a1 = bf_lo(sv);
    float a2 = bf_hi(sv);
    int e0 = rp[node], e1 = rp[node + 1];
    int e = e0;
    for (; e + 7 < e1; e += 8) {
        int s0 = es[e], s1 = es[e + 1], s2 = es[e + 2], s3 = es[e + 3];
        int s4 = es[e + 4], s5 = es[e + 5], s6 = es[e + 6], s7 = es[e + 7];
        uint v0 = *(const uint*)(Y12 + (size_t)s0 * 120 + 2 * lane);
        uint v1 = *(const uint*)(Y12 + (size_t)s1 * 120 + 2 * lane);
        uint v2 = *(const uint*)(Y12 + (size_t)s2 * 120 + 2 * lane);
        uint v3 = *(const uint*)(Y12 + (size_t)s3 * 120 + 2 * lane);
        uint v4 = *(const uint*)(Y12 + (size_t)s4 * 120 + 2 * lane);
        uint v5 = *(const uint*)(Y12 + (size_t)s5 * 120 + 2 * lane);
        uint v6 = *(const uint*)(Y12 + (size_t)s6 * 120 + 2 * lane);
        uint v7 = *(const uint*)(Y12 + (size_t)s7 * 120 + 2 * lane);
        a1 += ((bf_lo(v0) + bf_lo(v1)) + (bf_lo(v2) + bf_lo(v3))) +
              ((bf_lo(v4) + bf_lo(v5)) + (bf_lo(v6) + bf_lo(v7)));
        a2 += ((bf_hi(v0) + bf_hi(v1)) + (bf_hi(v2) + bf_hi(v3))) +
              ((bf_hi(v4) + bf_hi(v5)) + (bf_hi(v6) + bf_hi(v7)));
    }
    for (; e < e1; ++e) {
        uint v = *(const uint*)(Y12 + (size_t)es[e] * 120 + 2 * lane);
        a1 += bf_lo(v);
        a2 += bf_hi(v);
    }
    float di = dinv[node];
    Z1[(size_t)node * 60 + lane] = f2bf(di * a1 + b1[lane]);
    ZQ[(size_t)node * 60 + lane] = f2bf(di * di * a2);
}

// ---------------- propB: hop over pre-scaled ZQ -> Q2 bf16 (+b2)
__global__ __launch_bounds__(256) void k_propB(
        const ushort* __restrict__ ZQ, ushort* __restrict__ Q2,
        const float* __restrict__ b2,
        const float* __restrict__ dinv, const int* __restrict__ rp,
        const int* __restrict__ es, int n) {
    int node = blockIdx.x * 4 + (threadIdx.x >> 6);
    int lane = threadIdx.x & 63;
    if (node >= n || lane >= 60) return;
    float acc = bf2f(ZQ[(size_t)node * 60 + lane]);
    int e0 = rp[node], e1 = rp[node + 1];
    int e = e0;
    for (; e + 7 < e1; e += 8) {
        int s0 = es[e], s1 = es[e + 1], s2 = es[e + 2], s3 = es[e + 3];
        int s4 = es[e + 4], s5 = es[e + 5], s6 = es[e + 6], s7 = es[e + 7];
        float x0 = bf2f(ZQ[(size_t)s0 * 60 + lane]);
        float x1 = bf2f(ZQ[(size_t)s1 * 60 + lane]);
        float x2 = bf2f(ZQ[(size_t)s2 * 60 + lane]);
        float x3 = bf2f(ZQ[(size_t)s3 * 60 + lane]);
        float x4 = bf2f(ZQ[(size_t)s4 * 60 + lane]);
        float x5 = bf2f(ZQ[(size_t)s5 * 60 + lane]);
        float x6 = bf2f(ZQ[(size_t)s6 * 60 + lane]);
        float x7 = bf2f(ZQ[(size_t)s7 * 60 + lane]);
        acc += ((x0 + x1) + (x2 + x3)) + ((x4 + x5) + (x6 + x7));
    }
    for (; e < e1; ++e) {
        acc += bf2f(ZQ[(size_t)es[e] * 60 + lane]);
    }
    Q2[(size_t)node * 60 + lane] = f2bf(dinv[node] * acc + b2[lane]);
}

// ---------------- BN stats (bf16 inputs, fp32 sums)
__global__ __launch_bounds__(192) void k_bnstats(
        const ushort* __restrict__ Y0, const ushort* __restrict__ Z1,
        const ushort* __restrict__ Q2,
        float* __restrict__ gsum, float* __restrict__ gsum2,
        int n, int rows_per) {
    int t = threadIdx.x;
    if (t >= CAT) return;
    int reg = t / 60, col = t - reg * 60;
    const ushort* src = ((reg == 0) ? Y0 : ((reg == 1) ? Z1 : Q2)) + col;
    int r0 = blockIdx.x * rows_per;
    int r1 = r0 + rows_per; if (r1 > n) r1 = n;
    float s1 = 0.f, s2 = 0.f;
    for (int r = r0; r < r1; ++r) {
        float v = bf2f(src[(size_t)r * 60]);
        s1 += v;
        s2 += v * v;
    }
    atomicAdd(&gsum[t], s1);
    atomicAdd(&gsum2[t], s2);
}

// ---------------- BN apply (inline finalize) -> CB (N x 192 bf16, zero-padded)
__global__ __launch_bounds__(256) void k_bnapply(
        const ushort* __restrict__ Y0, const ushort* __restrict__ Z1,
        const ushort* __restrict__ Q2,
        const float* __restrict__ gsum, const float* __restrict__ gsum2,
        const float* __restrict__ g, const float* __restrict__ b,
        ushort* __restrict__ CB, int n, size_t total) {  // total = n*48
    __shared__ float ssc[CAT], ssh[CAT];
    int tt = threadIdx.x;
    if (tt < CAT) {
        float mu = gsum[tt] / (float)n;
        float var = gsum2[tt] / (float)n - mu * mu;
        float sc = rsqrtf(var + BN_EPS) * g[tt];
        ssc[tt] = sc;
        ssh[tt] = b[tt] - mu * sc;
    }
    __syncthreads();
    size_t stride = (size_t)gridDim.x * blockDim.x;
    for (size_t i = (size_t)blockIdx.x * blockDim.x + tt; i < total; i += stride) {
        size_t node = i / 48;
        int c0 = (int)(i % 48) * 4;
        ushort4 o;
        if (c0 >= CAT) {
            o.x = 0; o.y = 0; o.z = 0; o.w = 0;
        } else {
            const ushort* sp;
            if (c0 < 60) sp = Y0 + node * 60 + c0;
            else if (c0 < 120) sp = Z1 + node * 60 + (c0 - 60);
            else sp = Q2 + node * 60 + (c0 - 120);
            uint u0 = *(const uint*)sp;
            uint u1 = *(const uint*)(sp + 2);
            o.x = f2bf(bf_lo(u0) * ssc[c0 + 0] + ssh[c0 + 0]);
            o.y = f2bf(bf_hi(u0) * ssc[c0 + 1] + ssh[c0 + 1]);
            o.z = f2bf(bf_lo(u1) * ssc[c0 + 2] + ssh[c0 + 2]);
            o.w = f2bf(bf_hi(u1) * ssc[c0 + 3] + ssh[c0 + 3]);
        }
        *(ushort4*)(CB + node * 192 + c0) = o;
    }
}

// ---------------- final linear with fused BN (layer 3): out = BN(h) @ w + b
__global__ __launch_bounds__(256) void k_final_fused(
        const ushort* __restrict__ Y0, const ushort* __restrict__ Z1,
        const ushort* __restrict__ Q2,
        const float* __restrict__ gsum, const float* __restrict__ gsum2,
        const float* __restrict__ g, const float* __restrict__ bb,
        const float* __restrict__ w, const float* __restrict__ wb,
        float* __restrict__ out, int n) {
    __shared__ float sw[CAT * NCLS];
    __shared__ float ssc[CAT], ssh[CAT];
    __shared__ float sb[NCLS];
    int t = threadIdx.x;
    for (int i = t; i < CAT * NCLS; i += 256) sw[i] = w[i];
    if (t < CAT) {
        float mu = gsum[t] / (float)n;
        float var = gsum2[t] / (float)n - mu * mu;
        float sc = rsqrtf(var + BN_EPS) * g[t];
        ssc[t] = sc;
        ssh[t] = bb[t] - mu * sc;
    }
    if (t < NCLS) sb[t] = wb[t];
    __syncthreads();
    int node = blockIdx.x * 256 + t;
    if (node >= n) return;
    float acc[NCLS];
#pragma unroll
    for (int j = 0; j < NCLS; ++j) acc[j] = sb[j];
    const ushort* bufs[3] = {Y0, Z1, Q2};
#pragma unroll
    for (int rgn = 0; rgn < 3; ++rgn) {
        const ushort* sp = bufs[rgn] + (size_t)node * 60;
        int cb = rgn * 60;
#pragma unroll 6
        for (int k2 = 0; k2 < 30; ++k2) {
            uint u = *(const uint*)(sp + 2 * k2);
            int c = cb + 2 * k2;
            float f0 = bf_lo(u) * ssc[c] + ssh[c];
            float f1 = bf_hi(u) * ssc[c + 1] + ssh[c + 1];
#pragma unroll
            for (int j = 0; j < NCLS; ++j)
                acc[j] += f0 * sw[c * NCLS + j] + f1 * sw[(c + 1) * NCLS + j];
        }
    }
#pragma unroll
    for (int j = 0; j < NCLS; ++j) out[(size_t)node * NCLS + j] = acc[j];
}

extern "C" void kernel_launch(void* const* d_in, const int* in_sizes, int n_in,
                              void* d_out, int out_size, void* d_ws, size_t ws_size,
                              hipStream_t stream) {
    const float* x = (const float*)d_in[0];
    const int* ei = (const int*)d_in[1];
    const int* esrc = ei;
    const int* edst = ei + NE;

    const float* c_w[3][3];
    const float* c_b[3][3];
    for (int p = 0; p < 3; ++p)
        for (int l = 0; l < 3; ++l) {
            c_w[l][p] = (const float*)d_in[2 + p * 6 + l * 2];
            c_b[l][p] = (const float*)d_in[3 + p * 6 + l * 2];
        }
    const float* bn_g[3] = {(const float*)d_in[20], (const float*)d_in[22], (const float*)d_in[24]};
    const float* bn_b[3] = {(const float*)d_in[21], (const float*)d_in[23], (const float*)d_in[25]};
    const float* lw = (const float*)d_in[26];
    const float* lb = (const float*)d_in[27];
    float* out = (float*)d_out;

    char* wp = (char*)d_ws;
    auto alloc = [&](size_t bytes) {
        char* p = wp;
        wp += (bytes + 255) & ~(size_t)255;
        return p;
    };
    int* gcur = (int*)alloc((size_t)NBUCK * 4);
    int* bbase = (int*)alloc((size_t)(NBUCK + 1) * 4);
    int* bcnt = (int*)alloc((size_t)NBUCK * 4);
    int2* ebuf = (int2*)alloc((size_t)NBUCK * BCAP * 8);
    int* row_ptr = (int*)alloc((size_t)(NN + 1) * 4);
    int* ssrc = (int*)alloc((size_t)NE * 4);
    float* dinv = (float*)alloc((size_t)NN * 4);
    float* gsum = (float*)alloc((size_t)2 * CAT * 4);
    float* gsum2 = gsum + CAT;
    ushort* Y0 = (ushort*)alloc((size_t)NN * 60 * 2);
    ushort* Y12 = (ushort*)alloc((size_t)NN * 120 * 2);
    ushort* Z1 = (ushort*)alloc((size_t)NN * 60 * 2);
    ushort* ZQ = (ushort*)alloc((size_t)NN * 60 * 2);
    ushort* Q2 = (ushort*)alloc((size_t)NN * 60 * 2);
    ushort* XB1 = (ushort*)alloc((size_t)NN * 128 * 2);
    ushort* CB = (ushort*)alloc((size_t)NN * 192 * 2);
    ushort* WP1 = (ushort*)alloc((size_t)3 * 4 * 4 * 512 * 2);
    ushort* WP2 = (ushort*)alloc((size_t)3 * 6 * 4 * 512 * 2);
    ushort* WP3 = (ushort*)alloc((size_t)3 * 6 * 4 * 512 * 2);

    // ---- CSR build (write-combined bucketed sort) ----
    k_initcur<<<1, 256, 0, stream>>>(gcur);
    k_bin<<<391, 256, 0, stream>>>(esrc, edst, gcur, ebuf, NE);
    k_bscan<<<1, 256, 0, stream>>>(gcur, bbase, bcnt, row_ptr);
    k_bucket_csr<<<NBUCK, 256, 0, stream>>>(ebuf, bbase, bcnt, row_ptr, dinv, ssrc, NN);

    // ---- prep: x cast + weight packs ----
    k_cast<<<2048, 256, 0, stream>>>(x, XB1, (size_t)NN * 128 / 4);
    k_wpack<<<dim3(16, 3), 64, 0, stream>>>(c_w[0][0], c_w[0][1], c_w[0][2], WP1, FIN0, 4);
    k_wpack<<<dim3(24, 3), 64, 0, stream>>>(c_w[1][0], c_w[1][1], c_w[1][2], WP2, CAT, 6);
    k_wpack<<<dim3(24, 3), 64, 0, stream>>>(c_w[2][0], c_w[2][1], c_w[2][2], WP3, CAT, 6);

    const int gemm_gx = (NN + 63) / 64;
    const int prop_gx = (NN + 3) / 4;
    const int stats_blocks = 500;
    const int rows_per = (NN + stats_blocks - 1) / stats_blocks;
    const size_t bn_total = (size_t)NN * 48;

    for (int l = 0; l < 3; ++l) {
        if (l == 0) {
            k_gemm_mfma<4><<<gemm_gx, 256, 0, stream>>>(XB1, WP1, c_b[0][0], dinv, Y0, Y12, NN);
        } else {
            const ushort* WPl = (l == 1) ? WP2 : WP3;
            k_gemm_mfma<6><<<gemm_gx, 256, 0, stream>>>(CB, WPl, c_b[l][0], dinv, Y0, Y12, NN);
        }
        k_propA<<<prop_gx, 256, 0, stream>>>(Y12, Z1, ZQ, c_b[l][1], dinv, row_ptr, ssrc, NN);
        k_propB<<<prop_gx, 256, 0, stream>>>(ZQ, Q2, c_b[l][2], dinv, row_ptr, ssrc, NN);
        hipMemsetAsync(gsum, 0, (size_t)2 * CAT * 4, stream);
        k_bnstats<<<stats_blocks, 192, 0, stream>>>(Y0, Z1, Q2, gsum, gsum2, NN, rows_per);
        if (l < 2) {
            k_bnapply<<<2048, 256, 0, stream>>>(Y0, Z1, Q2, gsum, gsum2, bn_g[l], bn_b[l],
                                                CB, NN, bn_total);
        } else {
            k_final_fused<<<(NN + 255) / 256, 256, 0, stream>>>(
                Y0, Z1, Q2, gsum, gsum2, bn_g[2], bn_b[2], lw, lb, out, NN);
        }
    }
}

// Round 7
// 398.092 us; speedup vs baseline: 4.6174x; 1.2320x over previous
//
#include <hip/hip_runtime.h>
#include <hip/hip_bf16.h>

#define NN 50000
#define NE 800000
#define FIN0 128
#define HID 60
#define CAT 180
#define NCLS 7
#define BN_EPS 1e-5f
#define NBUCK 196      // ceil(NN/256)
#define BCAP 5120      // max edges per 256-node bucket (mean 4096, sigma 64)

typedef unsigned int uint;
typedef unsigned short ushort;
typedef __attribute__((ext_vector_type(8))) short short8;
typedef __attribute__((ext_vector_type(4))) float f32x4;

__device__ __forceinline__ ushort f2bf(float f) {
    uint u = __float_as_uint(f);
    u += 0x7FFFu + ((u >> 16) & 1u);
    return (ushort)(u >> 16);
}
__device__ __forceinline__ float bf_lo(uint v) { return __uint_as_float(v << 16); }
__device__ __forceinline__ float bf_hi(uint v) { return __uint_as_float(v & 0xFFFF0000u); }
__device__ __forceinline__ float bf2f(ushort u) { return __uint_as_float(((uint)u) << 16); }

// ---------------- CSR build: bucketed, write-combined ----------------

__global__ void k_initcur(int* __restrict__ gcur) {
    int t = threadIdx.x;
    if (t < NBUCK) gcur[t] = t * BCAP;
}

__global__ __launch_bounds__(256) void k_bin(const int* __restrict__ src,
                                             const int* __restrict__ dst,
                                             int* __restrict__ gcur,
                                             int2* __restrict__ ebuf, int e) {
    __shared__ int cnt[NBUCK];
    __shared__ int base[NBUCK];
    int t = threadIdx.x;
    for (int c0 = blockIdx.x * 2048; c0 < e; c0 += gridDim.x * 2048) {
        if (t < NBUCK) cnt[t] = 0;
        __syncthreads();
        int sv[8], dv[8], rk[8], bk[8], ok[8];
#pragma unroll
        for (int j = 0; j < 8; ++j) {
            int i = c0 + j * 256 + t;
            ok[j] = i < e;
            if (ok[j]) {
                sv[j] = src[i];
                dv[j] = dst[i];
                bk[j] = dv[j] >> 8;
                rk[j] = atomicAdd(&cnt[bk[j]], 1);
            }
        }
        __syncthreads();
        if (t < NBUCK && cnt[t] > 0) base[t] = atomicAdd(&gcur[t], cnt[t]);
        __syncthreads();
#pragma unroll
        for (int j = 0; j < 8; ++j) {
            if (ok[j]) {
                int2 v; v.x = sv[j]; v.y = dv[j];
                ebuf[base[bk[j]] + rk[j]] = v;
            }
        }
        __syncthreads();
    }
}

__global__ void k_bscan(const int* __restrict__ gcur, int* __restrict__ bbase,
                        int* __restrict__ bcnt, int* __restrict__ row_ptr) {
    __shared__ int s[256];
    int t = threadIdx.x;
    int c = (t < NBUCK) ? (gcur[t] - t * BCAP) : 0;
    s[t] = c;
    __syncthreads();
    for (int off = 1; off < 256; off <<= 1) {
        int v = (t >= off) ? s[t - off] : 0;
        __syncthreads();
        s[t] += v;
        __syncthreads();
    }
    if (t < NBUCK) { bbase[t] = s[t] - c; bcnt[t] = c; }
    if (t == 0) row_ptr[NN] = NE;
}

__global__ __launch_bounds__(256) void k_bucket_csr(
        const int2* __restrict__ ebuf, const int* __restrict__ bbase,
        const int* __restrict__ bcnt,
        int* __restrict__ row_ptr, float* __restrict__ dinv,
        int* __restrict__ ssrc, int n) {
    __shared__ int ncnt[256];
    __shared__ int loff[256];
    int b = blockIdx.x, t = threadIdx.x;
    int cnt = bcnt[b];
    int gbase = bbase[b];
    const int2* ee = ebuf + (size_t)b * BCAP;
    ncnt[t] = 0;
    __syncthreads();
    for (int i = t; i < cnt; i += 256) atomicAdd(&ncnt[ee[i].y & 255], 1);
    __syncthreads();
    int c = ncnt[t];
    loff[t] = c;
    __syncthreads();
    for (int off = 1; off < 256; off <<= 1) {
        int v = (t >= off) ? loff[t - off] : 0;
        __syncthreads();
        loff[t] += v;
        __syncthreads();
    }
    int excl = loff[t] - c;
    int node = b * 256 + t;
    if (node < n) {
        row_ptr[node] = gbase + excl;
        dinv[node] = rsqrtf((float)(c + 1));  // +1 self loop
    }
    __syncthreads();
    ncnt[t] = excl;  // reuse as cursor
    __syncthreads();
    for (int i = t; i < cnt; i += 256) {
        int2 ed = ee[i];
        int pos = atomicAdd(&ncnt[ed.y & 255], 1);
        ssrc[gbase + pos] = ed.x;
    }
}

// ---------------- x -> bf16 cast ----------------
__global__ __launch_bounds__(256) void k_cast(const float* __restrict__ x,
                                              ushort* __restrict__ xb, size_t total4) {
    size_t stride = (size_t)gridDim.x * blockDim.x;
    for (size_t i = (size_t)blockIdx.x * blockDim.x + threadIdx.x; i < total4; i += stride) {
        float4 v = *(const float4*)(x + i * 4);
        ushort4 o;
        o.x = f2bf(v.x); o.y = f2bf(v.y); o.z = f2bf(v.z); o.w = f2bf(v.w);
        *(ushort4*)(xb + i * 4) = o;
    }
}

// ---------------- weight pack into MFMA B-fragment order ----------------
__global__ void k_wpack(const float* __restrict__ w0, const float* __restrict__ w1,
                        const float* __restrict__ w2, ushort* __restrict__ WP,
                        int K_real, int KT) {
    int p = blockIdx.y;
    int kt = blockIdx.x >> 2;
    int ct = blockIdx.x & 3;
    const float* __restrict__ W = (p == 0) ? w0 : ((p == 1) ? w1 : w2);
    int lane = threadIdx.x;  // 0..63
    int k0 = kt * 32 + (lane >> 4) * 8;
    int c = ct * 16 + (lane & 15);
    ushort* dst = WP + (((size_t)(p * KT + kt) * 4 + ct) << 9) + (lane << 3);
    ushort4 o0, o1;
    float v;
#define WVAL(J) ((k0 + (J)) < K_real && c < 60) ? W[(size_t)(k0 + (J)) * 60 + c] : 0.f
    v = WVAL(0); o0.x = f2bf(v);
    v = WVAL(1); o0.y = f2bf(v);
    v = WVAL(2); o0.z = f2bf(v);
    v = WVAL(3); o0.w = f2bf(v);
    v = WVAL(4); o1.x = f2bf(v);
    v = WVAL(5); o1.y = f2bf(v);
    v = WVAL(6); o1.z = f2bf(v);
    v = WVAL(7); o1.w = f2bf(v);
#undef WVAL
    *(ushort4*)dst = o0;
    *(ushort4*)(dst + 4) = o1;
}

// ---------------- MFMA GEMM, all 3 powers in one block (shared A-frags)
// Y0 bf16 stride 64 (+b0); Y12 bf16 stride 128, interleaved p1/p2, pre-scaled by dinv
template <int KT>
__global__ __launch_bounds__(256) void k_gemm_mfma(
        const ushort* __restrict__ XB,   // N x (KT*32) bf16
        const ushort* __restrict__ WP,   // packed [3][KT][4][64][8]
        const float* __restrict__ b0,
        const float* __restrict__ dinv,
        ushort* __restrict__ Y0,
        ushort* __restrict__ Y12,
        int n) {
    const int t = threadIdx.x;
    const int wv = t >> 6;
    const int lane = t & 63;
    const int l15 = lane & 15;
    const int lhi = lane >> 4;
    const int nb = blockIdx.x * 64 + wv * 16;

    f32x4 acc[3][4];
#pragma unroll
    for (int p = 0; p < 3; ++p)
#pragma unroll
        for (int ct = 0; ct < 4; ++ct) acc[p][ct] = (f32x4){0.f, 0.f, 0.f, 0.f};

    int arow = nb + l15;
    const ushort* xrow = XB + (size_t)(arow < n ? arow : 0) * (KT * 32) + lhi * 8;
    const ushort* wpL = WP + (lane << 3);

#pragma unroll
    for (int kt = 0; kt < KT; ++kt) {
        short8 a = *(const short8*)(xrow + kt * 32);
#pragma unroll
        for (int p = 0; p < 3; ++p)
#pragma unroll
            for (int ct = 0; ct < 4; ++ct) {
                short8 b = *(const short8*)(wpL + (((size_t)(p * KT + kt) * 4 + ct) << 9));
                acc[p][ct] = __builtin_amdgcn_mfma_f32_16x16x32_bf16(a, b, acc[p][ct], 0, 0, 0);
            }
    }

    // C/D layout: col = lane&15, row = (lane>>4)*4 + reg
    float dv[4];
#pragma unroll
    for (int j = 0; j < 4; ++j) {
        int node = nb + lhi * 4 + j;
        dv[j] = (node < n) ? dinv[node] : 0.f;
    }
#pragma unroll
    for (int ct = 0; ct < 4; ++ct) {
        int col = ct * 16 + l15;
        if (col >= 60) continue;
        float bias = b0[col];
#pragma unroll
        for (int j = 0; j < 4; ++j) {
            int node = nb + lhi * 4 + j;
            if (node >= n) continue;
            Y0[(size_t)node * 64 + col] = f2bf(acc[0][ct][j] + bias);
            uint pk = ((uint)f2bf(dv[j] * acc[2][ct][j]) << 16) |
                      (uint)f2bf(dv[j] * acc[1][ct][j]);
            *(uint*)(Y12 + (size_t)node * 128 + 2 * col) = pk;
        }
    }
}

// ---------------- propA: hop over pre-scaled Y12 (bf16 interleaved, stride 128)
// Z1 = dinv*sum1 + b1 (bf16 s64); ZQ = dinv^2*sum2 (bf16 s64, for hop 2)
__global__ __launch_bounds__(256) void k_propA(
        const ushort* __restrict__ Y12, ushort* __restrict__ Z1, ushort* __restrict__ ZQ,
        const float* __restrict__ b1,
        const float* __restrict__ dinv, const int* __restrict__ rp,
        const int* __restrict__ es, int n) {
    int node = blockIdx.x * 4 + (threadIdx.x >> 6);
    int lane = threadIdx.x & 63;
    if (node >= n || lane >= 60) return;
    uint sv = *(const uint*)(Y12 + (size_t)node * 128 + 2 * lane);
    float a1 = bf_lo(sv);
    float a2 = bf_hi(sv);
    int e0 = rp[node], e1 = rp[node + 1];
    int e = e0;
    for (; e + 7 < e1; e += 8) {
        int s0 = es[e], s1 = es[e + 1], s2 = es[e + 2], s3 = es[e + 3];
        int s4 = es[e + 4], s5 = es[e + 5], s6 = es[e + 6], s7 = es[e + 7];
        uint v0 = *(const uint*)(Y12 + (size_t)s0 * 128 + 2 * lane);
        uint v1 = *(const uint*)(Y12 + (size_t)s1 * 128 + 2 * lane);
        uint v2 = *(const uint*)(Y12 + (size_t)s2 * 128 + 2 * lane);
        uint v3 = *(const uint*)(Y12 + (size_t)s3 * 128 + 2 * lane);
        uint v4 = *(const uint*)(Y12 + (size_t)s4 * 128 + 2 * lane);
        uint v5 = *(const uint*)(Y12 + (size_t)s5 * 128 + 2 * lane);
        uint v6 = *(const uint*)(Y12 + (size_t)s6 * 128 + 2 * lane);
        uint v7 = *(const uint*)(Y12 + (size_t)s7 * 128 + 2 * lane);
        a1 += ((bf_lo(v0) + bf_lo(v1)) + (bf_lo(v2) + bf_lo(v3))) +
              ((bf_lo(v4) + bf_lo(v5)) + (bf_lo(v6) + bf_lo(v7)));
        a2 += ((bf_hi(v0) + bf_hi(v1)) + (bf_hi(v2) + bf_hi(v3))) +
              ((bf_hi(v4) + bf_hi(v5)) + (bf_hi(v6) + bf_hi(v7)));
    }
    for (; e < e1; ++e) {
        uint v = *(const uint*)(Y12 + (size_t)es[e] * 128 + 2 * lane);
        a1 += bf_lo(v);
        a2 += bf_hi(v);
    }
    float di = dinv[node];
    Z1[(size_t)node * 64 + lane] = f2bf(di * a1 + b1[lane]);
    ZQ[(size_t)node * 64 + lane] = f2bf(di * di * a2);
}

// ---------------- propB: hop over pre-scaled ZQ (s64) -> Q2 bf16 s64 (+b2)
__global__ __launch_bounds__(256) void k_propB(
        const ushort* __restrict__ ZQ, ushort* __restrict__ Q2,
        const float* __restrict__ b2,
        const float* __restrict__ dinv, const int* __restrict__ rp,
        const int* __restrict__ es, int n) {
    int node = blockIdx.x * 4 + (threadIdx.x >> 6);
    int lane = threadIdx.x & 63;
    if (node >= n || lane >= 60) return;
    float acc = bf2f(ZQ[(size_t)node * 64 + lane]);
    int e0 = rp[node], e1 = rp[node + 1];
    int e = e0;
    for (; e + 7 < e1; e += 8) {
        int s0 = es[e], s1 = es[e + 1], s2 = es[e + 2], s3 = es[e + 3];
        int s4 = es[e + 4], s5 = es[e + 5], s6 = es[e + 6], s7 = es[e + 7];
        float x0 = bf2f(ZQ[(size_t)s0 * 64 + lane]);
        float x1 = bf2f(ZQ[(size_t)s1 * 64 + lane]);
        float x2 = bf2f(ZQ[(size_t)s2 * 64 + lane]);
        float x3 = bf2f(ZQ[(size_t)s3 * 64 + lane]);
        float x4 = bf2f(ZQ[(size_t)s4 * 64 + lane]);
        float x5 = bf2f(ZQ[(size_t)s5 * 64 + lane]);
        float x6 = bf2f(ZQ[(size_t)s6 * 64 + lane]);
        float x7 = bf2f(ZQ[(size_t)s7 * 64 + lane]);
        acc += ((x0 + x1) + (x2 + x3)) + ((x4 + x5) + (x6 + x7));
    }
    for (; e < e1; ++e) {
        acc += bf2f(ZQ[(size_t)es[e] * 64 + lane]);
    }
    Q2[(size_t)node * 64 + lane] = f2bf(dinv[node] * acc + b2[lane]);
}

// ---------------- BN stats: coalesced uint4 reads, shfl+LDS reduce, few atomics
__global__ __launch_bounds__(256) void k_bnstats(
        const ushort* __restrict__ Y0, const ushort* __restrict__ Z1,
        const ushort* __restrict__ Q2,
        float* __restrict__ gsum, float* __restrict__ gsum2, int n) {
    int rgn = blockIdx.y;
    const ushort* __restrict__ src = (rgn == 0) ? Y0 : ((rgn == 1) ? Z1 : Q2);
    int t = threadIdx.x;
    int c8 = (t & 7) * 8;   // 8-col group base
    int rsub = t >> 3;      // 0..31
    float s1[8], s2[8];
#pragma unroll
    for (int j = 0; j < 8; ++j) { s1[j] = 0.f; s2[j] = 0.f; }
    for (int r = blockIdx.x * 32 + rsub; r < n; r += gridDim.x * 32) {
        uint4 v = *(const uint4*)(src + (size_t)r * 64 + c8);
        float f;
        f = bf_lo(v.x); s1[0] += f; s2[0] += f * f;
        f = bf_hi(v.x); s1[1] += f; s2[1] += f * f;
        f = bf_lo(v.y); s1[2] += f; s2[2] += f * f;
        f = bf_hi(v.y); s1[3] += f; s2[3] += f * f;
        f = bf_lo(v.z); s1[4] += f; s2[4] += f * f;
        f = bf_hi(v.z); s1[5] += f; s2[5] += f * f;
        f = bf_lo(v.w); s1[6] += f; s2[6] += f * f;
        f = bf_hi(v.w); s1[7] += f; s2[7] += f * f;
    }
    // reduce across lanes sharing (lane&7): xor masks 8,16,32
#pragma unroll
    for (int m = 8; m < 64; m <<= 1) {
#pragma unroll
        for (int j = 0; j < 8; ++j) {
            s1[j] += __shfl_xor(s1[j], m);
            s2[j] += __shfl_xor(s2[j], m);
        }
    }
    __shared__ float ls1[4][64], ls2[4][64];
    int wv = t >> 6, lane = t & 63;
    if (lane < 8) {
#pragma unroll
        for (int j = 0; j < 8; ++j) {
            ls1[wv][lane * 8 + j] = s1[j];
            ls2[wv][lane * 8 + j] = s2[j];
        }
    }
    __syncthreads();
    if (t < 64 && t < 60) {
        float a1 = ls1[0][t] + ls1[1][t] + ls1[2][t] + ls1[3][t];
        float a2 = ls2[0][t] + ls2[1][t] + ls2[2][t] + ls2[3][t];
        atomicAdd(&gsum[rgn * 60 + t], a1);
        atomicAdd(&gsum2[rgn * 60 + t], a2);
    }
}

// ---------------- BN apply (inline finalize) -> CB (N x 192 bf16, zero-padded)
__global__ __launch_bounds__(256) void k_bnapply(
        const ushort* __restrict__ Y0, const ushort* __restrict__ Z1,
        const ushort* __restrict__ Q2,
        const float* __restrict__ gsum, const float* __restrict__ gsum2,
        const float* __restrict__ g, const float* __restrict__ b,
        ushort* __restrict__ CB, int n, size_t total) {  // total = n*48
    __shared__ float ssc[CAT], ssh[CAT];
    int tt = threadIdx.x;
    if (tt < CAT) {
        float mu = gsum[tt] / (float)n;
        float var = gsum2[tt] / (float)n - mu * mu;
        float sc = rsqrtf(var + BN_EPS) * g[tt];
        ssc[tt] = sc;
        ssh[tt] = b[tt] - mu * sc;
    }
    __syncthreads();
    size_t stride = (size_t)gridDim.x * blockDim.x;
    for (size_t i = (size_t)blockIdx.x * blockDim.x + tt; i < total; i += stride) {
        size_t node = i / 48;
        int c0 = (int)(i % 48) * 4;
        ushort4 o;
        if (c0 >= CAT) {
            o.x = 0; o.y = 0; o.z = 0; o.w = 0;
        } else {
            const ushort* sp;
            if (c0 < 60) sp = Y0 + node * 64 + c0;
            else if (c0 < 120) sp = Z1 + node * 64 + (c0 - 60);
            else sp = Q2 + node * 64 + (c0 - 120);
            uint u0 = *(const uint*)sp;
            uint u1 = *(const uint*)(sp + 2);
            o.x = f2bf(bf_lo(u0) * ssc[c0 + 0] + ssh[c0 + 0]);
            o.y = f2bf(bf_hi(u0) * ssc[c0 + 1] + ssh[c0 + 1]);
            o.z = f2bf(bf_lo(u1) * ssc[c0 + 2] + ssh[c0 + 2]);
            o.w = f2bf(bf_hi(u1) * ssc[c0 + 3] + ssh[c0 + 3]);
        }
        *(ushort4*)(CB + node * 192 + c0) = o;
    }
}

// ---------------- final linear with fused BN (layer 3): out = BN(h) @ w + b
__global__ __launch_bounds__(256) void k_final_fused(
        const ushort* __restrict__ Y0, const ushort* __restrict__ Z1,
        const ushort* __restrict__ Q2,
        const float* __restrict__ gsum, const float* __restrict__ gsum2,
        const float* __restrict__ g, const float* __restrict__ bb,
        const float* __restrict__ w, const float* __restrict__ wb,
        float* __restrict__ out, int n) {
    __shared__ float sw[CAT * NCLS];
    __shared__ float ssc[CAT], ssh[CAT];
    __shared__ float sb[NCLS];
    int t = threadIdx.x;
    for (int i = t; i < CAT * NCLS; i += 256) sw[i] = w[i];
    if (t < CAT) {
        float mu = gsum[t] / (float)n;
        float var = gsum2[t] / (float)n - mu * mu;
        float sc = rsqrtf(var + BN_EPS) * g[t];
        ssc[t] = sc;
        ssh[t] = bb[t] - mu * sc;
    }
    if (t < NCLS) sb[t] = wb[t];
    __syncthreads();
    int node = blockIdx.x * 256 + t;
    if (node >= n) return;
    float acc[NCLS];
#pragma unroll
    for (int j = 0; j < NCLS; ++j) acc[j] = sb[j];
    const ushort* bufs[3] = {Y0, Z1, Q2};
#pragma unroll
    for (int rgn = 0; rgn < 3; ++rgn) {
        const ushort* sp = bufs[rgn] + (size_t)node * 64;
        int cb = rgn * 60;
#pragma unroll 6
        for (int k2 = 0; k2 < 30; ++k2) {
            uint u = *(const uint*)(sp + 2 * k2);
            int c = cb + 2 * k2;
            float f0 = bf_lo(u) * ssc[c] + ssh[c];
            float f1 = bf_hi(u) * ssc[c + 1] + ssh[c + 1];
#pragma unroll
            for (int j = 0; j < NCLS; ++j)
                acc[j] += f0 * sw[c * NCLS + j] + f1 * sw[(c + 1) * NCLS + j];
        }
    }
#pragma unroll
    for (int j = 0; j < NCLS; ++j) out[(size_t)node * NCLS + j] = acc[j];
}

extern "C" void kernel_launch(void* const* d_in, const int* in_sizes, int n_in,
                              void* d_out, int out_size, void* d_ws, size_t ws_size,
                              hipStream_t stream) {
    const float* x = (const float*)d_in[0];
    const int* ei = (const int*)d_in[1];
    const int* esrc = ei;
    const int* edst = ei + NE;

    const float* c_w[3][3];
    const float* c_b[3][3];
    for (int p = 0; p < 3; ++p)
        for (int l = 0; l < 3; ++l) {
            c_w[l][p] = (const float*)d_in[2 + p * 6 + l * 2];
            c_b[l][p] = (const float*)d_in[3 + p * 6 + l * 2];
        }
    const float* bn_g[3] = {(const float*)d_in[20], (const float*)d_in[22], (const float*)d_in[24]};
    const float* bn_b[3] = {(const float*)d_in[21], (const float*)d_in[23], (const float*)d_in[25]};
    const float* lw = (const float*)d_in[26];
    const float* lb = (const float*)d_in[27];
    float* out = (float*)d_out;

    char* wp = (char*)d_ws;
    auto alloc = [&](size_t bytes) {
        char* p = wp;
        wp += (bytes + 255) & ~(size_t)255;
        return p;
    };
    int* gcur = (int*)alloc((size_t)NBUCK * 4);
    int* bbase = (int*)alloc((size_t)(NBUCK + 1) * 4);
    int* bcnt = (int*)alloc((size_t)NBUCK * 4);
    int2* ebuf = (int2*)alloc((size_t)NBUCK * BCAP * 8);
    int* row_ptr = (int*)alloc((size_t)(NN + 1) * 4);
    int* ssrc = (int*)alloc((size_t)NE * 4);
    float* dinv = (float*)alloc((size_t)NN * 4);
    float* gsum = (float*)alloc((size_t)2 * CAT * 4);
    float* gsum2 = gsum + CAT;
    ushort* Y0 = (ushort*)alloc((size_t)NN * 64 * 2);
    ushort* Y12 = (ushort*)alloc((size_t)NN * 128 * 2);
    ushort* Z1 = (ushort*)alloc((size_t)NN * 64 * 2);
    ushort* ZQ = (ushort*)alloc((size_t)NN * 64 * 2);
    ushort* Q2 = (ushort*)alloc((size_t)NN * 64 * 2);
    ushort* XB1 = (ushort*)alloc((size_t)NN * 128 * 2);
    ushort* CB = (ushort*)alloc((size_t)NN * 192 * 2);
    ushort* WP1 = (ushort*)alloc((size_t)3 * 4 * 4 * 512 * 2);
    ushort* WP2 = (ushort*)alloc((size_t)3 * 6 * 4 * 512 * 2);
    ushort* WP3 = (ushort*)alloc((size_t)3 * 6 * 4 * 512 * 2);

    // ---- CSR build (write-combined bucketed sort) ----
    k_initcur<<<1, 256, 0, stream>>>(gcur);
    k_bin<<<391, 256, 0, stream>>>(esrc, edst, gcur, ebuf, NE);
    k_bscan<<<1, 256, 0, stream>>>(gcur, bbase, bcnt, row_ptr);
    k_bucket_csr<<<NBUCK, 256, 0, stream>>>(ebuf, bbase, bcnt, row_ptr, dinv, ssrc, NN);

    // ---- prep: x cast + weight packs ----
    k_cast<<<2048, 256, 0, stream>>>(x, XB1, (size_t)NN * 128 / 4);
    k_wpack<<<dim3(16, 3), 64, 0, stream>>>(c_w[0][0], c_w[0][1], c_w[0][2], WP1, FIN0, 4);
    k_wpack<<<dim3(24, 3), 64, 0, stream>>>(c_w[1][0], c_w[1][1], c_w[1][2], WP2, CAT, 6);
    k_wpack<<<dim3(24, 3), 64, 0, stream>>>(c_w[2][0], c_w[2][1], c_w[2][2], WP3, CAT, 6);

    const int gemm_gx = (NN + 63) / 64;
    const int prop_gx = (NN + 3) / 4;
    const size_t bn_total = (size_t)NN * 48;

    for (int l = 0; l < 3; ++l) {
        if (l == 0) {
            k_gemm_mfma<4><<<gemm_gx, 256, 0, stream>>>(XB1, WP1, c_b[0][0], dinv, Y0, Y12, NN);
        } else {
            const ushort* WPl = (l == 1) ? WP2 : WP3;
            k_gemm_mfma<6><<<gemm_gx, 256, 0, stream>>>(CB, WPl, c_b[l][0], dinv, Y0, Y12, NN);
        }
        k_propA<<<prop_gx, 256, 0, stream>>>(Y12, Z1, ZQ, c_b[l][1], dinv, row_ptr, ssrc, NN);
        k_propB<<<prop_gx, 256, 0, stream>>>(ZQ, Q2, c_b[l][2], dinv, row_ptr, ssrc, NN);
        hipMemsetAsync(gsum, 0, (size_t)2 * CAT * 4, stream);
        k_bnstats<<<dim3(256, 3), 256, 0, stream>>>(Y0, Z1, Q2, gsum, gsum2, NN);
        if (l < 2) {
            k_bnapply<<<2048, 256, 0, stream>>>(Y0, Z1, Q2, gsum, gsum2, bn_g[l], bn_b[l],
                                                CB, NN, bn_total);
        } else {
            k_final_fused<<<(NN + 255) / 256, 256, 0, stream>>>(
                Y0, Z1, Q2, gsum, gsum2, bn_g[2], bn_b[2], lw, lb, out, NN);
        }
    }
}

// Round 8
// 383.119 us; speedup vs baseline: 4.7979x; 1.0391x over previous
//
#include <hip/hip_runtime.h>
#include <hip/hip_bf16.h>

#define NN 50000
#define NE 800000
#define FIN0 128
#define HID 60
#define CAT 180
#define NCLS 7
#define BN_EPS 1e-5f
#define NBUCK 196      // ceil(NN/256)
#define BCAP 5120      // max edges per 256-node bucket (mean 4096, sigma 64)

typedef unsigned int uint;
typedef unsigned short ushort;
typedef __attribute__((ext_vector_type(8))) short short8;
typedef __attribute__((ext_vector_type(4))) float f32x4;

__device__ __forceinline__ ushort f2bf(float f) {
    uint u = __float_as_uint(f);
    u += 0x7FFFu + ((u >> 16) & 1u);
    return (ushort)(u >> 16);
}
__device__ __forceinline__ float bf_lo(uint v) { return __uint_as_float(v << 16); }
__device__ __forceinline__ float bf_hi(uint v) { return __uint_as_float(v & 0xFFFF0000u); }
__device__ __forceinline__ float bf2f(ushort u) { return __uint_as_float(((uint)u) << 16); }

// ---------------- CSR build: bucketed, write-combined, 4B packed entries ----

__global__ void k_initcur(int* __restrict__ gcur) {
    int t = threadIdx.x;
    if (t < NBUCK) gcur[t] = t * BCAP;
}

// entry: bits 0-15 = src (N < 65536), bits 16-23 = dst & 255
__global__ __launch_bounds__(256) void k_bin(const int* __restrict__ src,
                                             const int* __restrict__ dst,
                                             int* __restrict__ gcur,
                                             uint* __restrict__ ebuf, int e) {
    __shared__ int cnt[NBUCK];
    __shared__ int base[NBUCK];
    int t = threadIdx.x;
    for (int c0 = blockIdx.x * 2048; c0 < e; c0 += gridDim.x * 2048) {
        if (t < NBUCK) cnt[t] = 0;
        __syncthreads();
        uint pe[8]; int rk[8], bk[8], ok[8];
#pragma unroll
        for (int j = 0; j < 8; ++j) {
            int i = c0 + j * 256 + t;
            ok[j] = i < e;
            if (ok[j]) {
                int sv = src[i], dv = dst[i];
                pe[j] = (uint)(sv & 0xFFFF) | ((uint)(dv & 255) << 16);
                bk[j] = dv >> 8;
                rk[j] = atomicAdd(&cnt[bk[j]], 1);
            }
        }
        __syncthreads();
        if (t < NBUCK && cnt[t] > 0) base[t] = atomicAdd(&gcur[t], cnt[t]);
        __syncthreads();
#pragma unroll
        for (int j = 0; j < 8; ++j) {
            if (ok[j]) ebuf[base[bk[j]] + rk[j]] = pe[j];
        }
        __syncthreads();
    }
}

__global__ void k_bscan(const int* __restrict__ gcur, int* __restrict__ bbase,
                        int* __restrict__ bcnt, int* __restrict__ row_ptr) {
    __shared__ int s[256];
    int t = threadIdx.x;
    int c = (t < NBUCK) ? (gcur[t] - t * BCAP) : 0;
    s[t] = c;
    __syncthreads();
    for (int off = 1; off < 256; off <<= 1) {
        int v = (t >= off) ? s[t - off] : 0;
        __syncthreads();
        s[t] += v;
        __syncthreads();
    }
    if (t < NBUCK) { bbase[t] = s[t] - c; bcnt[t] = c; }
    if (t == 0) row_ptr[NN] = NE;
}

__global__ __launch_bounds__(256) void k_bucket_csr(
        const uint* __restrict__ ebuf, const int* __restrict__ bbase,
        const int* __restrict__ bcnt,
        int* __restrict__ row_ptr, float* __restrict__ dinv,
        ushort* __restrict__ ssrc, int n) {
    __shared__ int ncnt[256];
    __shared__ int loff[256];
    int b = blockIdx.x, t = threadIdx.x;
    int cnt = bcnt[b];
    int gbase = bbase[b];
    const uint* ee = ebuf + (size_t)b * BCAP;
    ncnt[t] = 0;
    __syncthreads();
    for (int i = t; i < cnt; i += 256) atomicAdd(&ncnt[(ee[i] >> 16) & 255], 1);
    __syncthreads();
    int c = ncnt[t];
    loff[t] = c;
    __syncthreads();
    for (int off = 1; off < 256; off <<= 1) {
        int v = (t >= off) ? loff[t - off] : 0;
        __syncthreads();
        loff[t] += v;
        __syncthreads();
    }
    int excl = loff[t] - c;
    int node = b * 256 + t;
    if (node < n) {
        row_ptr[node] = gbase + excl;
        dinv[node] = rsqrtf((float)(c + 1));  // +1 self loop
    }
    __syncthreads();
    ncnt[t] = excl;  // reuse as cursor
    __syncthreads();
    for (int i = t; i < cnt; i += 256) {
        uint pe = ee[i];
        int pos = atomicAdd(&ncnt[(pe >> 16) & 255], 1);
        ssrc[gbase + pos] = (ushort)(pe & 0xFFFF);
    }
}

// ---------------- weight pack into MFMA B-fragment order (all layers) -------
// layer 0: K_real=128 linear. layers 1,2: padded K=192 (3 x 64, cols 60-63 zero)
__global__ void k_wpack_all(
        const float* __restrict__ w00, const float* __restrict__ w01, const float* __restrict__ w02,
        const float* __restrict__ w10, const float* __restrict__ w11, const float* __restrict__ w12,
        const float* __restrict__ w20, const float* __restrict__ w21, const float* __restrict__ w22,
        ushort* __restrict__ WP0, ushort* __restrict__ WP1, ushort* __restrict__ WP2) {
    int l = blockIdx.z, p = blockIdx.y;
    int kt = blockIdx.x >> 2, ct = blockIdx.x & 3;
    int KT = (l == 0) ? 4 : 6;
    if (kt >= KT) return;
    const float* W;
    if (l == 0) W = (p == 0) ? w00 : ((p == 1) ? w01 : w02);
    else if (l == 1) W = (p == 0) ? w10 : ((p == 1) ? w11 : w12);
    else W = (p == 0) ? w20 : ((p == 1) ? w21 : w22);
    ushort* WP = (l == 0) ? WP0 : ((l == 1) ? WP1 : WP2);
    int lane = threadIdx.x;  // 0..63
    int k0 = kt * 32 + (lane >> 4) * 8;
    int c = ct * 16 + (lane & 15);
    ushort* dst = WP + (((size_t)(p * KT + kt) * 4 + ct) << 9) + (lane << 3);
    ushort o[8];
#pragma unroll
    for (int j = 0; j < 8; ++j) {
        int kl = k0 + j;
        float v = 0.f;
        if (c < 60) {
            if (l == 0) {
                if (kl < FIN0) v = W[(size_t)kl * 60 + c];
            } else {
                int rgn = kl >> 6, cc = kl & 63;
                if (cc < 60) v = W[(size_t)(rgn * 60 + cc) * 60 + c];
            }
        }
        o[j] = f2bf(v);
    }
    *(ushort4*)dst = make_ushort4(o[0], o[1], o[2], o[3]);
    *(ushort4*)(dst + 4) = make_ushort4(o[4], o[5], o[6], o[7]);
}

// ---------------- MFMA GEMM, 3 powers per block.
// MODE 0: A from fp32 X (layer 1), no BN. MODE 1: A = BN(Y0|Z1|Q2) on the fly.
// Outputs: Y0 bf16 s64 (+b0); Y12 bf16 s128 interleaved p1/p2, pre-scaled by dinv.
template <int KT, int MODE>
__global__ __launch_bounds__(256) void k_gemm_mfma(
        const float* __restrict__ Xf,
        const ushort* __restrict__ B0q, const ushort* __restrict__ B1q,
        const ushort* __restrict__ B2q,
        const float* __restrict__ gsum, const float* __restrict__ gsum2,
        const float* __restrict__ bng, const float* __restrict__ bnb,
        const ushort* __restrict__ WP,
        const float* __restrict__ b0, const float* __restrict__ dinv,
        ushort* __restrict__ Y0, ushort* __restrict__ Y12, int n) {
    __shared__ float ssc[200], ssh[200];
    const int t = threadIdx.x;
    if (MODE == 1) {
        if (t < 192) {
            int rgn = t >> 6, cc = t & 63;
            float sc = 0.f, sh = 0.f;
            if (cc < 60) {
                int c = rgn * 60 + cc;
                float mu = gsum[c] / (float)n;
                float var = gsum2[c] / (float)n - mu * mu;
                sc = rsqrtf(var + BN_EPS) * bng[c];
                sh = bnb[c] - mu * sc;
            }
            ssc[t] = sc; ssh[t] = sh;
        }
        __syncthreads();
    }
    const int wv = t >> 6;
    const int lane = t & 63;
    const int l15 = lane & 15;
    const int lhi = lane >> 4;
    const int nb = blockIdx.x * 64 + wv * 16;

    f32x4 acc[3][4];
#pragma unroll
    for (int p = 0; p < 3; ++p)
#pragma unroll
        for (int ct = 0; ct < 4; ++ct) acc[p][ct] = (f32x4){0.f, 0.f, 0.f, 0.f};

    const int arow = nb + l15;
    const int arowc = (arow < n) ? arow : 0;
    const ushort* wpL = WP + (lane << 3);

#pragma unroll
    for (int kt = 0; kt < KT; ++kt) {
        short8 a;
        if (MODE == 0) {
            const float* xr = Xf + (size_t)arowc * (KT * 32) + kt * 32 + lhi * 8;
            float4 v0 = *(const float4*)xr;
            float4 v1 = *(const float4*)(xr + 4);
            a[0] = (short)f2bf(v0.x); a[1] = (short)f2bf(v0.y);
            a[2] = (short)f2bf(v0.z); a[3] = (short)f2bf(v0.w);
            a[4] = (short)f2bf(v1.x); a[5] = (short)f2bf(v1.y);
            a[6] = (short)f2bf(v1.z); a[7] = (short)f2bf(v1.w);
        } else {
            const ushort* base = (kt < 2) ? B0q : ((kt < 4) ? B1q : B2q);
            const ushort* ar = base + (size_t)arowc * 64 + (kt & 1) * 32 + lhi * 8;
            uint4 raw = *(const uint4*)ar;
            int kb = kt * 32 + lhi * 8;
            float4 sc0 = *(const float4*)&ssc[kb];
            float4 sc1 = *(const float4*)&ssc[kb + 4];
            float4 sh0 = *(const float4*)&ssh[kb];
            float4 sh1 = *(const float4*)&ssh[kb + 4];
            a[0] = (short)f2bf(bf_lo(raw.x) * sc0.x + sh0.x);
            a[1] = (short)f2bf(bf_hi(raw.x) * sc0.y + sh0.y);
            a[2] = (short)f2bf(bf_lo(raw.y) * sc0.z + sh0.z);
            a[3] = (short)f2bf(bf_hi(raw.y) * sc0.w + sh0.w);
            a[4] = (short)f2bf(bf_lo(raw.z) * sc1.x + sh1.x);
            a[5] = (short)f2bf(bf_hi(raw.z) * sc1.y + sh1.y);
            a[6] = (short)f2bf(bf_lo(raw.w) * sc1.z + sh1.z);
            a[7] = (short)f2bf(bf_hi(raw.w) * sc1.w + sh1.w);
        }
#pragma unroll
        for (int p = 0; p < 3; ++p)
#pragma unroll
            for (int ct = 0; ct < 4; ++ct) {
                short8 b = *(const short8*)(wpL + (((size_t)(p * KT + kt) * 4 + ct) << 9));
                acc[p][ct] = __builtin_amdgcn_mfma_f32_16x16x32_bf16(a, b, acc[p][ct], 0, 0, 0);
            }
    }

    // C/D layout: col = lane&15, row = (lane>>4)*4 + reg
    float dv[4];
#pragma unroll
    for (int j = 0; j < 4; ++j) {
        int node = nb + lhi * 4 + j;
        dv[j] = (node < n) ? dinv[node] : 0.f;
    }
#pragma unroll
    for (int ct = 0; ct < 4; ++ct) {
        int col = ct * 16 + l15;
        if (col >= 60) continue;
        float bias = b0[col];
#pragma unroll
        for (int j = 0; j < 4; ++j) {
            int node = nb + lhi * 4 + j;
            if (node >= n) continue;
            Y0[(size_t)node * 64 + col] = f2bf(acc[0][ct][j] + bias);
            uint pk = ((uint)f2bf(dv[j] * acc[2][ct][j]) << 16) |
                      (uint)f2bf(dv[j] * acc[1][ct][j]);
            *(uint*)(Y12 + (size_t)node * 128 + 2 * col) = pk;
        }
    }
}

// ---------------- propA: hop over pre-scaled Y12 (bf16 interleaved, s128)
__global__ __launch_bounds__(256) void k_propA(
        const ushort* __restrict__ Y12, ushort* __restrict__ Z1, ushort* __restrict__ ZQ,
        const float* __restrict__ b1,
        const float* __restrict__ dinv, const int* __restrict__ rp,
        const ushort* __restrict__ es, int n) {
    int node = blockIdx.x * 4 + (threadIdx.x >> 6);
    int lane = threadIdx.x & 63;
    if (node >= n || lane >= 60) return;
    uint sv = *(const uint*)(Y12 + (size_t)node * 128 + 2 * lane);
    float a1 = bf_lo(sv);
    float a2 = bf_hi(sv);
    int e0 = rp[node], e1 = rp[node + 1];
    int e = e0;
    for (; e + 7 < e1; e += 8) {
        int s0 = es[e], s1 = es[e + 1], s2 = es[e + 2], s3 = es[e + 3];
        int s4 = es[e + 4], s5 = es[e + 5], s6 = es[e + 6], s7 = es[e + 7];
        uint v0 = *(const uint*)(Y12 + (size_t)s0 * 128 + 2 * lane);
        uint v1 = *(const uint*)(Y12 + (size_t)s1 * 128 + 2 * lane);
        uint v2 = *(const uint*)(Y12 + (size_t)s2 * 128 + 2 * lane);
        uint v3 = *(const uint*)(Y12 + (size_t)s3 * 128 + 2 * lane);
        uint v4 = *(const uint*)(Y12 + (size_t)s4 * 128 + 2 * lane);
        uint v5 = *(const uint*)(Y12 + (size_t)s5 * 128 + 2 * lane);
        uint v6 = *(const uint*)(Y12 + (size_t)s6 * 128 + 2 * lane);
        uint v7 = *(const uint*)(Y12 + (size_t)s7 * 128 + 2 * lane);
        a1 += ((bf_lo(v0) + bf_lo(v1)) + (bf_lo(v2) + bf_lo(v3))) +
              ((bf_lo(v4) + bf_lo(v5)) + (bf_lo(v6) + bf_lo(v7)));
        a2 += ((bf_hi(v0) + bf_hi(v1)) + (bf_hi(v2) + bf_hi(v3))) +
              ((bf_hi(v4) + bf_hi(v5)) + (bf_hi(v6) + bf_hi(v7)));
    }
    for (; e < e1; ++e) {
        uint v = *(const uint*)(Y12 + (size_t)es[e] * 128 + 2 * lane);
        a1 += bf_lo(v);
        a2 += bf_hi(v);
    }
    float di = dinv[node];
    Z1[(size_t)node * 64 + lane] = f2bf(di * a1 + b1[lane]);
    ZQ[(size_t)node * 64 + lane] = f2bf(di * di * a2);
}

// ---------------- propB: hop over pre-scaled ZQ (s64) -> Q2 bf16 s64 (+b2)
__global__ __launch_bounds__(256) void k_propB(
        const ushort* __restrict__ ZQ, ushort* __restrict__ Q2,
        const float* __restrict__ b2,
        const float* __restrict__ dinv, const int* __restrict__ rp,
        const ushort* __restrict__ es, int n) {
    int node = blockIdx.x * 4 + (threadIdx.x >> 6);
    int lane = threadIdx.x & 63;
    if (node >= n || lane >= 60) return;
    float acc = bf2f(ZQ[(size_t)node * 64 + lane]);
    int e0 = rp[node], e1 = rp[node + 1];
    int e = e0;
    for (; e + 7 < e1; e += 8) {
        int s0 = es[e], s1 = es[e + 1], s2 = es[e + 2], s3 = es[e + 3];
        int s4 = es[e + 4], s5 = es[e + 5], s6 = es[e + 6], s7 = es[e + 7];
        float x0 = bf2f(ZQ[(size_t)s0 * 64 + lane]);
        float x1 = bf2f(ZQ[(size_t)s1 * 64 + lane]);
        float x2 = bf2f(ZQ[(size_t)s2 * 64 + lane]);
        float x3 = bf2f(ZQ[(size_t)s3 * 64 + lane]);
        float x4 = bf2f(ZQ[(size_t)s4 * 64 + lane]);
        float x5 = bf2f(ZQ[(size_t)s5 * 64 + lane]);
        float x6 = bf2f(ZQ[(size_t)s6 * 64 + lane]);
        float x7 = bf2f(ZQ[(size_t)s7 * 64 + lane]);
        acc += ((x0 + x1) + (x2 + x3)) + ((x4 + x5) + (x6 + x7));
    }
    for (; e < e1; ++e) {
        acc += bf2f(ZQ[(size_t)es[e] * 64 + lane]);
    }
    Q2[(size_t)node * 64 + lane] = f2bf(dinv[node] * acc + b2[lane]);
}

// ---------------- BN stats: coalesced uint4 reads, shfl+LDS reduce
__global__ __launch_bounds__(256) void k_bnstats(
        const ushort* __restrict__ Y0, const ushort* __restrict__ Z1,
        const ushort* __restrict__ Q2,
        float* __restrict__ gsum, float* __restrict__ gsum2, int n) {
    int rgn = blockIdx.y;
    const ushort* __restrict__ src = (rgn == 0) ? Y0 : ((rgn == 1) ? Z1 : Q2);
    int t = threadIdx.x;
    int c8 = (t & 7) * 8;
    int rsub = t >> 3;
    float s1[8], s2[8];
#pragma unroll
    for (int j = 0; j < 8; ++j) { s1[j] = 0.f; s2[j] = 0.f; }
    for (int r = blockIdx.x * 32 + rsub; r < n; r += gridDim.x * 32) {
        uint4 v = *(const uint4*)(src + (size_t)r * 64 + c8);
        float f;
        f = bf_lo(v.x); s1[0] += f; s2[0] += f * f;
        f = bf_hi(v.x); s1[1] += f; s2[1] += f * f;
        f = bf_lo(v.y); s1[2] += f; s2[2] += f * f;
        f = bf_hi(v.y); s1[3] += f; s2[3] += f * f;
        f = bf_lo(v.z); s1[4] += f; s2[4] += f * f;
        f = bf_hi(v.z); s1[5] += f; s2[5] += f * f;
        f = bf_lo(v.w); s1[6] += f; s2[6] += f * f;
        f = bf_hi(v.w); s1[7] += f; s2[7] += f * f;
    }
#pragma unroll
    for (int m = 8; m < 64; m <<= 1) {
#pragma unroll
        for (int j = 0; j < 8; ++j) {
            s1[j] += __shfl_xor(s1[j], m);
            s2[j] += __shfl_xor(s2[j], m);
        }
    }
    __shared__ float ls1[4][64], ls2[4][64];
    int wv = t >> 6, lane = t & 63;
    if (lane < 8) {
#pragma unroll
        for (int j = 0; j < 8; ++j) {
            ls1[wv][lane * 8 + j] = s1[j];
            ls2[wv][lane * 8 + j] = s2[j];
        }
    }
    __syncthreads();
    if (t < 60) {
        float a1 = ls1[0][t] + ls1[1][t] + ls1[2][t] + ls1[3][t];
        float a2 = ls2[0][t] + ls2[1][t] + ls2[2][t] + ls2[3][t];
        atomicAdd(&gsum[rgn * 60 + t], a1);
        atomicAdd(&gsum2[rgn * 60 + t], a2);
    }
}

// ---------------- final linear with fused BN (layer 3): out = BN(h) @ w + b
__global__ __launch_bounds__(256) void k_final_fused(
        const ushort* __restrict__ Y0, const ushort* __restrict__ Z1,
        const ushort* __restrict__ Q2,
        const float* __restrict__ gsum, const float* __restrict__ gsum2,
        const float* __restrict__ g, const float* __restrict__ bb,
        const float* __restrict__ w, const float* __restrict__ wb,
        float* __restrict__ out, int n) {
    __shared__ float sw[CAT * NCLS];
    __shared__ float ssc[CAT], ssh[CAT];
    __shared__ float sb[NCLS];
    int t = threadIdx.x;
    for (int i = t; i < CAT * NCLS; i += 256) sw[i] = w[i];
    if (t < CAT) {
        float mu = gsum[t] / (float)n;
        float var = gsum2[t] / (float)n - mu * mu;
        float sc = rsqrtf(var + BN_EPS) * g[t];
        ssc[t] = sc;
        ssh[t] = bb[t] - mu * sc;
    }
    if (t < NCLS) sb[t] = wb[t];
    __syncthreads();
    int node = blockIdx.x * 256 + t;
    if (node >= n) return;
    float acc[NCLS];
#pragma unroll
    for (int j = 0; j < NCLS; ++j) acc[j] = sb[j];
    const ushort* bufs[3] = {Y0, Z1, Q2};
#pragma unroll
    for (int rgn = 0; rgn < 3; ++rgn) {
        const ushort* sp = bufs[rgn] + (size_t)node * 64;
        int cb = rgn * 60;
#pragma unroll 6
        for (int k2 = 0; k2 < 30; ++k2) {
            uint u = *(const uint*)(sp + 2 * k2);
            int c = cb + 2 * k2;
            float f0 = bf_lo(u) * ssc[c] + ssh[c];
            float f1 = bf_hi(u) * ssc[c + 1] + ssh[c + 1];
#pragma unroll
            for (int j = 0; j < NCLS; ++j)
                acc[j] += f0 * sw[c * NCLS + j] + f1 * sw[(c + 1) * NCLS + j];
        }
    }
#pragma unroll
    for (int j = 0; j < NCLS; ++j) out[(size_t)node * NCLS + j] = acc[j];
}

extern "C" void kernel_launch(void* const* d_in, const int* in_sizes, int n_in,
                              void* d_out, int out_size, void* d_ws, size_t ws_size,
                              hipStream_t stream) {
    const float* x = (const float*)d_in[0];
    const int* ei = (const int*)d_in[1];
    const int* esrc = ei;
    const int* edst = ei + NE;

    const float* c_w[3][3];
    const float* c_b[3][3];
    for (int p = 0; p < 3; ++p)
        for (int l = 0; l < 3; ++l) {
            c_w[l][p] = (const float*)d_in[2 + p * 6 + l * 2];
            c_b[l][p] = (const float*)d_in[3 + p * 6 + l * 2];
        }
    const float* bn_g[3] = {(const float*)d_in[20], (const float*)d_in[22], (const float*)d_in[24]};
    const float* bn_b[3] = {(const float*)d_in[21], (const float*)d_in[23], (const float*)d_in[25]};
    const float* lw = (const float*)d_in[26];
    const float* lb = (const float*)d_in[27];
    float* out = (float*)d_out;

    char* wp = (char*)d_ws;
    auto alloc = [&](size_t bytes) {
        char* p = wp;
        wp += (bytes + 255) & ~(size_t)255;
        return p;
    };
    int* gcur = (int*)alloc((size_t)NBUCK * 4);
    int* bbase = (int*)alloc((size_t)(NBUCK + 1) * 4);
    int* bcnt = (int*)alloc((size_t)NBUCK * 4);
    uint* ebuf = (uint*)alloc((size_t)NBUCK * BCAP * 4);
    int* row_ptr = (int*)alloc((size_t)(NN + 1) * 4);
    ushort* ssrc = (ushort*)alloc((size_t)NE * 2);
    float* dinv = (float*)alloc((size_t)NN * 4);
    float* gsumAll = (float*)alloc((size_t)3 * 2 * CAT * 4);  // [layer][sum|sum2]
    ushort* Y0 = (ushort*)alloc((size_t)NN * 64 * 2);
    ushort* Y12 = (ushort*)alloc((size_t)NN * 128 * 2);
    ushort* Z1 = (ushort*)alloc((size_t)NN * 64 * 2);
    ushort* ZQ = (ushort*)alloc((size_t)NN * 64 * 2);
    ushort* Q2 = (ushort*)alloc((size_t)NN * 64 * 2);
    ushort* WP1 = (ushort*)alloc((size_t)3 * 4 * 4 * 512 * 2);
    ushort* WP2 = (ushort*)alloc((size_t)3 * 6 * 4 * 512 * 2);
    ushort* WP3 = (ushort*)alloc((size_t)3 * 6 * 4 * 512 * 2);

    auto gs = [&](int l) { return gsumAll + (size_t)l * 2 * CAT; };
    auto gs2 = [&](int l) { return gsumAll + (size_t)l * 2 * CAT + CAT; };

    // ---- CSR build (write-combined bucketed sort) ----
    k_initcur<<<1, 256, 0, stream>>>(gcur);
    k_bin<<<391, 256, 0, stream>>>(esrc, edst, gcur, ebuf, NE);
    k_bscan<<<1, 256, 0, stream>>>(gcur, bbase, bcnt, row_ptr);
    k_bucket_csr<<<NBUCK, 256, 0, stream>>>(ebuf, bbase, bcnt, row_ptr, dinv, ssrc, NN);

    // ---- weight packs (single launch) + BN-sum zeroing (single memset) ----
    k_wpack_all<<<dim3(24, 3, 3), 64, 0, stream>>>(
        c_w[0][0], c_w[0][1], c_w[0][2],
        c_w[1][0], c_w[1][1], c_w[1][2],
        c_w[2][0], c_w[2][1], c_w[2][2],
        WP1, WP2, WP3);
    hipMemsetAsync(gsumAll, 0, (size_t)3 * 2 * CAT * 4, stream);

    const int gemm_gx = (NN + 63) / 64;
    const int prop_gx = (NN + 3) / 4;

    for (int l = 0; l < 3; ++l) {
        if (l == 0) {
            k_gemm_mfma<4, 0><<<gemm_gx, 256, 0, stream>>>(
                x, nullptr, nullptr, nullptr, nullptr, nullptr, nullptr, nullptr,
                WP1, c_b[0][0], dinv, Y0, Y12, NN);
        } else {
            const ushort* WPl = (l == 1) ? WP2 : WP3;
            k_gemm_mfma<6, 1><<<gemm_gx, 256, 0, stream>>>(
                nullptr, Y0, Z1, Q2, gs(l - 1), gs2(l - 1), bn_g[l - 1], bn_b[l - 1],
                WPl, c_b[l][0], dinv, Y0, Y12, NN);
        }
        k_propA<<<prop_gx, 256, 0, stream>>>(Y12, Z1, ZQ, c_b[l][1], dinv, row_ptr, ssrc, NN);
        k_propB<<<prop_gx, 256, 0, stream>>>(ZQ, Q2, c_b[l][2], dinv, row_ptr, ssrc, NN);
        k_bnstats<<<dim3(256, 3), 256, 0, stream>>>(Y0, Z1, Q2, gs(l), gs2(l), NN);
    }

    k_final_fused<<<(NN + 255) / 256, 256, 0, stream>>>(
        Y0, Z1, Q2, gs(2), gs2(2), bn_g[2], bn_b[2], lw, lb, out, NN);
}

// Round 9
// 332.143 us; speedup vs baseline: 5.5342x; 1.1535x over previous
//
#include <hip/hip_runtime.h>
#include <hip/hip_bf16.h>

#define NN 50000
#define NE 800000
#define FIN0 128
#define HID 60
#define CAT 180
#define NCLS 7
#define BN_EPS 1e-5f
#define NBUCK 196      // ceil(NN/256)
#define BCAP 5120      // max edges per 256-node bucket (mean 4096, sigma 64)
#define STG 96         // staged edge-index cap per node (P(deg>96) ~ 0)

typedef unsigned int uint;
typedef unsigned short ushort;
typedef __attribute__((ext_vector_type(8))) short short8;
typedef __attribute__((ext_vector_type(4))) float f32x4;

__device__ __forceinline__ ushort f2bf(float f) {
    uint u = __float_as_uint(f);
    u += 0x7FFFu + ((u >> 16) & 1u);
    return (ushort)(u >> 16);
}
__device__ __forceinline__ float bf_lo(uint v) { return __uint_as_float(v << 16); }
__device__ __forceinline__ float bf_hi(uint v) { return __uint_as_float(v & 0xFFFF0000u); }
__device__ __forceinline__ float bf2f(ushort u) { return __uint_as_float(((uint)u) << 16); }

// ---------------- CSR build: bucketed, write-combined, 4B packed entries ----

__global__ void k_initcur(int* __restrict__ gcur) {
    int t = threadIdx.x;
    if (t < NBUCK) gcur[t] = t * BCAP;
}

// entry: bits 0-15 = src (N < 65536), bits 16-23 = dst & 255
__global__ __launch_bounds__(256) void k_bin(const int* __restrict__ src,
                                             const int* __restrict__ dst,
                                             int* __restrict__ gcur,
                                             uint* __restrict__ ebuf, int e) {
    __shared__ int cnt[NBUCK];
    __shared__ int base[NBUCK];
    int t = threadIdx.x;
    for (int c0 = blockIdx.x * 2048; c0 < e; c0 += gridDim.x * 2048) {
        if (t < NBUCK) cnt[t] = 0;
        __syncthreads();
        uint pe[8]; int rk[8], bk[8], ok[8];
#pragma unroll
        for (int j = 0; j < 8; ++j) {
            int i = c0 + j * 256 + t;
            ok[j] = i < e;
            if (ok[j]) {
                int sv = src[i], dv = dst[i];
                pe[j] = (uint)(sv & 0xFFFF) | ((uint)(dv & 255) << 16);
                bk[j] = dv >> 8;
                rk[j] = atomicAdd(&cnt[bk[j]], 1);
            }
        }
        __syncthreads();
        if (t < NBUCK && cnt[t] > 0) base[t] = atomicAdd(&gcur[t], cnt[t]);
        __syncthreads();
#pragma unroll
        for (int j = 0; j < 8; ++j) {
            if (ok[j]) ebuf[base[bk[j]] + rk[j]] = pe[j];
        }
        __syncthreads();
    }
}

__global__ void k_bscan(const int* __restrict__ gcur, int* __restrict__ bbase,
                        int* __restrict__ bcnt, int* __restrict__ row_ptr) {
    __shared__ int s[256];
    int t = threadIdx.x;
    int c = (t < NBUCK) ? (gcur[t] - t * BCAP) : 0;
    s[t] = c;
    __syncthreads();
    for (int off = 1; off < 256; off <<= 1) {
        int v = (t >= off) ? s[t - off] : 0;
        __syncthreads();
        s[t] += v;
        __syncthreads();
    }
    if (t < NBUCK) { bbase[t] = s[t] - c; bcnt[t] = c; }
    if (t == 0) row_ptr[NN] = NE;
}

__global__ __launch_bounds__(256) void k_bucket_csr(
        const uint* __restrict__ ebuf, const int* __restrict__ bbase,
        const int* __restrict__ bcnt,
        int* __restrict__ row_ptr, float* __restrict__ dinv,
        ushort* __restrict__ ssrc, int n) {
    __shared__ int ncnt[256];
    __shared__ int loff[256];
    int b = blockIdx.x, t = threadIdx.x;
    int cnt = bcnt[b];
    int gbase = bbase[b];
    const uint* ee = ebuf + (size_t)b * BCAP;
    ncnt[t] = 0;
    __syncthreads();
    for (int i = t; i < cnt; i += 256) atomicAdd(&ncnt[(ee[i] >> 16) & 255], 1);
    __syncthreads();
    int c = ncnt[t];
    loff[t] = c;
    __syncthreads();
    for (int off = 1; off < 256; off <<= 1) {
        int v = (t >= off) ? loff[t - off] : 0;
        __syncthreads();
        loff[t] += v;
        __syncthreads();
    }
    int excl = loff[t] - c;
    int node = b * 256 + t;
    if (node < n) {
        row_ptr[node] = gbase + excl;
        dinv[node] = rsqrtf((float)(c + 1));  // +1 self loop
    }
    __syncthreads();
    ncnt[t] = excl;  // reuse as cursor
    __syncthreads();
    for (int i = t; i < cnt; i += 256) {
        uint pe = ee[i];
        int pos = atomicAdd(&ncnt[(pe >> 16) & 255], 1);
        ssrc[gbase + pos] = (ushort)(pe & 0xFFFF);
    }
}

// ---------------- weight pack into MFMA B-fragment order (all layers) -------
__global__ void k_wpack_all(
        const float* __restrict__ w00, const float* __restrict__ w01, const float* __restrict__ w02,
        const float* __restrict__ w10, const float* __restrict__ w11, const float* __restrict__ w12,
        const float* __restrict__ w20, const float* __restrict__ w21, const float* __restrict__ w22,
        ushort* __restrict__ WP0, ushort* __restrict__ WP1, ushort* __restrict__ WP2) {
    int l = blockIdx.z, p = blockIdx.y;
    int kt = blockIdx.x >> 2, ct = blockIdx.x & 3;
    int KT = (l == 0) ? 4 : 6;
    if (kt >= KT) return;
    const float* W;
    if (l == 0) W = (p == 0) ? w00 : ((p == 1) ? w01 : w02);
    else if (l == 1) W = (p == 0) ? w10 : ((p == 1) ? w11 : w12);
    else W = (p == 0) ? w20 : ((p == 1) ? w21 : w22);
    ushort* WP = (l == 0) ? WP0 : ((l == 1) ? WP1 : WP2);
    int lane = threadIdx.x;  // 0..63
    int k0 = kt * 32 + (lane >> 4) * 8;
    int c = ct * 16 + (lane & 15);
    ushort* dst = WP + (((size_t)(p * KT + kt) * 4 + ct) << 9) + (lane << 3);
    ushort o[8];
#pragma unroll
    for (int j = 0; j < 8; ++j) {
        int kl = k0 + j;
        float v = 0.f;
        if (c < 60) {
            if (l == 0) {
                if (kl < FIN0) v = W[(size_t)kl * 60 + c];
            } else {
                int rgn = kl >> 6, cc = kl & 63;
                if (cc < 60) v = W[(size_t)(rgn * 60 + cc) * 60 + c];
            }
        }
        o[j] = f2bf(v);
    }
    *(ushort4*)dst = make_ushort4(o[0], o[1], o[2], o[3]);
    *(ushort4*)(dst + 4) = make_ushort4(o[4], o[5], o[6], o[7]);
}

// ---------------- MFMA GEMM, 3 powers per block.
template <int KT, int MODE>
__global__ __launch_bounds__(256) void k_gemm_mfma(
        const float* __restrict__ Xf,
        const ushort* __restrict__ B0q, const ushort* __restrict__ B1q,
        const ushort* __restrict__ B2q,
        const float* __restrict__ gsum, const float* __restrict__ gsum2,
        const float* __restrict__ bng, const float* __restrict__ bnb,
        const ushort* __restrict__ WP,
        const float* __restrict__ b0, const float* __restrict__ dinv,
        ushort* __restrict__ Y0, ushort* __restrict__ Y12, int n) {
    __shared__ float ssc[200], ssh[200];
    const int t = threadIdx.x;
    if (MODE == 1) {
        if (t < 192) {
            int rgn = t >> 6, cc = t & 63;
            float sc = 0.f, sh = 0.f;
            if (cc < 60) {
                int c = rgn * 60 + cc;
                float mu = gsum[c] / (float)n;
                float var = gsum2[c] / (float)n - mu * mu;
                sc = rsqrtf(var + BN_EPS) * bng[c];
                sh = bnb[c] - mu * sc;
            }
            ssc[t] = sc; ssh[t] = sh;
        }
        __syncthreads();
    }
    const int wv = t >> 6;
    const int lane = t & 63;
    const int l15 = lane & 15;
    const int lhi = lane >> 4;
    const int nb = blockIdx.x * 64 + wv * 16;

    f32x4 acc[3][4];
#pragma unroll
    for (int p = 0; p < 3; ++p)
#pragma unroll
        for (int ct = 0; ct < 4; ++ct) acc[p][ct] = (f32x4){0.f, 0.f, 0.f, 0.f};

    const int arow = nb + l15;
    const int arowc = (arow < n) ? arow : 0;
    const ushort* wpL = WP + (lane << 3);

#pragma unroll
    for (int kt = 0; kt < KT; ++kt) {
        short8 a;
        if (MODE == 0) {
            const float* xr = Xf + (size_t)arowc * (KT * 32) + kt * 32 + lhi * 8;
            float4 v0 = *(const float4*)xr;
            float4 v1 = *(const float4*)(xr + 4);
            a[0] = (short)f2bf(v0.x); a[1] = (short)f2bf(v0.y);
            a[2] = (short)f2bf(v0.z); a[3] = (short)f2bf(v0.w);
            a[4] = (short)f2bf(v1.x); a[5] = (short)f2bf(v1.y);
            a[6] = (short)f2bf(v1.z); a[7] = (short)f2bf(v1.w);
        } else {
            const ushort* base = (kt < 2) ? B0q : ((kt < 4) ? B1q : B2q);
            const ushort* ar = base + (size_t)arowc * 64 + (kt & 1) * 32 + lhi * 8;
            uint4 raw = *(const uint4*)ar;
            int kb = kt * 32 + lhi * 8;
            float4 sc0 = *(const float4*)&ssc[kb];
            float4 sc1 = *(const float4*)&ssc[kb + 4];
            float4 sh0 = *(const float4*)&ssh[kb];
            float4 sh1 = *(const float4*)&ssh[kb + 4];
            a[0] = (short)f2bf(bf_lo(raw.x) * sc0.x + sh0.x);
            a[1] = (short)f2bf(bf_hi(raw.x) * sc0.y + sh0.y);
            a[2] = (short)f2bf(bf_lo(raw.y) * sc0.z + sh0.z);
            a[3] = (short)f2bf(bf_hi(raw.y) * sc0.w + sh0.w);
            a[4] = (short)f2bf(bf_lo(raw.z) * sc1.x + sh1.x);
            a[5] = (short)f2bf(bf_hi(raw.z) * sc1.y + sh1.y);
            a[6] = (short)f2bf(bf_lo(raw.w) * sc1.z + sh1.z);
            a[7] = (short)f2bf(bf_hi(raw.w) * sc1.w + sh1.w);
        }
#pragma unroll
        for (int p = 0; p < 3; ++p)
#pragma unroll
            for (int ct = 0; ct < 4; ++ct) {
                short8 b = *(const short8*)(wpL + (((size_t)(p * KT + kt) * 4 + ct) << 9));
                acc[p][ct] = __builtin_amdgcn_mfma_f32_16x16x32_bf16(a, b, acc[p][ct], 0, 0, 0);
            }
    }

    // C/D layout: col = lane&15, row = (lane>>4)*4 + reg
    float dv[4];
#pragma unroll
    for (int j = 0; j < 4; ++j) {
        int node = nb + lhi * 4 + j;
        dv[j] = (node < n) ? dinv[node] : 0.f;
    }
#pragma unroll
    for (int ct = 0; ct < 4; ++ct) {
        int col = ct * 16 + l15;
        if (col >= 60) continue;
        float bias = b0[col];
#pragma unroll
        for (int j = 0; j < 4; ++j) {
            int node = nb + lhi * 4 + j;
            if (node >= n) continue;
            Y0[(size_t)node * 64 + col] = f2bf(acc[0][ct][j] + bias);
            uint pk = ((uint)f2bf(dv[j] * acc[2][ct][j]) << 16) |
                      (uint)f2bf(dv[j] * acc[1][ct][j]);
            *(uint*)(Y12 + (size_t)node * 128 + 2 * col) = pk;
        }
    }
}

// ---------------- propA: hop over pre-scaled Y12 (bf16 interleaved, s128)
// LDS-staged edge indices -> all gathers independent (max MLP)
__global__ __launch_bounds__(256) void k_propA(
        const ushort* __restrict__ Y12, ushort* __restrict__ Z1, ushort* __restrict__ ZQ,
        const float* __restrict__ b1,
        const float* __restrict__ dinv, const int* __restrict__ rp,
        const ushort* __restrict__ es, int n) {
    __shared__ ushort sidx[4][STG];
    int sub = threadIdx.x >> 6;
    int lane = threadIdx.x & 63;
    int node = blockIdx.x * 4 + sub;
    if (node >= n) return;
    int e0 = rp[node], e1 = rp[node + 1];
    int deg = e1 - e0;
    int stg = (deg < STG) ? deg : STG;
    for (int i = lane; i < stg; i += 64) sidx[sub][i] = es[e0 + i];
    // same-wave LDS write->read: compiler inserts lgkmcnt wait, no barrier needed
    if (lane >= 60) return;
    uint sv = *(const uint*)(Y12 + (size_t)node * 128 + 2 * lane);
    float a1 = bf_lo(sv);
    float a2 = bf_hi(sv);
    int e = 0;
    for (; e + 15 < stg; e += 16) {
        uint v[16];
#pragma unroll
        for (int j = 0; j < 16; ++j) {
            int s = sidx[sub][e + j];
            v[j] = *(const uint*)(Y12 + (size_t)s * 128 + 2 * lane);
        }
#pragma unroll
        for (int j = 0; j < 16; ++j) { a1 += bf_lo(v[j]); a2 += bf_hi(v[j]); }
    }
    for (; e + 3 < stg; e += 4) {
        uint v[4];
#pragma unroll
        for (int j = 0; j < 4; ++j) {
            int s = sidx[sub][e + j];
            v[j] = *(const uint*)(Y12 + (size_t)s * 128 + 2 * lane);
        }
#pragma unroll
        for (int j = 0; j < 4; ++j) { a1 += bf_lo(v[j]); a2 += bf_hi(v[j]); }
    }
    for (; e < stg; ++e) {
        uint v = *(const uint*)(Y12 + (size_t)sidx[sub][e] * 128 + 2 * lane);
        a1 += bf_lo(v);
        a2 += bf_hi(v);
    }
    for (int ee = e0 + stg; ee < e1; ++ee) {  // overflow tail (rare)
        uint v = *(const uint*)(Y12 + (size_t)es[ee] * 128 + 2 * lane);
        a1 += bf_lo(v);
        a2 += bf_hi(v);
    }
    float di = dinv[node];
    Z1[(size_t)node * 64 + lane] = f2bf(di * a1 + b1[lane]);
    ZQ[(size_t)node * 64 + lane] = f2bf(di * di * a2);
}

// ---------------- propB: hop over pre-scaled ZQ (s64) -> Q2 bf16 s64 (+b2)
__global__ __launch_bounds__(256) void k_propB(
        const ushort* __restrict__ ZQ, ushort* __restrict__ Q2,
        const float* __restrict__ b2,
        const float* __restrict__ dinv, const int* __restrict__ rp,
        const ushort* __restrict__ es, int n) {
    __shared__ ushort sidx[4][STG];
    int sub = threadIdx.x >> 6;
    int lane = threadIdx.x & 63;
    int node = blockIdx.x * 4 + sub;
    if (node >= n) return;
    int e0 = rp[node], e1 = rp[node + 1];
    int deg = e1 - e0;
    int stg = (deg < STG) ? deg : STG;
    for (int i = lane; i < stg; i += 64) sidx[sub][i] = es[e0 + i];
    if (lane >= 60) return;
    float acc = bf2f(ZQ[(size_t)node * 64 + lane]);
    int e = 0;
    for (; e + 15 < stg; e += 16) {
        ushort v[16];
#pragma unroll
        for (int j = 0; j < 16; ++j) {
            int s = sidx[sub][e + j];
            v[j] = ZQ[(size_t)s * 64 + lane];
        }
#pragma unroll
        for (int j = 0; j < 16; ++j) acc += bf2f(v[j]);
    }
    for (; e + 3 < stg; e += 4) {
        ushort v[4];
#pragma unroll
        for (int j = 0; j < 4; ++j) {
            int s = sidx[sub][e + j];
            v[j] = ZQ[(size_t)s * 64 + lane];
        }
#pragma unroll
        for (int j = 0; j < 4; ++j) acc += bf2f(v[j]);
    }
    for (; e < stg; ++e) acc += bf2f(ZQ[(size_t)sidx[sub][e] * 64 + lane]);
    for (int ee = e0 + stg; ee < e1; ++ee) acc += bf2f(ZQ[(size_t)es[ee] * 64 + lane]);
    Q2[(size_t)node * 64 + lane] = f2bf(dinv[node] * acc + b2[lane]);
}

// ---------------- BN stats: coalesced uint4 reads, shfl+LDS reduce
__global__ __launch_bounds__(256) void k_bnstats(
        const ushort* __restrict__ Y0, const ushort* __restrict__ Z1,
        const ushort* __restrict__ Q2,
        float* __restrict__ gsum, float* __restrict__ gsum2, int n) {
    int rgn = blockIdx.y;
    const ushort* __restrict__ src = (rgn == 0) ? Y0 : ((rgn == 1) ? Z1 : Q2);
    int t = threadIdx.x;
    int c8 = (t & 7) * 8;
    int rsub = t >> 3;
    float s1[8], s2[8];
#pragma unroll
    for (int j = 0; j < 8; ++j) { s1[j] = 0.f; s2[j] = 0.f; }
    for (int r = blockIdx.x * 32 + rsub; r < n; r += gridDim.x * 32) {
        uint4 v = *(const uint4*)(src + (size_t)r * 64 + c8);
        float f;
        f = bf_lo(v.x); s1[0] += f; s2[0] += f * f;
        f = bf_hi(v.x); s1[1] += f; s2[1] += f * f;
        f = bf_lo(v.y); s1[2] += f; s2[2] += f * f;
        f = bf_hi(v.y); s1[3] += f; s2[3] += f * f;
        f = bf_lo(v.z); s1[4] += f; s2[4] += f * f;
        f = bf_hi(v.z); s1[5] += f; s2[5] += f * f;
        f = bf_lo(v.w); s1[6] += f; s2[6] += f * f;
        f = bf_hi(v.w); s1[7] += f; s2[7] += f * f;
    }
#pragma unroll
    for (int m = 8; m < 64; m <<= 1) {
#pragma unroll
        for (int j = 0; j < 8; ++j) {
            s1[j] += __shfl_xor(s1[j], m);
            s2[j] += __shfl_xor(s2[j], m);
        }
    }
    __shared__ float ls1[4][64], ls2[4][64];
    int wv = t >> 6, lane = t & 63;
    if (lane < 8) {
#pragma unroll
        for (int j = 0; j < 8; ++j) {
            ls1[wv][lane * 8 + j] = s1[j];
            ls2[wv][lane * 8 + j] = s2[j];
        }
    }
    __syncthreads();
    if (t < 60) {
        float a1 = ls1[0][t] + ls1[1][t] + ls1[2][t] + ls1[3][t];
        float a2 = ls2[0][t] + ls2[1][t] + ls2[2][t] + ls2[3][t];
        atomicAdd(&gsum[rgn * 60 + t], a1);
        atomicAdd(&gsum2[rgn * 60 + t], a2);
    }
}

// ---------------- final linear with fused BN (layer 3): out = BN(h) @ w + b
__global__ __launch_bounds__(256) void k_final_fused(
        const ushort* __restrict__ Y0, const ushort* __restrict__ Z1,
        const ushort* __restrict__ Q2,
        const float* __restrict__ gsum, const float* __restrict__ gsum2,
        const float* __restrict__ g, const float* __restrict__ bb,
        const float* __restrict__ w, const float* __restrict__ wb,
        float* __restrict__ out, int n) {
    __shared__ float sw[CAT * NCLS];
    __shared__ float ssc[CAT], ssh[CAT];
    __shared__ float sb[NCLS];
    int t = threadIdx.x;
    for (int i = t; i < CAT * NCLS; i += 256) sw[i] = w[i];
    if (t < CAT) {
        float mu = gsum[t] / (float)n;
        float var = gsum2[t] / (float)n - mu * mu;
        float sc = rsqrtf(var + BN_EPS) * g[t];
        ssc[t] = sc;
        ssh[t] = bb[t] - mu * sc;
    }
    if (t < NCLS) sb[t] = wb[t];
    __syncthreads();
    int node = blockIdx.x * 256 + t;
    if (node >= n) return;
    float acc[NCLS];
#pragma unroll
    for (int j = 0; j < NCLS; ++j) acc[j] = sb[j];
    const ushort* bufs[3] = {Y0, Z1, Q2};
#pragma unroll
    for (int rgn = 0; rgn < 3; ++rgn) {
        const ushort* sp = bufs[rgn] + (size_t)node * 64;
        int cb = rgn * 60;
#pragma unroll 6
        for (int k2 = 0; k2 < 30; ++k2) {
            uint u = *(const uint*)(sp + 2 * k2);
            int c = cb + 2 * k2;
            float f0 = bf_lo(u) * ssc[c] + ssh[c];
            float f1 = bf_hi(u) * ssc[c + 1] + ssh[c + 1];
#pragma unroll
            for (int j = 0; j < NCLS; ++j)
                acc[j] += f0 * sw[c * NCLS + j] + f1 * sw[(c + 1) * NCLS + j];
        }
    }
#pragma unroll
    for (int j = 0; j < NCLS; ++j) out[(size_t)node * NCLS + j] = acc[j];
}

extern "C" void kernel_launch(void* const* d_in, const int* in_sizes, int n_in,
                              void* d_out, int out_size, void* d_ws, size_t ws_size,
                              hipStream_t stream) {
    const float* x = (const float*)d_in[0];
    const int* ei = (const int*)d_in[1];
    const int* esrc = ei;
    const int* edst = ei + NE;

    const float* c_w[3][3];
    const float* c_b[3][3];
    for (int p = 0; p < 3; ++p)
        for (int l = 0; l < 3; ++l) {
            c_w[l][p] = (const float*)d_in[2 + p * 6 + l * 2];
            c_b[l][p] = (const float*)d_in[3 + p * 6 + l * 2];
        }
    const float* bn_g[3] = {(const float*)d_in[20], (const float*)d_in[22], (const float*)d_in[24]};
    const float* bn_b[3] = {(const float*)d_in[21], (const float*)d_in[23], (const float*)d_in[25]};
    const float* lw = (const float*)d_in[26];
    const float* lb = (const float*)d_in[27];
    float* out = (float*)d_out;

    char* wp = (char*)d_ws;
    auto alloc = [&](size_t bytes) {
        char* p = wp;
        wp += (bytes + 255) & ~(size_t)255;
        return p;
    };
    int* gcur = (int*)alloc((size_t)NBUCK * 4);
    int* bbase = (int*)alloc((size_t)(NBUCK + 1) * 4);
    int* bcnt = (int*)alloc((size_t)NBUCK * 4);
    uint* ebuf = (uint*)alloc((size_t)NBUCK * BCAP * 4);
    int* row_ptr = (int*)alloc((size_t)(NN + 1) * 4);
    ushort* ssrc = (ushort*)alloc((size_t)NE * 2);
    float* dinv = (float*)alloc((size_t)NN * 4);
    float* gsumAll = (float*)alloc((size_t)3 * 2 * CAT * 4);  // [layer][sum|sum2]
    ushort* Y0 = (ushort*)alloc((size_t)NN * 64 * 2);
    ushort* Y12 = (ushort*)alloc((size_t)NN * 128 * 2);
    ushort* Z1 = (ushort*)alloc((size_t)NN * 64 * 2);
    ushort* ZQ = (ushort*)alloc((size_t)NN * 64 * 2);
    ushort* Q2 = (ushort*)alloc((size_t)NN * 64 * 2);
    ushort* WP1 = (ushort*)alloc((size_t)3 * 4 * 4 * 512 * 2);
    ushort* WP2 = (ushort*)alloc((size_t)3 * 6 * 4 * 512 * 2);
    ushort* WP3 = (ushort*)alloc((size_t)3 * 6 * 4 * 512 * 2);

    auto gs = [&](int l) { return gsumAll + (size_t)l * 2 * CAT; };
    auto gs2 = [&](int l) { return gsumAll + (size_t)l * 2 * CAT + CAT; };

    // ---- CSR build (write-combined bucketed sort) ----
    k_initcur<<<1, 256, 0, stream>>>(gcur);
    k_bin<<<391, 256, 0, stream>>>(esrc, edst, gcur, ebuf, NE);
    k_bscan<<<1, 256, 0, stream>>>(gcur, bbase, bcnt, row_ptr);
    k_bucket_csr<<<NBUCK, 256, 0, stream>>>(ebuf, bbase, bcnt, row_ptr, dinv, ssrc, NN);

    // ---- weight packs (single launch) + BN-sum zeroing (single memset) ----
    k_wpack_all<<<dim3(24, 3, 3), 64, 0, stream>>>(
        c_w[0][0], c_w[0][1], c_w[0][2],
        c_w[1][0], c_w[1][1], c_w[1][2],
        c_w[2][0], c_w[2][1], c_w[2][2],
        WP1, WP2, WP3);
    hipMemsetAsync(gsumAll, 0, (size_t)3 * 2 * CAT * 4, stream);

    const int gemm_gx = (NN + 63) / 64;
    const int prop_gx = (NN + 3) / 4;

    for (int l = 0; l < 3; ++l) {
        if (l == 0) {
            k_gemm_mfma<4, 0><<<gemm_gx, 256, 0, stream>>>(
                x, nullptr, nullptr, nullptr, nullptr, nullptr, nullptr, nullptr,
                WP1, c_b[0][0], dinv, Y0, Y12, NN);
        } else {
            const ushort* WPl = (l == 1) ? WP2 : WP3;
            k_gemm_mfma<6, 1><<<gemm_gx, 256, 0, stream>>>(
                nullptr, Y0, Z1, Q2, gs(l - 1), gs2(l - 1), bn_g[l - 1], bn_b[l - 1],
                WPl, c_b[l][0], dinv, Y0, Y12, NN);
        }
        k_propA<<<prop_gx, 256, 0, stream>>>(Y12, Z1, ZQ, c_b[l][1], dinv, row_ptr, ssrc, NN);
        k_propB<<<prop_gx, 256, 0, stream>>>(ZQ, Q2, c_b[l][2], dinv, row_ptr, ssrc, NN);
        k_bnstats<<<dim3(256, 3), 256, 0, stream>>>(Y0, Z1, Q2, gs(l), gs2(l), NN);
    }

    k_final_fused<<<(NN + 255) / 256, 256, 0, stream>>>(
        Y0, Z1, Q2, gs(2), gs2(2), bn_g[2], bn_b[2], lw, lb, out, NN);
}